// Round 6
// baseline (5919.762 us; speedup 1.0000x reference)
//
#include <hip/hip_runtime.h>
#include <stdint.h>

typedef __attribute__((ext_vector_type(8))) short bf16x8;
typedef __attribute__((ext_vector_type(4))) float f32x4;
typedef unsigned short u16;
typedef unsigned int u32;

#define MTOK 2048
#define DMODEL 1024
#define NCELL 4096
#define DCELL 256
#define DFF 4096
#define NVOCAB 50257
#define VCHUNK 3072            // vocab cols per chunk (24 panels)
#define VPAD_LD 3072

struct __attribute__((packed, aligned(4))) f4u { float x, y, z, w; };

static __device__ __forceinline__ u16 f2bf(float f) {
  u32 u = __builtin_bit_cast(u32, f);
  u = (u + 0x7FFFu + ((u >> 16) & 1u)) >> 16;
  return (u16)u;
}
static __device__ __forceinline__ u32 pk2(float a, float b) {
  return (u32)f2bf(a) | ((u32)f2bf(b) << 16);
}
static __device__ __forceinline__ float sigm(float x) { return 1.0f / (1.0f + __expf(-x)); }

static __device__ __forceinline__ float blockReduceSum(float v) {
#pragma unroll
  for (int o = 32; o > 0; o >>= 1) v += __shfl_xor(v, o);
  __shared__ float sm[4];
  __syncthreads();
  if ((threadIdx.x & 63) == 0) sm[threadIdx.x >> 6] = v;
  __syncthreads();
  return sm[0] + sm[1] + sm[2] + sm[3];
}

// ---------------------------------------------------------------------------
// 128x128 GEMM (NT): C[2048,N] = A[2048,K](bf16) x B[N,K]^T
// 1D grid, XCD-affine swizzle. EPI: 0 = Cf = alpha*acc
//   3 = fused SwiGLU (B cols interleaved even=g odd=u) -> bf16 Cb, packed u32
// ---------------------------------------------------------------------------
template<int BF32, int EPI>
__global__ __launch_bounds__(256, 2) void k_gemm(
    const u16* __restrict__ A, const void* __restrict__ Bv,
    float* __restrict__ Cf, u16* __restrict__ Cb,
    int N, int K, int lda, int ldb, int ldc, float alpha)
{
  __shared__ __align__(16) u16 As[128 * 64];
  __shared__ __align__(16) u16 Bs[128 * 64];
  const int tid = threadIdx.x;
  const int T = gridDim.x;
  const int bid = blockIdx.x;
  const int w = (bid & 7) * (T >> 3) + (bid >> 3);
  const int m0 = (w & 15) * 128;
  const int n0 = (w >> 4) * 128;
  const int l = tid & 63;
  const int wv = tid >> 6;
  const int wm = wv >> 1, wn = wv & 1;
  const int lr = l & 15, lg = l >> 4;

  const u16* Bb = (const u16*)Bv;
  const float* Bf = (const float*)Bv;

  uint4 aR[4];
  uint4 bR[4];
  float4 bF[8];
  f32x4 acc[4][4] = {};
  const int nk = K >> 6;

  auto loadA = [&](int k0) {
#pragma unroll
    for (int c = 0; c < 4; ++c) {
      int id = c * 256 + tid;
      int row = id >> 3, kc = (id & 7) << 3;
      aR[c] = *(const uint4*)&A[(size_t)(m0 + row) * lda + k0 + kc];
    }
  };
  auto loadB = [&](int k0) {
    if constexpr (BF32) {
#pragma unroll
      for (int c = 0; c < 8; ++c) {
        int id = c * 256 + tid;
        int row = id >> 4, kc = (id & 15) << 2;
        int gr = n0 + row; if (gr > N - 1) gr = N - 1;
        bF[c] = *(const float4*)&Bf[(size_t)gr * ldb + k0 + kc];
      }
    } else {
#pragma unroll
      for (int c = 0; c < 4; ++c) {
        int id = c * 256 + tid;
        int row = id >> 3, kc = (id & 7) << 3;
        int gr = n0 + row; if (gr > N - 1) gr = N - 1;
        bR[c] = *(const uint4*)&Bb[(size_t)gr * ldb + k0 + kc];
      }
    }
  };
  auto stage = [&]() {
#pragma unroll
    for (int c = 0; c < 4; ++c) {
      int id = c * 256 + tid;
      int row = id >> 3, kc = (id & 7) << 3;
      *(uint4*)&As[row * 64 + kc] = aR[c];
    }
    if constexpr (BF32) {
#pragma unroll
      for (int c = 0; c < 8; ++c) {
        int id = c * 256 + tid;
        int row = id >> 4, kc = (id & 15) << 2;
        *(uint2*)&Bs[row * 64 + kc] = make_uint2(pk2(bF[c].x, bF[c].y), pk2(bF[c].z, bF[c].w));
      }
    } else {
#pragma unroll
      for (int c = 0; c < 4; ++c) {
        int id = c * 256 + tid;
        int row = id >> 3, kc = (id & 7) << 3;
        *(uint4*)&Bs[row * 64 + kc] = bR[c];
      }
    }
  };

  loadA(0); loadB(0);
  for (int s = 0; s < nk; ++s) {
    __syncthreads();
    stage();
    __syncthreads();
    if (s + 1 < nk) { loadA((s + 1) << 6); loadB((s + 1) << 6); }
#pragma unroll
    for (int kk = 0; kk < 2; ++kk) {
      bf16x8 fa[4], fb[4];
#pragma unroll
      for (int mi = 0; mi < 4; ++mi)
        fa[mi] = *(const bf16x8*)&As[(wm * 64 + mi * 16 + lr) * 64 + kk * 32 + lg * 8];
#pragma unroll
      for (int ni = 0; ni < 4; ++ni)
        fb[ni] = *(const bf16x8*)&Bs[(wn * 64 + ni * 16 + lr) * 64 + kk * 32 + lg * 8];
#pragma unroll
      for (int mi = 0; mi < 4; ++mi)
#pragma unroll
        for (int ni = 0; ni < 4; ++ni)
          acc[mi][ni] = __builtin_amdgcn_mfma_f32_16x16x32_bf16(fa[mi], fb[ni], acc[mi][ni], 0, 0, 0);
    }
  }

#pragma unroll
  for (int mi = 0; mi < 4; ++mi)
#pragma unroll
    for (int ni = 0; ni < 4; ++ni) {
      int col = n0 + wn * 64 + ni * 16 + lr;
#pragma unroll
      for (int j = 0; j < 4; ++j) {
        int row = m0 + wm * 64 + mi * 16 + lg * 4 + j;
        float v = acc[mi][ni][j];
        if constexpr (EPI == 0) {
          Cf[(size_t)row * ldc + col] = v * alpha;
        } else {  // EPI == 3: even col = g, odd col = u; pack 2 outputs per u32
          float p = __shfl_xor(v, 1);
          float a = v * sigm(v) * p;          // valid on even lr
          float a2 = __shfl_xor(a, 2);        // neighbor pair's value
          if ((lr & 3) == 0)
            *(u32*)&Cb[(size_t)row * DFF + (col >> 1)] = pk2(a, a2);
        }
      }
    }
}

// ---------------------------------------------------------------------------
// Vocab chunk GEMM: pad[2048, VPAD_LD] = A[2048,1024] x B[nbase..]^T
// All output stores are 16-B aligned float4 (ld = 3072). LDS-staged epilogue.
// ---------------------------------------------------------------------------
__global__ __launch_bounds__(256, 2) void k_gemm_pad(
    const u16* __restrict__ A, const u16* __restrict__ B,
    float* __restrict__ pad, int nbase)
{
  __shared__ __align__(16) char smem[32768];
  u16* As = (u16*)smem;
  u16* Bs = (u16*)(smem + 16384);
  float* eps = (float*)smem;

  const int tid = threadIdx.x;
  const int m0 = blockIdx.x * 128;
  const int n0l = blockIdx.y * 128;

  const int l = tid & 63;
  const int wv = tid >> 6;
  const int wm = wv >> 1, wn = wv & 1;
  const int lr = l & 15, lg = l >> 4;

  uint4 aR[4], bR[4];
  f32x4 acc[4][4] = {};

  auto loadAB = [&](int k0) {
#pragma unroll
    for (int c = 0; c < 4; ++c) {
      int id = c * 256 + tid;
      int row = id >> 3, kc = (id & 7) << 3;
      aR[c] = *(const uint4*)&A[(size_t)(m0 + row) * DMODEL + k0 + kc];
      int gr = nbase + n0l + row; if (gr > NVOCAB - 1) gr = NVOCAB - 1;
      bR[c] = *(const uint4*)&B[(size_t)gr * DMODEL + k0 + kc];
    }
  };
  auto stage = [&]() {
#pragma unroll
    for (int c = 0; c < 4; ++c) {
      int id = c * 256 + tid;
      int row = id >> 3, kc = (id & 7) << 3;
      *(uint4*)&As[row * 64 + kc] = aR[c];
      *(uint4*)&Bs[row * 64 + kc] = bR[c];
    }
  };

  loadAB(0);
  for (int s = 0; s < 16; ++s) {
    __syncthreads();
    stage();
    __syncthreads();
    if (s + 1 < 16) loadAB((s + 1) << 6);
#pragma unroll
    for (int kk = 0; kk < 2; ++kk) {
      bf16x8 fa[4], fb[4];
#pragma unroll
      for (int mi = 0; mi < 4; ++mi)
        fa[mi] = *(const bf16x8*)&As[(wm * 64 + mi * 16 + lr) * 64 + kk * 32 + lg * 8];
#pragma unroll
      for (int ni = 0; ni < 4; ++ni)
        fb[ni] = *(const bf16x8*)&Bs[(wn * 64 + ni * 16 + lr) * 64 + kk * 32 + lg * 8];
#pragma unroll
      for (int mi = 0; mi < 4; ++mi)
#pragma unroll
        for (int ni = 0; ni < 4; ++ni)
          acc[mi][ni] = __builtin_amdgcn_mfma_f32_16x16x32_bf16(fa[mi], fb[ni], acc[mi][ni], 0, 0, 0);
    }
  }

#pragma unroll
  for (int mi = 0; mi < 4; ++mi) {
    __syncthreads();
#pragma unroll
    for (int ni = 0; ni < 4; ++ni) {
      int lcol = wn * 64 + ni * 16 + lr;
#pragma unroll
      for (int j = 0; j < 4; ++j)
        eps[(wm * 16 + lg * 4 + j) * 132 + lcol] = acc[mi][ni][j];
    }
    __syncthreads();
    int lrow = tid >> 3, c0e = (tid & 7) << 4;
    int grow = m0 + (lrow >> 4) * 64 + mi * 16 + (lrow & 15);
    const float4* rp = (const float4*)&eps[lrow * 132 + c0e];
    float* dst = &pad[(size_t)grow * VPAD_LD + n0l + c0e];
#pragma unroll
    for (int q = 0; q < 4; ++q)
      *(float4*)&dst[q * 4] = rp[q];
  }
}

// ---------------------------------------------------------------------------
// Streaming row copy: pad[row][0:cols] -> out[row][c0:c0+cols]
// One wave per row; head/body/tail so body stores are 16-B aligned on dst.
// ---------------------------------------------------------------------------
__global__ __launch_bounds__(256) void k_copy_rows(
    const float* __restrict__ pad, float* __restrict__ out, int cols, int c0)
{
  int wid = (blockIdx.x * 256 + threadIdx.x) >> 6;  // row
  int l = threadIdx.x & 63;
  if (wid >= MTOK) return;
  const float* s = pad + (size_t)wid * VPAD_LD;
  float* d = out + (size_t)wid * NVOCAB + c0;
  int head = (int)((16 - (((size_t)d) & 15)) & 15) >> 2;  // dwords until aligned
  if (head > cols) head = cols;
  if (l < head) d[l] = s[l];
  int nb = (cols - head) >> 2;          // aligned float4 count
  const float* sb = s + head;
  float* db = d + head;
  for (int i = l; i < nb; i += 64) {
    f4u v = *(const f4u*)&sb[i * 4];
    *(float4*)&db[i * 4] = make_float4(v.x, v.y, v.z, v.w);
  }
  int t0 = head + nb * 4;
  int rem = cols - t0;
  if (l < rem) d[t0 + l] = s[t0 + l];
}

// ---------------------------------------------------------------------------
// 64x64 GEMM (NT), bf16 B. EPI: 0 = Cf = acc; 1 = residual r = Cf+acc,
// Cf = r, Cb = bf16(r).
// ---------------------------------------------------------------------------
template<int EPI>
__global__ __launch_bounds__(256, 3) void k_gemm64(
    const u16* __restrict__ A, const u16* __restrict__ B,
    float* __restrict__ Cf, u16* __restrict__ Cb,
    int K, int lda, int ldb, int ldc)
{
  __shared__ __align__(16) u16 As[64 * 64];
  __shared__ __align__(16) u16 Bs[64 * 64];
  const int tid = threadIdx.x;
  const int m0 = blockIdx.x * 64;
  const int n0 = blockIdx.y * 64;
  const int l = tid & 63;
  const int wv = tid >> 6;
  const int wm = wv >> 1, wn = wv & 1;
  const int lr = l & 15, lg = l >> 4;

  uint4 aR[2], bR[2];
  f32x4 acc[2][2] = {};
  const int nk = K >> 6;

  auto loadAB = [&](int k0) {
#pragma unroll
    for (int c = 0; c < 2; ++c) {
      int id = c * 256 + tid;
      int row = id >> 3, kc = (id & 7) << 3;
      aR[c] = *(const uint4*)&A[(size_t)(m0 + row) * lda + k0 + kc];
      bR[c] = *(const uint4*)&B[(size_t)(n0 + row) * ldb + k0 + kc];
    }
  };
  auto stage = [&]() {
#pragma unroll
    for (int c = 0; c < 2; ++c) {
      int id = c * 256 + tid;
      int row = id >> 3, kc = (id & 7) << 3;
      *(uint4*)&As[row * 64 + kc] = aR[c];
      *(uint4*)&Bs[row * 64 + kc] = bR[c];
    }
  };

  loadAB(0);
  for (int s = 0; s < nk; ++s) {
    __syncthreads();
    stage();
    __syncthreads();
    if (s + 1 < nk) loadAB((s + 1) << 6);
#pragma unroll
    for (int kk = 0; kk < 2; ++kk) {
      bf16x8 fa[2], fb[2];
#pragma unroll
      for (int mi = 0; mi < 2; ++mi)
        fa[mi] = *(const bf16x8*)&As[(wm * 32 + mi * 16 + lr) * 64 + kk * 32 + lg * 8];
#pragma unroll
      for (int ni = 0; ni < 2; ++ni)
        fb[ni] = *(const bf16x8*)&Bs[(wn * 32 + ni * 16 + lr) * 64 + kk * 32 + lg * 8];
#pragma unroll
      for (int mi = 0; mi < 2; ++mi)
#pragma unroll
        for (int ni = 0; ni < 2; ++ni)
          acc[mi][ni] = __builtin_amdgcn_mfma_f32_16x16x32_bf16(fa[mi], fb[ni], acc[mi][ni], 0, 0, 0);
    }
  }

#pragma unroll
  for (int mi = 0; mi < 2; ++mi)
#pragma unroll
    for (int ni = 0; ni < 2; ++ni) {
      int col = n0 + wn * 32 + ni * 16 + lr;
#pragma unroll
      for (int j = 0; j < 4; ++j) {
        int row = m0 + wm * 32 + mi * 16 + lg * 4 + j;
        size_t off = (size_t)row * ldc + col;
        float v = acc[mi][ni][j];
        if constexpr (EPI == 0) {
          Cf[off] = v;
        } else {
          float r = Cf[off] + v;
          Cf[off] = r;
          Cb[off] = f2bf(r);
        }
      }
    }
}

// ---------------------------------------------------------------------------
// Per-layer weight transpose+convert fp32 [R,C] -> bf16 [C,R] (Wg/Wu
// interleave into WguT: dst row = 2c / 2c+1)
// ---------------------------------------------------------------------------
__global__ void k_transpose_layer(
    const float* __restrict__ Wi, const float* __restrict__ Wo,
    const float* __restrict__ Wg, const float* __restrict__ Wu,
    const float* __restrict__ Wd,
    u16* __restrict__ WiT, u16* __restrict__ WoT,
    u16* __restrict__ WguT, u16* __restrict__ WdT)
{
  int bid = blockIdx.x;
  const float* src; u16* dst; int R, C, t0, mul, add;
  if (bid < 256)       { src = Wi; dst = WiT;  R = 1024; C = 256;  t0 = bid;        mul = 1; add = 0; }
  else if (bid < 512)  { src = Wo; dst = WoT;  R = 256;  C = 1024; t0 = bid - 256;  mul = 1; add = 0; }
  else if (bid < 4608) { src = Wg; dst = WguT; R = 1024; C = 4096; t0 = bid - 512;  mul = 2; add = 0; }
  else if (bid < 8704) { src = Wu; dst = WguT; R = 1024; C = 4096; t0 = bid - 4608; mul = 2; add = 1; }
  else                 { src = Wd; dst = WdT;  R = 4096; C = 1024; t0 = bid - 8704; mul = 1; add = 0; }
  int tC = C >> 5;
  int r0 = (t0 / tC) << 5, c0 = (t0 % tC) << 5;
  __shared__ float tile[32][33];
  int ty = threadIdx.x >> 3;
  int tx = (threadIdx.x & 7) << 2;
  float4 v = *(const float4*)&src[(size_t)(r0 + ty) * C + c0 + tx];
  tile[ty][tx] = v.x; tile[ty][tx + 1] = v.y; tile[ty][tx + 2] = v.z; tile[ty][tx + 3] = v.w;
  __syncthreads();
  float a = tile[tx][ty], b = tile[tx + 1][ty], c = tile[tx + 2][ty], d = tile[tx + 3][ty];
  *(uint2*)&dst[((size_t)(c0 + ty) * mul + add) * R + r0 + tx] = make_uint2(pk2(a, b), pk2(c, d));
}

// fp32 -> bf16 flat convert (n8 = count of 8-element groups)
__global__ void k_f2bf(const float* __restrict__ src, u16* __restrict__ dst, int n8)
{
  int i = blockIdx.x * 256 + threadIdx.x;
  if (i >= n8) return;
  const float4* s = (const float4*)(src + (size_t)i * 8);
  float4 a = s[0], b = s[1];
  *(uint4*)(dst + (size_t)i * 8) =
      make_uint4(pk2(a.x, a.y), pk2(a.z, a.w), pk2(b.x, b.y), pk2(b.z, b.w));
}

__global__ void k_embed_norm(const int* __restrict__ tok, const float* __restrict__ emb,
                             const float* __restrict__ w, float* __restrict__ xf,
                             u16* __restrict__ xb)
{
  int row = blockIdx.x;
  int t = tok[row];
  float4 v = ((const float4*)(emb + (size_t)t * DMODEL))[threadIdx.x];
  float tot = blockReduceSum(v.x * v.x + v.y * v.y + v.z * v.z + v.w * v.w);
  float inv = rsqrtf(tot * (1.0f / DMODEL) + 1e-6f);
  int d0 = threadIdx.x << 2;
  float4 wv = *(const float4*)(w + d0);
  float4 o;
  o.x = v.x * inv * wv.x; o.y = v.y * inv * wv.y;
  o.z = v.z * inv * wv.z; o.w = v.w * inv * wv.w;
  *(float4*)(xf + (size_t)row * DMODEL + d0) = o;
  *(uint2*)(xb + (size_t)row * DMODEL + d0) = make_uint2(pk2(o.x, o.y), pk2(o.z, o.w));
}

__global__ __launch_bounds__(256) void k_topk(const float* __restrict__ scores,
                                              float* __restrict__ wout, int* __restrict__ iout)
{
  int row = blockIdx.x * 4 + (threadIdx.x >> 6);
  int l = threadIdx.x & 63;
  const float* s = scores + (size_t)row * NCELL;
  float v[8]; int ix[8];
#pragma unroll
  for (int i = 0; i < 8; ++i) { v[i] = -3.4e38f; ix[i] = 0x7fffffff; }
  for (int j = 0; j < 64; ++j) {
    float x = s[j * 64 + l];
    if (x > v[7]) {
      v[7] = x; ix[7] = j * 64 + l;
#pragma unroll
      for (int q = 7; q > 0; --q) {
        if (v[q] > v[q - 1]) {
          float tv = v[q]; v[q] = v[q - 1]; v[q - 1] = tv;
          int tt = ix[q]; ix[q] = ix[q - 1]; ix[q - 1] = tt;
        }
      }
    }
  }
  float ov[8]; int oi[8];
#pragma unroll
  for (int r = 0; r < 8; ++r) {
    float bv = v[0]; int bi = ix[0];
#pragma unroll
    for (int o = 32; o > 0; o >>= 1) {
      float tv = __shfl_xor(bv, o);
      int tb = __shfl_xor(bi, o);
      if (tv > bv || (tv == bv && tb < bi)) { bv = tv; bi = tb; }
    }
    ov[r] = bv; oi[r] = bi;
    if (bi == ix[0]) {
#pragma unroll
      for (int q = 0; q < 7; ++q) { v[q] = v[q + 1]; ix[q] = ix[q + 1]; }
      v[7] = -3.4e38f; ix[7] = 0x7fffffff;
    }
  }
  if (l == 0) {
    float m = ov[0], sum = 0.f, e[8];
#pragma unroll
    for (int r = 0; r < 8; ++r) { e[r] = __expf(ov[r] - m); sum += e[r]; }
    float inv = 1.0f / sum;
#pragma unroll
    for (int r = 0; r < 8; ++r) {
      wout[(size_t)row * 8 + r] = e[r] * inv;
      iout[(size_t)row * 8 + r] = oi[r];
    }
  }
}

__global__ void k_readout(const float* __restrict__ cells, const int* __restrict__ ti,
                          const float* __restrict__ tw, const float* __restrict__ xin,
                          u16* __restrict__ rb)
{
  int row = blockIdx.x, d = threadIdx.x;
  float acc = xin[(size_t)row * DCELL + d];
#pragma unroll
  for (int k = 0; k < 8; ++k) {
    int ci = ti[row * 8 + k];
    float wk = tw[row * 8 + k];
    acc += wk * cells[(size_t)ci * DCELL + d];
  }
  rb[(size_t)row * DCELL + d] = f2bf(acc);
}

// Chunked decay scan: pass A computes per-chunk end states E[b][c][d]
__global__ void k_scan_a(const float* __restrict__ x, float* __restrict__ E,
                         const float* __restrict__ sgw, const float* __restrict__ sgb,
                         const float* __restrict__ sdec)
{
  int tid = blockIdx.x * 256 + threadIdx.x;   // 32768 = 8b * 4c * 1024d
  int d = tid & 1023, bc = tid >> 10;
  int b = bc >> 2, c = bc & 3;
  float dec = sigm(sdec[0]);
  dec = fminf(fmaxf(dec, 0.01f), 0.99f);
  float gw = sgw[d], gb = sgb[d];
  size_t base = ((size_t)b * 256 + c * 64) * DMODEL + d;
  float h = 0.f;
  for (int t = 0; t < 64; ++t) {
    float xv = x[base + (size_t)t * DMODEL];
    h = h * dec + sigm(xv * gw + gb) * xv;
  }
  E[tid] = h;
}

// pass B: combine carries, write pre = x + cs*co + sc*h
__global__ void k_scan_b(const float* __restrict__ x, const float* __restrict__ co,
                         const float* __restrict__ E, float* __restrict__ pre,
                         const float* __restrict__ sgw, const float* __restrict__ sgb,
                         const float* __restrict__ ssc, const float* __restrict__ sdec,
                         const float* __restrict__ csc)
{
  int tid = blockIdx.x * 256 + threadIdx.x;
  int d = tid & 1023, bc = tid >> 10;
  int b = bc >> 2, c = bc & 3;
  float dec = sigm(sdec[0]);
  dec = fminf(fmaxf(dec, 0.01f), 0.99f);
  float d2 = dec * dec, d4 = d2 * d2, d8 = d4 * d4, d16 = d8 * d8, d32 = d16 * d16;
  float d64 = d32 * d32;
  float cs = csc[0];
  float gw = sgw[d], gb = sgb[d], sc = ssc[d];
  float h = 0.f;
  for (int cc = 0; cc < c; ++cc) h = h * d64 + E[((b << 2) + cc) * 1024 + d];
  size_t base = ((size_t)b * 256 + c * 64) * DMODEL + d;
  for (int t = 0; t < 64; ++t) {
    size_t o = base + (size_t)t * DMODEL;
    float xv = x[o];
    float g = sigm(xv * gw + gb);
    h = h * dec + g * xv;
    pre[o] = xv + cs * co[o] + h * sc;
  }
}

__global__ void k_norm2(const float* __restrict__ pre, const float* __restrict__ nw,
                        const float* __restrict__ fw, float* __restrict__ xf,
                        u16* __restrict__ h2b)
{
  int row = blockIdx.x;
  float4 v = ((const float4*)(pre + (size_t)row * DMODEL))[threadIdx.x];
  float tot = blockReduceSum(v.x * v.x + v.y * v.y + v.z * v.z + v.w * v.w);
  float inv = rsqrtf(tot * (1.0f / DMODEL) + 1e-6f);
  int d0 = threadIdx.x << 2;
  float4 wv = *(const float4*)(nw + d0);
  float4 x1;
  x1.x = v.x * inv * wv.x; x1.y = v.y * inv * wv.y;
  x1.z = v.z * inv * wv.z; x1.w = v.w * inv * wv.w;
  *(float4*)(xf + (size_t)row * DMODEL + d0) = x1;
  float tot2 = blockReduceSum(x1.x * x1.x + x1.y * x1.y + x1.z * x1.z + x1.w * x1.w);
  float inv2 = rsqrtf(tot2 * (1.0f / DMODEL) + 1e-6f);
  float4 fv = *(const float4*)(fw + d0);
  *(uint2*)(h2b + (size_t)row * DMODEL + d0) =
      make_uint2(pk2(x1.x * inv2 * fv.x, x1.y * inv2 * fv.y),
                 pk2(x1.z * inv2 * fv.z, x1.w * inv2 * fv.w));
}

__global__ void k_norm_bf(const float* __restrict__ in, const float* __restrict__ w,
                          u16* __restrict__ ob)
{
  int row = blockIdx.x;
  float4 v = ((const float4*)(in + (size_t)row * DMODEL))[threadIdx.x];
  float tot = blockReduceSum(v.x * v.x + v.y * v.y + v.z * v.z + v.w * v.w);
  float inv = rsqrtf(tot * (1.0f / DMODEL) + 1e-6f);
  int d0 = threadIdx.x << 2;
  float4 wv = *(const float4*)(w + d0);
  *(uint2*)(ob + (size_t)row * DMODEL + d0) =
      make_uint2(pk2(v.x * inv * wv.x, v.y * inv * wv.y),
                 pk2(v.z * inv * wv.z, v.w * inv * wv.w));
}

// ---------------------------------------------------------------------------
extern "C" void kernel_launch(void* const* d_in, const int* in_sizes, int n_in,
                              void* d_out, int out_size, void* d_ws, size_t ws_size,
                              hipStream_t stream)
{
  const int*   tokens  = (const int*)d_in[0];
  const float* embed   = (const float*)d_in[1];
  const float* ln_in_w = (const float*)d_in[2];
  const float* ln_out_w= (const float*)d_in[3];
  const float* W_route = (const float*)d_in[4];
  const float* cells   = (const float*)d_in[5];
  const float* W_in    = (const float*)d_in[6];
  const float* W_out   = (const float*)d_in[7];
  const float* sdec    = (const float*)d_in[8];
  const float* sgw     = (const float*)d_in[9];
  const float* sgb     = (const float*)d_in[10];
  const float* ssc     = (const float*)d_in[11];
  const float* csc     = (const float*)d_in[12];
  const float* Wg      = (const float*)d_in[13];
  const float* Wu      = (const float*)d_in[14];
  const float* Wd      = (const float*)d_in[15];
  const float* ffw     = (const float*)d_in[16];
  const float* nrw     = (const float*)d_in[17];
  float* out = (float*)d_out;
  (void)in_sizes; (void)n_in; (void)out_size; (void)ws_size;

  char* ws = (char*)d_ws;
  size_t off = 0;
  auto alloc = [&](size_t bytes) -> void* {
    void* p = ws + off;
    off += (bytes + 255) & ~(size_t)255;
    return p;
  };

  // ---- epoch 1 (layer loop scratch) ----
  float* scores = (float*)alloc((size_t)MTOK * NCELL * 4);
  u16*  act_bf  = (u16*)alloc((size_t)MTOK * DFF * 2);      // aliased with s_pre
  float* s_pre  = (float*)act_bf;
  float* x_f    = (float*)alloc((size_t)MTOK * DMODEL * 4);
  u16*  x_bf    = (u16*)alloc((size_t)MTOK * DMODEL * 2);
  u16*  h2_bf   = (u16*)alloc((size_t)MTOK * DMODEL * 2);
  float* tw     = (float*)alloc((size_t)MTOK * 8 * 4);
  int*  ti      = (int*)alloc((size_t)MTOK * 8 * 4);
  float* xin    = (float*)alloc((size_t)MTOK * DCELL * 4);
  u16*  r_bf    = (u16*)alloc((size_t)MTOK * DCELL * 2);
  float* cellout= (float*)alloc((size_t)MTOK * DMODEL * 4);
  u16*  WiT     = (u16*)alloc((size_t)DCELL * DMODEL * 2);
  u16*  WoT     = (u16*)alloc((size_t)DMODEL * DCELL * 2);
  u16*  WguT    = (u16*)alloc((size_t)8192 * DMODEL * 2);
  u16*  WdT     = (u16*)alloc((size_t)DMODEL * DFF * 2);
  float* E      = (float*)alloc((size_t)32768 * 4);
  // ---- persistent tail (above embed_bf's 103 MB span) ----
  if (off < ((size_t)108 << 20)) off = (size_t)108 << 20;
  u16*  xf_bf   = (u16*)alloc((size_t)MTOK * DMODEL * 2);
  float* vpad   = (float*)alloc((size_t)MTOK * VPAD_LD * 4);   // 25.2 MB
  // ---- epoch 2 overlay (written only after layer loop) ----
  u16*  embed_bf = (u16*)ws;   // 102.9 MB, overlays dead epoch-1 scratch

  k_embed_norm<<<MTOK, 256, 0, stream>>>(tokens, embed, ln_in_w, x_f, x_bf);

  for (int lay = 0; lay < 8; ++lay) {
    const float* Wi_l = W_in  + (size_t)lay * DMODEL * DCELL;
    const float* Wo_l = W_out + (size_t)lay * DCELL * DMODEL;
    const float* Wg_l = Wg    + (size_t)lay * DMODEL * DFF;
    const float* Wu_l = Wu    + (size_t)lay * DMODEL * DFF;
    const float* Wd_l = Wd    + (size_t)lay * DFF * DMODEL;
    const float* Wr_l = W_route + (size_t)lay * NCELL * DMODEL;
    const float* cells_l = cells + (size_t)lay * NCELL * DCELL;

    k_transpose_layer<<<12800, 256, 0, stream>>>(Wi_l, Wo_l, Wg_l, Wu_l, Wd_l,
                                                 WiT, WoT, WguT, WdT);
    // scores = x @ Wr^T / 32   (512 blocks = 16 Mblk x 32 panels, XCD-swizzled)
    k_gemm<1, 0><<<512, 256, 0, stream>>>(x_bf, Wr_l, scores, nullptr,
        NCELL, DMODEL, DMODEL, DMODEL, NCELL, 0.03125f);
    k_topk<<<512, 256, 0, stream>>>(scores, tw, ti);
    // x_in = x @ W_in
    k_gemm64<0><<<dim3(32, 4), 256, 0, stream>>>(x_bf, WiT, xin, nullptr,
        DMODEL, DMODEL, DMODEL, DCELL);
    k_readout<<<MTOK, 256, 0, stream>>>(cells_l, ti, tw, xin, r_bf);
    // cell_out = (readout + x_in) @ W_out
    k_gemm64<0><<<dim3(32, 16), 256, 0, stream>>>(r_bf, WoT, cellout, nullptr,
        DCELL, DCELL, DCELL, DMODEL);
    k_scan_a<<<128, 256, 0, stream>>>(x_f, E, sgw + lay * DMODEL,
        sgb + lay * DMODEL, sdec + lay);
    k_scan_b<<<128, 256, 0, stream>>>(x_f, cellout, E, s_pre, sgw + lay * DMODEL,
        sgb + lay * DMODEL, ssc + lay * DMODEL, sdec + lay, csc + lay);
    k_norm2<<<MTOK, 256, 0, stream>>>(s_pre, nrw + lay * DMODEL, ffw + lay * DMODEL,
        x_f, h2_bf);
    // act = silu(g)*u fused in epilogue (1024 blocks = 16 x 64 panels, swizzled)
    k_gemm<0, 3><<<1024, 256, 0, stream>>>(h2_bf, WguT, nullptr, act_bf,
        8192, DMODEL, DMODEL, DMODEL, 8192, 1.0f);
    // x = x + act @ Wd
    k_gemm64<1><<<dim3(32, 16), 256, 0, stream>>>(act_bf, WdT, x_f, x_bf,
        DFF, DFF, DFF, DMODEL);
  }

  k_norm_bf<<<MTOK, 256, 0, stream>>>(x_f, ln_out_w, xf_bf);
  // embed -> bf16 (overlays dead layer scratch)
  k_f2bf<<<(NVOCAB * (DMODEL / 8) + 255) / 256, 256, 0, stream>>>(
      embed, embed_bf, NVOCAB * (DMODEL / 8));
  // logits via aligned pad chunks + streaming copy
  for (int c = 0; c * VCHUNK < NVOCAB; ++c) {
    int nbase = c * VCHUNK;
    int cols = NVOCAB - nbase; if (cols > VCHUNK) cols = VCHUNK;
    int panels = (cols + 127) >> 7;
    k_gemm_pad<<<dim3(16, panels), 256, 0, stream>>>(xf_bf, embed_bf, vpad, nbase);
    k_copy_rows<<<512, 256, 0, stream>>>(vpad, out, cols, nbase);
  }
}

// Round 7
// 4790.761 us; speedup vs baseline: 1.2357x; 1.2357x over previous
//
#include <hip/hip_runtime.h>
#include <stdint.h>

typedef __attribute__((ext_vector_type(8))) short bf16x8;
typedef __attribute__((ext_vector_type(4))) float f32x4;
typedef unsigned short u16;
typedef unsigned int u32;

#define MTOK 2048
#define DMODEL 1024
#define NCELL 4096
#define DCELL 256
#define DFF 4096
#define NVOCAB 50257
#define VPAD_LD 50304          // 393 * 128, aligned pad leading dim

struct __attribute__((packed, aligned(4))) f4u { float x, y, z, w; };

static __device__ __forceinline__ u16 f2bf(float f) {
  u32 u = __builtin_bit_cast(u32, f);
  u = (u + 0x7FFFu + ((u >> 16) & 1u)) >> 16;
  return (u16)u;
}
static __device__ __forceinline__ u32 pk2(float a, float b) {
  return (u32)f2bf(a) | ((u32)f2bf(b) << 16);
}
static __device__ __forceinline__ float sigm(float x) { return 1.0f / (1.0f + __expf(-x)); }

// async global->LDS, 16 B per lane; lds dest = wave-uniform base + lane*16
static __device__ __forceinline__ void glds16(const void* g, void* l) {
  __builtin_amdgcn_global_load_lds(
      (const __attribute__((address_space(1))) void*)g,
      (__attribute__((address_space(3))) void*)l, 16, 0, 0);
}

static __device__ __forceinline__ float blockReduceSum(float v) {
#pragma unroll
  for (int o = 32; o > 0; o >>= 1) v += __shfl_xor(v, o);
  __shared__ float sm[4];
  __syncthreads();
  if ((threadIdx.x & 63) == 0) sm[threadIdx.x >> 6] = v;
  __syncthreads();
  return sm[0] + sm[1] + sm[2] + sm[3];
}

// ---------------------------------------------------------------------------
// 128x128 GEMM (NT): C[2048,N] = A[2048,K](bf16) x B[N,K]^T
// 1D grid, XCD-affine swizzle. EPI: 0 = Cf = alpha*acc
//   3 = fused SwiGLU (B cols interleaved even=g odd=u) -> bf16 Cb, packed u32
// ---------------------------------------------------------------------------
template<int BF32, int EPI>
__global__ __launch_bounds__(256, 2) void k_gemm(
    const u16* __restrict__ A, const void* __restrict__ Bv,
    float* __restrict__ Cf, u16* __restrict__ Cb,
    int N, int K, int lda, int ldb, int ldc, float alpha)
{
  __shared__ __align__(16) u16 As[128 * 64];
  __shared__ __align__(16) u16 Bs[128 * 64];
  const int tid = threadIdx.x;
  const int T = gridDim.x;
  const int bid = blockIdx.x;
  const int w = (bid & 7) * (T >> 3) + (bid >> 3);
  const int m0 = (w & 15) * 128;
  const int n0 = (w >> 4) * 128;
  const int l = tid & 63;
  const int wv = tid >> 6;
  const int wm = wv >> 1, wn = wv & 1;
  const int lr = l & 15, lg = l >> 4;

  const u16* Bb = (const u16*)Bv;
  const float* Bf = (const float*)Bv;

  uint4 aR[4];
  uint4 bR[4];
  float4 bF[8];
  f32x4 acc[4][4] = {};
  const int nk = K >> 6;

  auto loadA = [&](int k0) {
#pragma unroll
    for (int c = 0; c < 4; ++c) {
      int id = c * 256 + tid;
      int row = id >> 3, kc = (id & 7) << 3;
      aR[c] = *(const uint4*)&A[(size_t)(m0 + row) * lda + k0 + kc];
    }
  };
  auto loadB = [&](int k0) {
    if constexpr (BF32) {
#pragma unroll
      for (int c = 0; c < 8; ++c) {
        int id = c * 256 + tid;
        int row = id >> 4, kc = (id & 15) << 2;
        int gr = n0 + row; if (gr > N - 1) gr = N - 1;
        bF[c] = *(const float4*)&Bf[(size_t)gr * ldb + k0 + kc];
      }
    } else {
#pragma unroll
      for (int c = 0; c < 4; ++c) {
        int id = c * 256 + tid;
        int row = id >> 3, kc = (id & 7) << 3;
        int gr = n0 + row; if (gr > N - 1) gr = N - 1;
        bR[c] = *(const uint4*)&Bb[(size_t)gr * ldb + k0 + kc];
      }
    }
  };
  auto stage = [&]() {
#pragma unroll
    for (int c = 0; c < 4; ++c) {
      int id = c * 256 + tid;
      int row = id >> 3, kc = (id & 7) << 3;
      *(uint4*)&As[row * 64 + kc] = aR[c];
    }
    if constexpr (BF32) {
#pragma unroll
      for (int c = 0; c < 8; ++c) {
        int id = c * 256 + tid;
        int row = id >> 4, kc = (id & 15) << 2;
        *(uint2*)&Bs[row * 64 + kc] = make_uint2(pk2(bF[c].x, bF[c].y), pk2(bF[c].z, bF[c].w));
      }
    } else {
#pragma unroll
      for (int c = 0; c < 4; ++c) {
        int id = c * 256 + tid;
        int row = id >> 3, kc = (id & 7) << 3;
        *(uint4*)&Bs[row * 64 + kc] = bR[c];
      }
    }
  };

  loadA(0); loadB(0);
  for (int s = 0; s < nk; ++s) {
    __syncthreads();
    stage();
    __syncthreads();
    if (s + 1 < nk) { loadA((s + 1) << 6); loadB((s + 1) << 6); }
#pragma unroll
    for (int kk = 0; kk < 2; ++kk) {
      bf16x8 fa[4], fb[4];
#pragma unroll
      for (int mi = 0; mi < 4; ++mi)
        fa[mi] = *(const bf16x8*)&As[(wm * 64 + mi * 16 + lr) * 64 + kk * 32 + lg * 8];
#pragma unroll
      for (int ni = 0; ni < 4; ++ni)
        fb[ni] = *(const bf16x8*)&Bs[(wn * 64 + ni * 16 + lr) * 64 + kk * 32 + lg * 8];
#pragma unroll
      for (int mi = 0; mi < 4; ++mi)
#pragma unroll
        for (int ni = 0; ni < 4; ++ni)
          acc[mi][ni] = __builtin_amdgcn_mfma_f32_16x16x32_bf16(fa[mi], fb[ni], acc[mi][ni], 0, 0, 0);
    }
  }

#pragma unroll
  for (int mi = 0; mi < 4; ++mi)
#pragma unroll
    for (int ni = 0; ni < 4; ++ni) {
      int col = n0 + wn * 64 + ni * 16 + lr;
#pragma unroll
      for (int j = 0; j < 4; ++j) {
        int row = m0 + wm * 64 + mi * 16 + lg * 4 + j;
        float v = acc[mi][ni][j];
        if constexpr (EPI == 0) {
          Cf[(size_t)row * ldc + col] = v * alpha;
        } else {  // EPI == 3: even col = g, odd col = u; pack 2 outputs per u32
          float p = __shfl_xor(v, 1);
          float a = v * sigm(v) * p;          // valid on even lr
          float a2 = __shfl_xor(a, 2);        // neighbor pair's value
          if ((lr & 3) == 0)
            *(u32*)&Cb[(size_t)row * DFF + (col >> 1)] = pk2(a, a2);
        }
      }
    }
}

// ---------------------------------------------------------------------------
// Vocab GEMM v2 with global_load_lds staging (m97 structure).
// C[2048, *] = A[2048,1024](bf16) x B[50257,1024]^T (bf16)
// 1D grid 6288 = 16 m-blocks x 393 panels, XCD-affine swizzle.
// PAD=1: unpredicated f32 stores to pad (ld = VPAD_LD, aligned).
// PAD=0: predicated stores to out (ld = NVOCAB, misaligned fallback).
// ---------------------------------------------------------------------------
template<int PAD>
__global__ __launch_bounds__(256, 2) void k_gemm_v2(
    const u16* __restrict__ A, const u16* __restrict__ B,
    float* __restrict__ Cf)
{
  __shared__ __align__(16) u16 As[128 * 64];
  __shared__ __align__(16) u16 Bs[128 * 64];
  const int tid = threadIdx.x;
  const int T = gridDim.x;
  const int bid = blockIdx.x;
  const int w = (bid & 7) * (T >> 3) + (bid >> 3);
  const int m0 = (w & 15) * 128;
  const int n0 = (w >> 4) * 128;
  const int l = tid & 63;
  const int wv = tid >> 6;
  const int wm = wv >> 1, wn = wv & 1;
  const int lr = l & 15, lg = l >> 4;
  const int wbase = tid & ~63;          // wave-uniform

  f32x4 acc[4][4] = {};

  const int row_ = tid >> 3;            // 0..31 within chunk
  const int kc_ = (tid & 7) << 3;

  for (int s = 0; s < 16; ++s) {
    const int k0 = s << 6;
    // issue 4 A-chunks + 4 B-chunks of global_load_lds (16 B/lane)
#pragma unroll
    for (int c = 0; c < 4; ++c) {
      int row = c * 32 + row_;
      glds16(&A[(size_t)(m0 + row) * DMODEL + k0 + kc_],
             &As[(size_t)(c * 256 + wbase) * 8]);
    }
#pragma unroll
    for (int c = 0; c < 4; ++c) {
      int row = c * 32 + row_;
      int gr = n0 + row; if (gr > NVOCAB - 1) gr = NVOCAB - 1;
      glds16(&B[(size_t)gr * DMODEL + k0 + kc_],
             &Bs[(size_t)(c * 256 + wbase) * 8]);
    }
    __syncthreads();    // vmcnt(0) drain + barrier
#pragma unroll
    for (int kk = 0; kk < 2; ++kk) {
      bf16x8 fa[4], fb[4];
#pragma unroll
      for (int mi = 0; mi < 4; ++mi)
        fa[mi] = *(const bf16x8*)&As[(wm * 64 + mi * 16 + lr) * 64 + kk * 32 + lg * 8];
#pragma unroll
      for (int ni = 0; ni < 4; ++ni)
        fb[ni] = *(const bf16x8*)&Bs[(wn * 64 + ni * 16 + lr) * 64 + kk * 32 + lg * 8];
#pragma unroll
      for (int mi = 0; mi < 4; ++mi)
#pragma unroll
        for (int ni = 0; ni < 4; ++ni)
          acc[mi][ni] = __builtin_amdgcn_mfma_f32_16x16x32_bf16(fa[mi], fb[ni], acc[mi][ni], 0, 0, 0);
    }
    __syncthreads();    // LDS reads done before next overwrite
  }

#pragma unroll
  for (int mi = 0; mi < 4; ++mi)
#pragma unroll
    for (int ni = 0; ni < 4; ++ni) {
      int col = n0 + wn * 64 + ni * 16 + lr;
#pragma unroll
      for (int j = 0; j < 4; ++j) {
        int row = m0 + wm * 64 + mi * 16 + lg * 4 + j;
        float v = acc[mi][ni][j];
        if constexpr (PAD) {
          Cf[(size_t)row * VPAD_LD + col] = v;
        } else {
          if (col < NVOCAB) Cf[(size_t)row * NVOCAB + col] = v;
        }
      }
    }
}

// Streaming copy pad[row][0:NVOCAB] -> out[row][*], one block per row.
__global__ __launch_bounds__(256) void k_copy_out(
    const float* __restrict__ pad, float* __restrict__ out)
{
  int row = blockIdx.x;
  const float* s = pad + (size_t)row * VPAD_LD;
  float* d = out + (size_t)row * NVOCAB;
  int t = threadIdx.x;
  int head = (int)((16 - (((size_t)d) & 15)) & 15) >> 2;
  if (t < head) d[t] = s[t];
  int nb = (NVOCAB - head) >> 2;
  const float* sb = s + head;
  float* db = d + head;
  for (int i = t; i < nb; i += 256) {
    f4u v = *(const f4u*)&sb[i * 4];
    *(float4*)&db[i * 4] = make_float4(v.x, v.y, v.z, v.w);
  }
  int t0 = head + nb * 4;
  int rem = NVOCAB - t0;
  if (t < rem) d[t0 + t] = s[t0 + t];
}

// ---------------------------------------------------------------------------
// 64x64 GEMM (NT), bf16 B. EPI: 0 = Cf = acc; 1 = residual r = Cf+acc,
// Cf = r, Cb = bf16(r).
// ---------------------------------------------------------------------------
template<int EPI>
__global__ __launch_bounds__(256, 3) void k_gemm64(
    const u16* __restrict__ A, const u16* __restrict__ B,
    float* __restrict__ Cf, u16* __restrict__ Cb,
    int K, int lda, int ldb, int ldc)
{
  __shared__ __align__(16) u16 As[64 * 64];
  __shared__ __align__(16) u16 Bs[64 * 64];
  const int tid = threadIdx.x;
  const int m0 = blockIdx.x * 64;
  const int n0 = blockIdx.y * 64;
  const int l = tid & 63;
  const int wv = tid >> 6;
  const int wm = wv >> 1, wn = wv & 1;
  const int lr = l & 15, lg = l >> 4;

  uint4 aR[2], bR[2];
  f32x4 acc[2][2] = {};
  const int nk = K >> 6;

  auto loadAB = [&](int k0) {
#pragma unroll
    for (int c = 0; c < 2; ++c) {
      int id = c * 256 + tid;
      int row = id >> 3, kc = (id & 7) << 3;
      aR[c] = *(const uint4*)&A[(size_t)(m0 + row) * lda + k0 + kc];
      bR[c] = *(const uint4*)&B[(size_t)(n0 + row) * ldb + k0 + kc];
    }
  };
  auto stage = [&]() {
#pragma unroll
    for (int c = 0; c < 2; ++c) {
      int id = c * 256 + tid;
      int row = id >> 3, kc = (id & 7) << 3;
      *(uint4*)&As[row * 64 + kc] = aR[c];
      *(uint4*)&Bs[row * 64 + kc] = bR[c];
    }
  };

  loadAB(0);
  for (int s = 0; s < nk; ++s) {
    __syncthreads();
    stage();
    __syncthreads();
    if (s + 1 < nk) loadAB((s + 1) << 6);
#pragma unroll
    for (int kk = 0; kk < 2; ++kk) {
      bf16x8 fa[2], fb[2];
#pragma unroll
      for (int mi = 0; mi < 2; ++mi)
        fa[mi] = *(const bf16x8*)&As[(wm * 32 + mi * 16 + lr) * 64 + kk * 32 + lg * 8];
#pragma unroll
      for (int ni = 0; ni < 2; ++ni)
        fb[ni] = *(const bf16x8*)&Bs[(wn * 32 + ni * 16 + lr) * 64 + kk * 32 + lg * 8];
#pragma unroll
      for (int mi = 0; mi < 2; ++mi)
#pragma unroll
        for (int ni = 0; ni < 2; ++ni)
          acc[mi][ni] = __builtin_amdgcn_mfma_f32_16x16x32_bf16(fa[mi], fb[ni], acc[mi][ni], 0, 0, 0);
    }
  }

#pragma unroll
  for (int mi = 0; mi < 2; ++mi)
#pragma unroll
    for (int ni = 0; ni < 2; ++ni) {
      int col = n0 + wn * 32 + ni * 16 + lr;
#pragma unroll
      for (int j = 0; j < 4; ++j) {
        int row = m0 + wm * 32 + mi * 16 + lg * 4 + j;
        size_t off = (size_t)row * ldc + col;
        float v = acc[mi][ni][j];
        if constexpr (EPI == 0) {
          Cf[off] = v;
        } else {
          float r = Cf[off] + v;
          Cf[off] = r;
          Cb[off] = f2bf(r);
        }
      }
    }
}

// ---------------------------------------------------------------------------
// Per-layer weight transpose+convert fp32 [R,C] -> bf16 [C,R] (Wg/Wu
// interleave into WguT: dst row = 2c / 2c+1)
// ---------------------------------------------------------------------------
__global__ void k_transpose_layer(
    const float* __restrict__ Wi, const float* __restrict__ Wo,
    const float* __restrict__ Wg, const float* __restrict__ Wu,
    const float* __restrict__ Wd,
    u16* __restrict__ WiT, u16* __restrict__ WoT,
    u16* __restrict__ WguT, u16* __restrict__ WdT)
{
  int bid = blockIdx.x;
  const float* src; u16* dst; int R, C, t0, mul, add;
  if (bid < 256)       { src = Wi; dst = WiT;  R = 1024; C = 256;  t0 = bid;        mul = 1; add = 0; }
  else if (bid < 512)  { src = Wo; dst = WoT;  R = 256;  C = 1024; t0 = bid - 256;  mul = 1; add = 0; }
  else if (bid < 4608) { src = Wg; dst = WguT; R = 1024; C = 4096; t0 = bid - 512;  mul = 2; add = 0; }
  else if (bid < 8704) { src = Wu; dst = WguT; R = 1024; C = 4096; t0 = bid - 4608; mul = 2; add = 1; }
  else                 { src = Wd; dst = WdT;  R = 4096; C = 1024; t0 = bid - 8704; mul = 1; add = 0; }
  int tC = C >> 5;
  int r0 = (t0 / tC) << 5, c0 = (t0 % tC) << 5;
  __shared__ float tile[32][33];
  int ty = threadIdx.x >> 3;
  int tx = (threadIdx.x & 7) << 2;
  float4 v = *(const float4*)&src[(size_t)(r0 + ty) * C + c0 + tx];
  tile[ty][tx] = v.x; tile[ty][tx + 1] = v.y; tile[ty][tx + 2] = v.z; tile[ty][tx + 3] = v.w;
  __syncthreads();
  float a = tile[tx][ty], b = tile[tx + 1][ty], c = tile[tx + 2][ty], d = tile[tx + 3][ty];
  *(uint2*)&dst[((size_t)(c0 + ty) * mul + add) * R + r0 + tx] = make_uint2(pk2(a, b), pk2(c, d));
}

// fp32 -> bf16 flat convert (n8 = count of 8-element groups)
__global__ void k_f2bf(const float* __restrict__ src, u16* __restrict__ dst, int n8)
{
  int i = blockIdx.x * 256 + threadIdx.x;
  if (i >= n8) return;
  const float4* s = (const float4*)(src + (size_t)i * 8);
  float4 a = s[0], b = s[1];
  *(uint4*)(dst + (size_t)i * 8) =
      make_uint4(pk2(a.x, a.y), pk2(a.z, a.w), pk2(b.x, b.y), pk2(b.z, b.w));
}

__global__ void k_embed_norm(const int* __restrict__ tok, const float* __restrict__ emb,
                             const float* __restrict__ w, float* __restrict__ xf,
                             u16* __restrict__ xb)
{
  int row = blockIdx.x;
  int t = tok[row];
  float4 v = ((const float4*)(emb + (size_t)t * DMODEL))[threadIdx.x];
  float tot = blockReduceSum(v.x * v.x + v.y * v.y + v.z * v.z + v.w * v.w);
  float inv = rsqrtf(tot * (1.0f / DMODEL) + 1e-6f);
  int d0 = threadIdx.x << 2;
  float4 wv = *(const float4*)(w + d0);
  float4 o;
  o.x = v.x * inv * wv.x; o.y = v.y * inv * wv.y;
  o.z = v.z * inv * wv.z; o.w = v.w * inv * wv.w;
  *(float4*)(xf + (size_t)row * DMODEL + d0) = o;
  *(uint2*)(xb + (size_t)row * DMODEL + d0) = make_uint2(pk2(o.x, o.y), pk2(o.z, o.w));
}

__global__ __launch_bounds__(256) void k_topk(const float* __restrict__ scores,
                                              float* __restrict__ wout, int* __restrict__ iout)
{
  int row = blockIdx.x * 4 + (threadIdx.x >> 6);
  int l = threadIdx.x & 63;
  const float* s = scores + (size_t)row * NCELL;
  float v[8]; int ix[8];
#pragma unroll
  for (int i = 0; i < 8; ++i) { v[i] = -3.4e38f; ix[i] = 0x7fffffff; }
  for (int j = 0; j < 64; ++j) {
    float x = s[j * 64 + l];
    if (x > v[7]) {
      v[7] = x; ix[7] = j * 64 + l;
#pragma unroll
      for (int q = 7; q > 0; --q) {
        if (v[q] > v[q - 1]) {
          float tv = v[q]; v[q] = v[q - 1]; v[q - 1] = tv;
          int tt = ix[q]; ix[q] = ix[q - 1]; ix[q - 1] = tt;
        }
      }
    }
  }
  float ov[8]; int oi[8];
#pragma unroll
  for (int r = 0; r < 8; ++r) {
    float bv = v[0]; int bi = ix[0];
#pragma unroll
    for (int o = 32; o > 0; o >>= 1) {
      float tv = __shfl_xor(bv, o);
      int tb = __shfl_xor(bi, o);
      if (tv > bv || (tv == bv && tb < bi)) { bv = tv; bi = tb; }
    }
    ov[r] = bv; oi[r] = bi;
    if (bi == ix[0]) {
#pragma unroll
      for (int q = 0; q < 7; ++q) { v[q] = v[q + 1]; ix[q] = ix[q + 1]; }
      v[7] = -3.4e38f; ix[7] = 0x7fffffff;
    }
  }
  if (l == 0) {
    float m = ov[0], sum = 0.f, e[8];
#pragma unroll
    for (int r = 0; r < 8; ++r) { e[r] = __expf(ov[r] - m); sum += e[r]; }
    float inv = 1.0f / sum;
#pragma unroll
    for (int r = 0; r < 8; ++r) {
      wout[(size_t)row * 8 + r] = e[r] * inv;
      iout[(size_t)row * 8 + r] = oi[r];
    }
  }
}

__global__ void k_readout(const float* __restrict__ cells, const int* __restrict__ ti,
                          const float* __restrict__ tw, const float* __restrict__ xin,
                          u16* __restrict__ rb)
{
  int row = blockIdx.x, d = threadIdx.x;
  float acc = xin[(size_t)row * DCELL + d];
#pragma unroll
  for (int k = 0; k < 8; ++k) {
    int ci = ti[row * 8 + k];
    float wk = tw[row * 8 + k];
    acc += wk * cells[(size_t)ci * DCELL + d];
  }
  rb[(size_t)row * DCELL + d] = f2bf(acc);
}

// Chunked decay scan: pass A computes per-chunk end states E[b][c][d]
__global__ void k_scan_a(const float* __restrict__ x, float* __restrict__ E,
                         const float* __restrict__ sgw, const float* __restrict__ sgb,
                         const float* __restrict__ sdec)
{
  int tid = blockIdx.x * 256 + threadIdx.x;   // 32768 = 8b * 4c * 1024d
  int d = tid & 1023, bc = tid >> 10;
  int b = bc >> 2, c = bc & 3;
  float dec = sigm(sdec[0]);
  dec = fminf(fmaxf(dec, 0.01f), 0.99f);
  float gw = sgw[d], gb = sgb[d];
  size_t base = ((size_t)b * 256 + c * 64) * DMODEL + d;
  float h = 0.f;
  for (int t = 0; t < 64; ++t) {
    float xv = x[base + (size_t)t * DMODEL];
    h = h * dec + sigm(xv * gw + gb) * xv;
  }
  E[tid] = h;
}

// pass B: combine carries, write pre = x + cs*co + sc*h
__global__ void k_scan_b(const float* __restrict__ x, const float* __restrict__ co,
                         const float* __restrict__ E, float* __restrict__ pre,
                         const float* __restrict__ sgw, const float* __restrict__ sgb,
                         const float* __restrict__ ssc, const float* __restrict__ sdec,
                         const float* __restrict__ csc)
{
  int tid = blockIdx.x * 256 + threadIdx.x;
  int d = tid & 1023, bc = tid >> 10;
  int b = bc >> 2, c = bc & 3;
  float dec = sigm(sdec[0]);
  dec = fminf(fmaxf(dec, 0.01f), 0.99f);
  float d2 = dec * dec, d4 = d2 * d2, d8 = d4 * d4, d16 = d8 * d8, d32 = d16 * d16;
  float d64 = d32 * d32;
  float cs = csc[0];
  float gw = sgw[d], gb = sgb[d], sc = ssc[d];
  float h = 0.f;
  for (int cc = 0; cc < c; ++cc) h = h * d64 + E[((b << 2) + cc) * 1024 + d];
  size_t base = ((size_t)b * 256 + c * 64) * DMODEL + d;
  for (int t = 0; t < 64; ++t) {
    size_t o = base + (size_t)t * DMODEL;
    float xv = x[o];
    float g = sigm(xv * gw + gb);
    h = h * dec + g * xv;
    pre[o] = xv + cs * co[o] + h * sc;
  }
}

__global__ void k_norm2(const float* __restrict__ pre, const float* __restrict__ nw,
                        const float* __restrict__ fw, float* __restrict__ xf,
                        u16* __restrict__ h2b)
{
  int row = blockIdx.x;
  float4 v = ((const float4*)(pre + (size_t)row * DMODEL))[threadIdx.x];
  float tot = blockReduceSum(v.x * v.x + v.y * v.y + v.z * v.z + v.w * v.w);
  float inv = rsqrtf(tot * (1.0f / DMODEL) + 1e-6f);
  int d0 = threadIdx.x << 2;
  float4 wv = *(const float4*)(nw + d0);
  float4 x1;
  x1.x = v.x * inv * wv.x; x1.y = v.y * inv * wv.y;
  x1.z = v.z * inv * wv.z; x1.w = v.w * inv * wv.w;
  *(float4*)(xf + (size_t)row * DMODEL + d0) = x1;
  float tot2 = blockReduceSum(x1.x * x1.x + x1.y * x1.y + x1.z * x1.z + x1.w * x1.w);
  float inv2 = rsqrtf(tot2 * (1.0f / DMODEL) + 1e-6f);
  float4 fv = *(const float4*)(fw + d0);
  *(uint2*)(h2b + (size_t)row * DMODEL + d0) =
      make_uint2(pk2(x1.x * inv2 * fv.x, x1.y * inv2 * fv.y),
                 pk2(x1.z * inv2 * fv.z, x1.w * inv2 * fv.w));
}

__global__ void k_norm_bf(const float* __restrict__ in, const float* __restrict__ w,
                          u16* __restrict__ ob)
{
  int row = blockIdx.x;
  float4 v = ((const float4*)(in + (size_t)row * DMODEL))[threadIdx.x];
  float tot = blockReduceSum(v.x * v.x + v.y * v.y + v.z * v.z + v.w * v.w);
  float inv = rsqrtf(tot * (1.0f / DMODEL) + 1e-6f);
  int d0 = threadIdx.x << 2;
  float4 wv = *(const float4*)(w + d0);
  *(uint2*)(ob + (size_t)row * DMODEL + d0) =
      make_uint2(pk2(v.x * inv * wv.x, v.y * inv * wv.y),
                 pk2(v.z * inv * wv.z, v.w * inv * wv.w));
}

// ---------------------------------------------------------------------------
extern "C" void kernel_launch(void* const* d_in, const int* in_sizes, int n_in,
                              void* d_out, int out_size, void* d_ws, size_t ws_size,
                              hipStream_t stream)
{
  const int*   tokens  = (const int*)d_in[0];
  const float* embed   = (const float*)d_in[1];
  const float* ln_in_w = (const float*)d_in[2];
  const float* ln_out_w= (const float*)d_in[3];
  const float* W_route = (const float*)d_in[4];
  const float* cells   = (const float*)d_in[5];
  const float* W_in    = (const float*)d_in[6];
  const float* W_out   = (const float*)d_in[7];
  const float* sdec    = (const float*)d_in[8];
  const float* sgw     = (const float*)d_in[9];
  const float* sgb     = (const float*)d_in[10];
  const float* ssc     = (const float*)d_in[11];
  const float* csc     = (const float*)d_in[12];
  const float* Wg      = (const float*)d_in[13];
  const float* Wu      = (const float*)d_in[14];
  const float* Wd      = (const float*)d_in[15];
  const float* ffw     = (const float*)d_in[16];
  const float* nrw     = (const float*)d_in[17];
  float* out = (float*)d_out;
  (void)in_sizes; (void)n_in; (void)out_size;

  char* ws = (char*)d_ws;
  size_t off = 0;
  auto alloc = [&](size_t bytes) -> void* {
    void* p = ws + off;
    off += (bytes + 255) & ~(size_t)255;
    return p;
  };

  // ---- epoch 1 (layer loop scratch) ----
  float* scores = (float*)alloc((size_t)MTOK * NCELL * 4);
  u16*  act_bf  = (u16*)alloc((size_t)MTOK * DFF * 2);      // aliased with s_pre
  float* s_pre  = (float*)act_bf;
  float* x_f    = (float*)alloc((size_t)MTOK * DMODEL * 4);
  u16*  x_bf    = (u16*)alloc((size_t)MTOK * DMODEL * 2);
  u16*  h2_bf   = (u16*)alloc((size_t)MTOK * DMODEL * 2);
  float* tw     = (float*)alloc((size_t)MTOK * 8 * 4);
  int*  ti      = (int*)alloc((size_t)MTOK * 8 * 4);
  float* xin    = (float*)alloc((size_t)MTOK * DCELL * 4);
  u16*  r_bf    = (u16*)alloc((size_t)MTOK * DCELL * 2);
  float* cellout= (float*)alloc((size_t)MTOK * DMODEL * 4);
  u16*  WiT     = (u16*)alloc((size_t)DCELL * DMODEL * 2);
  u16*  WoT     = (u16*)alloc((size_t)DMODEL * DCELL * 2);
  u16*  WguT    = (u16*)alloc((size_t)8192 * DMODEL * 2);
  u16*  WdT     = (u16*)alloc((size_t)DMODEL * DFF * 2);
  float* E      = (float*)alloc((size_t)32768 * 4);
  // ---- persistent tail (above embed_bf's 103 MB span) ----
  if (off < ((size_t)108 << 20)) off = (size_t)108 << 20;
  u16*  xf_bf   = (u16*)alloc((size_t)MTOK * DMODEL * 2);
  float* vpad   = (float*)alloc((size_t)MTOK * VPAD_LD * 4);   // 412 MB
  size_t need_pad = off;
  // ---- epoch 2 overlay (written only after layer loop) ----
  u16*  embed_bf = (u16*)ws;   // 102.9 MB, overlays dead epoch-1 scratch

  const bool use_pad = (ws_size >= need_pad);

  k_embed_norm<<<MTOK, 256, 0, stream>>>(tokens, embed, ln_in_w, x_f, x_bf);

  for (int lay = 0; lay < 8; ++lay) {
    const float* Wi_l = W_in  + (size_t)lay * DMODEL * DCELL;
    const float* Wo_l = W_out + (size_t)lay * DCELL * DMODEL;
    const float* Wg_l = Wg    + (size_t)lay * DMODEL * DFF;
    const float* Wu_l = Wu    + (size_t)lay * DMODEL * DFF;
    const float* Wd_l = Wd    + (size_t)lay * DFF * DMODEL;
    const float* Wr_l = W_route + (size_t)lay * NCELL * DMODEL;
    const float* cells_l = cells + (size_t)lay * NCELL * DCELL;

    k_transpose_layer<<<12800, 256, 0, stream>>>(Wi_l, Wo_l, Wg_l, Wu_l, Wd_l,
                                                 WiT, WoT, WguT, WdT);
    // scores = x @ Wr^T / 32   (512 blocks = 16 Mblk x 32 panels, XCD-swizzled)
    k_gemm<1, 0><<<512, 256, 0, stream>>>(x_bf, Wr_l, scores, nullptr,
        NCELL, DMODEL, DMODEL, DMODEL, NCELL, 0.03125f);
    k_topk<<<512, 256, 0, stream>>>(scores, tw, ti);
    // x_in = x @ W_in
    k_gemm64<0><<<dim3(32, 4), 256, 0, stream>>>(x_bf, WiT, xin, nullptr,
        DMODEL, DMODEL, DMODEL, DCELL);
    k_readout<<<MTOK, 256, 0, stream>>>(cells_l, ti, tw, xin, r_bf);
    // cell_out = (readout + x_in) @ W_out
    k_gemm64<0><<<dim3(32, 16), 256, 0, stream>>>(r_bf, WoT, cellout, nullptr,
        DCELL, DCELL, DCELL, DMODEL);
    k_scan_a<<<128, 256, 0, stream>>>(x_f, E, sgw + lay * DMODEL,
        sgb + lay * DMODEL, sdec + lay);
    k_scan_b<<<128, 256, 0, stream>>>(x_f, cellout, E, s_pre, sgw + lay * DMODEL,
        sgb + lay * DMODEL, ssc + lay * DMODEL, sdec + lay, csc + lay);
    k_norm2<<<MTOK, 256, 0, stream>>>(s_pre, nrw + lay * DMODEL, ffw + lay * DMODEL,
        x_f, h2_bf);
    // act = silu(g)*u fused in epilogue (1024 blocks = 16 x 64 panels, swizzled)
    k_gemm<0, 3><<<1024, 256, 0, stream>>>(h2_bf, WguT, nullptr, act_bf,
        8192, DMODEL, DMODEL, DMODEL, 8192, 1.0f);
    // x = x + act @ Wd
    k_gemm64<1><<<dim3(32, 16), 256, 0, stream>>>(act_bf, WdT, x_f, x_bf,
        DFF, DFF, DFF, DMODEL);
  }

  k_norm_bf<<<MTOK, 256, 0, stream>>>(x_f, ln_out_w, xf_bf);
  // embed -> bf16 (overlays dead layer scratch)
  k_f2bf<<<(NVOCAB * (DMODEL / 8) + 255) / 256, 256, 0, stream>>>(
      embed, embed_bf, NVOCAB * (DMODEL / 8));
  // logits GEMM with global_load_lds staging
  if (use_pad) {
    k_gemm_v2<1><<<6288, 256, 0, stream>>>(xf_bf, embed_bf, vpad);
    k_copy_out<<<MTOK, 256, 0, stream>>>(vpad, out);
  } else {
    k_gemm_v2<0><<<6288, 256, 0, stream>>>(xf_bf, embed_bf, out);
  }
}

// Round 8
// 3107.349 us; speedup vs baseline: 1.9051x; 1.5418x over previous
//
#include <hip/hip_runtime.h>
#include <stdint.h>

typedef __attribute__((ext_vector_type(8))) short bf16x8;
typedef __attribute__((ext_vector_type(4))) float f32x4;
typedef unsigned short u16;
typedef unsigned int u32;

#define MTOK 2048
#define DMODEL 1024
#define NCELL 4096
#define DCELL 256
#define DFF 4096
#define NVOCAB 50257
#define VPAD_LD 50304          // 393 * 128, aligned pad leading dim

struct __attribute__((packed, aligned(4))) f4u { float x, y, z, w; };

static __device__ __forceinline__ u16 f2bf(float f) {
  u32 u = __builtin_bit_cast(u32, f);
  u = (u + 0x7FFFu + ((u >> 16) & 1u)) >> 16;
  return (u16)u;
}
static __device__ __forceinline__ u32 pk2(float a, float b) {
  return (u32)f2bf(a) | ((u32)f2bf(b) << 16);
}
static __device__ __forceinline__ float sigm(float x) { return 1.0f / (1.0f + __expf(-x)); }

// async global->LDS, 16 B per lane; lds dest = wave-uniform base + lane*16
static __device__ __forceinline__ void glds16(const void* g, void* l) {
  __builtin_amdgcn_global_load_lds(
      (const __attribute__((address_space(1))) void*)g,
      (__attribute__((address_space(3))) void*)l, 16, 0, 0);
}

static __device__ __forceinline__ float blockReduceSum(float v) {
#pragma unroll
  for (int o = 32; o > 0; o >>= 1) v += __shfl_xor(v, o);
  __shared__ float sm[4];
  __syncthreads();
  if ((threadIdx.x & 63) == 0) sm[threadIdx.x >> 6] = v;
  __syncthreads();
  return sm[0] + sm[1] + sm[2] + sm[3];
}

// ---------------------------------------------------------------------------
// Generalized m97-style GEMM: C[2048,N] = A[2048,K](bf16) x B[N,K]^T(bf16)
// TM=128 fixed (16 m-blocks). TN = 128 or 64. lda = ldb = K.
// global_load_lds (16B/lane) staging, 2 barriers per K-step.
// 1D grid = 16 * (N/TN), XCD-affine swizzle (grid % 8 == 0).
// EPI 0: Cf[row*ldc+col] = alpha*acc
// EPI 1: r = Res[off]+acc; Cf[off]=r; Cb[off]=f2bf(r)   (ldc aligned)
// EPI 2: predicated col<NB f32 store (misaligned fallback)
// EPI 3: fused SwiGLU (B cols interleaved even=g odd=u) -> bf16 Cb[row*DFF+col/2]
// ---------------------------------------------------------------------------
template<int TN, int EPI>
__global__ __launch_bounds__(256, 2) void k_gemm_v3(
    const u16* __restrict__ A, const u16* __restrict__ B,
    float* __restrict__ Cf, u16* __restrict__ Cb, const float* __restrict__ Res,
    int NB, int K, int ldc, float alpha)
{
  __shared__ __align__(16) u16 As[128 * 64];
  __shared__ __align__(16) u16 Bs[TN * 64];
  constexpr int NI = TN / 32;           // ni tiles per wave
  constexpr int BCH = TN / 32;          // B staging chunks
  const int tid = threadIdx.x;
  const int T = gridDim.x;
  const int bid = blockIdx.x;
  const int w = (bid & 7) * (T >> 3) + (bid >> 3);
  const int m0 = (w & 15) * 128;
  const int n0 = (w >> 4) * TN;
  const int l = tid & 63;
  const int wv = tid >> 6;
  const int wm = wv >> 1, wn = wv & 1;
  const int lr = l & 15, lg = l >> 4;
  const int wbase = tid & ~63;          // wave-uniform LDS chunk base

  f32x4 acc[4][NI] = {};

  const int row_ = tid >> 3;            // 0..31 within a 32-row chunk
  const int kc_ = (tid & 7) << 3;
  const int nk = K >> 6;

  for (int s = 0; s < nk; ++s) {
    const int k0 = s << 6;
#pragma unroll
    for (int c = 0; c < 4; ++c) {
      int row = c * 32 + row_;
      glds16(&A[(size_t)(m0 + row) * K + k0 + kc_],
             &As[(size_t)(c * 256 + wbase) * 8]);
    }
#pragma unroll
    for (int c = 0; c < BCH; ++c) {
      int row = c * 32 + row_;
      int gr = n0 + row; if (gr > NB - 1) gr = NB - 1;
      glds16(&B[(size_t)gr * K + k0 + kc_],
             &Bs[(size_t)(c * 256 + wbase) * 8]);
    }
    __syncthreads();    // vmcnt(0) drain + barrier
#pragma unroll
    for (int kk = 0; kk < 2; ++kk) {
      bf16x8 fa[4], fb[NI];
#pragma unroll
      for (int mi = 0; mi < 4; ++mi)
        fa[mi] = *(const bf16x8*)&As[(wm * 64 + mi * 16 + lr) * 64 + kk * 32 + lg * 8];
#pragma unroll
      for (int ni = 0; ni < NI; ++ni)
        fb[ni] = *(const bf16x8*)&Bs[(wn * (TN / 2) + ni * 16 + lr) * 64 + kk * 32 + lg * 8];
#pragma unroll
      for (int mi = 0; mi < 4; ++mi)
#pragma unroll
        for (int ni = 0; ni < NI; ++ni)
          acc[mi][ni] = __builtin_amdgcn_mfma_f32_16x16x32_bf16(fa[mi], fb[ni], acc[mi][ni], 0, 0, 0);
    }
    __syncthreads();    // LDS reads done before next overwrite
  }

#pragma unroll
  for (int mi = 0; mi < 4; ++mi)
#pragma unroll
    for (int ni = 0; ni < NI; ++ni) {
      int col = n0 + wn * (TN / 2) + ni * 16 + lr;
#pragma unroll
      for (int j = 0; j < 4; ++j) {
        int row = m0 + wm * 64 + mi * 16 + lg * 4 + j;
        float v = acc[mi][ni][j];
        if constexpr (EPI == 0) {
          Cf[(size_t)row * ldc + col] = v * alpha;
        } else if constexpr (EPI == 1) {
          size_t off = (size_t)row * ldc + col;
          float r = Res[off] + v;
          Cf[off] = r;
          Cb[off] = f2bf(r);
        } else if constexpr (EPI == 2) {
          if (col < NB) Cf[(size_t)row * ldc + col] = v;
        } else {  // EPI == 3
          float p = __shfl_xor(v, 1);
          float a = v * sigm(v) * p;          // valid on even lr
          float a2 = __shfl_xor(a, 2);
          if ((lr & 3) == 0)
            *(u32*)&Cb[(size_t)row * DFF + (col >> 1)] = pk2(a, a2);
        }
      }
    }
}

// Streaming copy pad[row][0:NVOCAB] -> out[row][*], one block per row.
__global__ __launch_bounds__(256) void k_copy_out(
    const float* __restrict__ pad, float* __restrict__ out)
{
  int row = blockIdx.x;
  const float* s = pad + (size_t)row * VPAD_LD;
  float* d = out + (size_t)row * NVOCAB;
  int t = threadIdx.x;
  int head = (int)((16 - (((size_t)d) & 15)) & 15) >> 2;
  if (t < head) d[t] = s[t];
  int nb = (NVOCAB - head) >> 2;
  const float* sb = s + head;
  float* db = d + head;
  for (int i = t; i < nb; i += 256) {
    f4u v = *(const f4u*)&sb[i * 4];
    *(float4*)&db[i * 4] = make_float4(v.x, v.y, v.z, v.w);
  }
  int t0 = head + nb * 4;
  int rem = NVOCAB - t0;
  if (t < rem) d[t0 + t] = s[t0 + t];
}

// ---------------------------------------------------------------------------
// 64x64 GEMM (NT), bf16 B, Cf = acc. For small Wi/Wo matmuls.
// ---------------------------------------------------------------------------
__global__ __launch_bounds__(256, 3) void k_gemm64(
    const u16* __restrict__ A, const u16* __restrict__ B,
    float* __restrict__ Cf, int K, int lda, int ldb, int ldc)
{
  __shared__ __align__(16) u16 As[64 * 64];
  __shared__ __align__(16) u16 Bs[64 * 64];
  const int tid = threadIdx.x;
  const int m0 = blockIdx.x * 64;
  const int n0 = blockIdx.y * 64;
  const int l = tid & 63;
  const int wv = tid >> 6;
  const int wm = wv >> 1, wn = wv & 1;
  const int lr = l & 15, lg = l >> 4;

  uint4 aR[2], bR[2];
  f32x4 acc[2][2] = {};
  const int nk = K >> 6;

  auto loadAB = [&](int k0) {
#pragma unroll
    for (int c = 0; c < 2; ++c) {
      int id = c * 256 + tid;
      int row = id >> 3, kc = (id & 7) << 3;
      aR[c] = *(const uint4*)&A[(size_t)(m0 + row) * lda + k0 + kc];
      bR[c] = *(const uint4*)&B[(size_t)(n0 + row) * ldb + k0 + kc];
    }
  };
  auto stage = [&]() {
#pragma unroll
    for (int c = 0; c < 2; ++c) {
      int id = c * 256 + tid;
      int row = id >> 3, kc = (id & 7) << 3;
      *(uint4*)&As[row * 64 + kc] = aR[c];
      *(uint4*)&Bs[row * 64 + kc] = bR[c];
    }
  };

  loadAB(0);
  for (int s = 0; s < nk; ++s) {
    __syncthreads();
    stage();
    __syncthreads();
    if (s + 1 < nk) loadAB((s + 1) << 6);
#pragma unroll
    for (int kk = 0; kk < 2; ++kk) {
      bf16x8 fa[2], fb[2];
#pragma unroll
      for (int mi = 0; mi < 2; ++mi)
        fa[mi] = *(const bf16x8*)&As[(wm * 32 + mi * 16 + lr) * 64 + kk * 32 + lg * 8];
#pragma unroll
      for (int ni = 0; ni < 2; ++ni)
        fb[ni] = *(const bf16x8*)&Bs[(wn * 32 + ni * 16 + lr) * 64 + kk * 32 + lg * 8];
#pragma unroll
      for (int mi = 0; mi < 2; ++mi)
#pragma unroll
        for (int ni = 0; ni < 2; ++ni)
          acc[mi][ni] = __builtin_amdgcn_mfma_f32_16x16x32_bf16(fa[mi], fb[ni], acc[mi][ni], 0, 0, 0);
    }
  }

#pragma unroll
  for (int mi = 0; mi < 2; ++mi)
#pragma unroll
    for (int ni = 0; ni < 2; ++ni) {
      int col = n0 + wn * 32 + ni * 16 + lr;
#pragma unroll
      for (int j = 0; j < 4; ++j) {
        int row = m0 + wm * 32 + mi * 16 + lg * 4 + j;
        Cf[(size_t)row * ldc + col] = acc[mi][ni][j];
      }
    }
}

// ---------------------------------------------------------------------------
// Per-layer weight transpose+convert fp32 [R,C] -> bf16 [C,R] (Wg/Wu
// interleave into WguT: dst row = 2c / 2c+1)
// ---------------------------------------------------------------------------
__global__ void k_transpose_layer(
    const float* __restrict__ Wi, const float* __restrict__ Wo,
    const float* __restrict__ Wg, const float* __restrict__ Wu,
    const float* __restrict__ Wd,
    u16* __restrict__ WiT, u16* __restrict__ WoT,
    u16* __restrict__ WguT, u16* __restrict__ WdT)
{
  int bid = blockIdx.x;
  const float* src; u16* dst; int R, C, t0, mul, add;
  if (bid < 256)       { src = Wi; dst = WiT;  R = 1024; C = 256;  t0 = bid;        mul = 1; add = 0; }
  else if (bid < 512)  { src = Wo; dst = WoT;  R = 256;  C = 1024; t0 = bid - 256;  mul = 1; add = 0; }
  else if (bid < 4608) { src = Wg; dst = WguT; R = 1024; C = 4096; t0 = bid - 512;  mul = 2; add = 0; }
  else if (bid < 8704) { src = Wu; dst = WguT; R = 1024; C = 4096; t0 = bid - 4608; mul = 2; add = 1; }
  else                 { src = Wd; dst = WdT;  R = 4096; C = 1024; t0 = bid - 8704; mul = 1; add = 0; }
  int tC = C >> 5;
  int r0 = (t0 / tC) << 5, c0 = (t0 % tC) << 5;
  __shared__ float tile[32][33];
  int ty = threadIdx.x >> 3;
  int tx = (threadIdx.x & 7) << 2;
  float4 v = *(const float4*)&src[(size_t)(r0 + ty) * C + c0 + tx];
  tile[ty][tx] = v.x; tile[ty][tx + 1] = v.y; tile[ty][tx + 2] = v.z; tile[ty][tx + 3] = v.w;
  __syncthreads();
  float a = tile[tx][ty], b = tile[tx + 1][ty], c = tile[tx + 2][ty], d = tile[tx + 3][ty];
  *(uint2*)&dst[((size_t)(c0 + ty) * mul + add) * R + r0 + tx] = make_uint2(pk2(a, b), pk2(c, d));
}

// fp32 -> bf16 flat convert (n8 = count of 8-element groups)
__global__ void k_f2bf(const float* __restrict__ src, u16* __restrict__ dst, int n8)
{
  int i = blockIdx.x * 256 + threadIdx.x;
  if (i >= n8) return;
  const float4* s = (const float4*)(src + (size_t)i * 8);
  float4 a = s[0], b = s[1];
  *(uint4*)(dst + (size_t)i * 8) =
      make_uint4(pk2(a.x, a.y), pk2(a.z, a.w), pk2(b.x, b.y), pk2(b.z, b.w));
}

__global__ void k_embed_norm(const int* __restrict__ tok, const float* __restrict__ emb,
                             const float* __restrict__ w, float* __restrict__ xf,
                             u16* __restrict__ xb)
{
  int row = blockIdx.x;
  int t = tok[row];
  float4 v = ((const float4*)(emb + (size_t)t * DMODEL))[threadIdx.x];
  float tot = blockReduceSum(v.x * v.x + v.y * v.y + v.z * v.z + v.w * v.w);
  float inv = rsqrtf(tot * (1.0f / DMODEL) + 1e-6f);
  int d0 = threadIdx.x << 2;
  float4 wv = *(const float4*)(w + d0);
  float4 o;
  o.x = v.x * inv * wv.x; o.y = v.y * inv * wv.y;
  o.z = v.z * inv * wv.z; o.w = v.w * inv * wv.w;
  *(float4*)(xf + (size_t)row * DMODEL + d0) = o;
  *(uint2*)(xb + (size_t)row * DMODEL + d0) = make_uint2(pk2(o.x, o.y), pk2(o.z, o.w));
}

__global__ __launch_bounds__(256) void k_topk(const float* __restrict__ scores,
                                              float* __restrict__ wout, int* __restrict__ iout)
{
  int row = blockIdx.x * 4 + (threadIdx.x >> 6);
  int l = threadIdx.x & 63;
  const float* s = scores + (size_t)row * NCELL;
  float v[8]; int ix[8];
#pragma unroll
  for (int i = 0; i < 8; ++i) { v[i] = -3.4e38f; ix[i] = 0x7fffffff; }
  for (int j = 0; j < 64; ++j) {
    float x = s[j * 64 + l];
    if (x > v[7]) {
      v[7] = x; ix[7] = j * 64 + l;
#pragma unroll
      for (int q = 7; q > 0; --q) {
        if (v[q] > v[q - 1]) {
          float tv = v[q]; v[q] = v[q - 1]; v[q - 1] = tv;
          int tt = ix[q]; ix[q] = ix[q - 1]; ix[q - 1] = tt;
        }
      }
    }
  }
  float ov[8]; int oi[8];
#pragma unroll
  for (int r = 0; r < 8; ++r) {
    float bv = v[0]; int bi = ix[0];
#pragma unroll
    for (int o = 32; o > 0; o >>= 1) {
      float tv = __shfl_xor(bv, o);
      int tb = __shfl_xor(bi, o);
      if (tv > bv || (tv == bv && tb < bi)) { bv = tv; bi = tb; }
    }
    ov[r] = bv; oi[r] = bi;
    if (bi == ix[0]) {
#pragma unroll
      for (int q = 0; q < 7; ++q) { v[q] = v[q + 1]; ix[q] = ix[q + 1]; }
      v[7] = -3.4e38f; ix[7] = 0x7fffffff;
    }
  }
  if (l == 0) {
    float m = ov[0], sum = 0.f, e[8];
#pragma unroll
    for (int r = 0; r < 8; ++r) { e[r] = __expf(ov[r] - m); sum += e[r]; }
    float inv = 1.0f / sum;
#pragma unroll
    for (int r = 0; r < 8; ++r) {
      wout[(size_t)row * 8 + r] = e[r] * inv;
      iout[(size_t)row * 8 + r] = oi[r];
    }
  }
}

__global__ void k_readout(const float* __restrict__ cells, const int* __restrict__ ti,
                          const float* __restrict__ tw, const float* __restrict__ xin,
                          u16* __restrict__ rb)
{
  int row = blockIdx.x, d = threadIdx.x;
  float acc = xin[(size_t)row * DCELL + d];
#pragma unroll
  for (int k = 0; k < 8; ++k) {
    int ci = ti[row * 8 + k];
    float wk = tw[row * 8 + k];
    acc += wk * cells[(size_t)ci * DCELL + d];
  }
  rb[(size_t)row * DCELL + d] = f2bf(acc);
}

// Chunked decay scan: pass A computes per-chunk end states E[b][c][d]
__global__ void k_scan_a(const float* __restrict__ x, float* __restrict__ E,
                         const float* __restrict__ sgw, const float* __restrict__ sgb,
                         const float* __restrict__ sdec)
{
  int tid = blockIdx.x * 256 + threadIdx.x;   // 32768 = 8b * 4c * 1024d
  int d = tid & 1023, bc = tid >> 10;
  int b = bc >> 2, c = bc & 3;
  float dec = sigm(sdec[0]);
  dec = fminf(fmaxf(dec, 0.01f), 0.99f);
  float gw = sgw[d], gb = sgb[d];
  size_t base = ((size_t)b * 256 + c * 64) * DMODEL + d;
  float h = 0.f;
  for (int t = 0; t < 64; ++t) {
    float xv = x[base + (size_t)t * DMODEL];
    h = h * dec + sigm(xv * gw + gb) * xv;
  }
  E[tid] = h;
}

// pass B: combine carries, write pre = x + cs*co + sc*h
__global__ void k_scan_b(const float* __restrict__ x, const float* __restrict__ co,
                         const float* __restrict__ E, float* __restrict__ pre,
                         const float* __restrict__ sgw, const float* __restrict__ sgb,
                         const float* __restrict__ ssc, const float* __restrict__ sdec,
                         const float* __restrict__ csc)
{
  int tid = blockIdx.x * 256 + threadIdx.x;
  int d = tid & 1023, bc = tid >> 10;
  int b = bc >> 2, c = bc & 3;
  float dec = sigm(sdec[0]);
  dec = fminf(fmaxf(dec, 0.01f), 0.99f);
  float d2 = dec * dec, d4 = d2 * d2, d8 = d4 * d4, d16 = d8 * d8, d32 = d16 * d16;
  float d64 = d32 * d32;
  float cs = csc[0];
  float gw = sgw[d], gb = sgb[d], sc = ssc[d];
  float h = 0.f;
  for (int cc = 0; cc < c; ++cc) h = h * d64 + E[((b << 2) + cc) * 1024 + d];
  size_t base = ((size_t)b * 256 + c * 64) * DMODEL + d;
  for (int t = 0; t < 64; ++t) {
    size_t o = base + (size_t)t * DMODEL;
    float xv = x[o];
    float g = sigm(xv * gw + gb);
    h = h * dec + g * xv;
    pre[o] = xv + cs * co[o] + h * sc;
  }
}

__global__ void k_norm2(const float* __restrict__ pre, const float* __restrict__ nw,
                        const float* __restrict__ fw, float* __restrict__ xf,
                        u16* __restrict__ h2b)
{
  int row = blockIdx.x;
  float4 v = ((const float4*)(pre + (size_t)row * DMODEL))[threadIdx.x];
  float tot = blockReduceSum(v.x * v.x + v.y * v.y + v.z * v.z + v.w * v.w);
  float inv = rsqrtf(tot * (1.0f / DMODEL) + 1e-6f);
  int d0 = threadIdx.x << 2;
  float4 wv = *(const float4*)(nw + d0);
  float4 x1;
  x1.x = v.x * inv * wv.x; x1.y = v.y * inv * wv.y;
  x1.z = v.z * inv * wv.z; x1.w = v.w * inv * wv.w;
  *(float4*)(xf + (size_t)row * DMODEL + d0) = x1;
  float tot2 = blockReduceSum(x1.x * x1.x + x1.y * x1.y + x1.z * x1.z + x1.w * x1.w);
  float inv2 = rsqrtf(tot2 * (1.0f / DMODEL) + 1e-6f);
  float4 fv = *(const float4*)(fw + d0);
  *(uint2*)(h2b + (size_t)row * DMODEL + d0) =
      make_uint2(pk2(x1.x * inv2 * fv.x, x1.y * inv2 * fv.y),
                 pk2(x1.z * inv2 * fv.z, x1.w * inv2 * fv.w));
}

__global__ void k_norm_bf(const float* __restrict__ in, const float* __restrict__ w,
                          u16* __restrict__ ob)
{
  int row = blockIdx.x;
  float4 v = ((const float4*)(in + (size_t)row * DMODEL))[threadIdx.x];
  float tot = blockReduceSum(v.x * v.x + v.y * v.y + v.z * v.z + v.w * v.w);
  float inv = rsqrtf(tot * (1.0f / DMODEL) + 1e-6f);
  int d0 = threadIdx.x << 2;
  float4 wv = *(const float4*)(w + d0);
  *(uint2*)(ob + (size_t)row * DMODEL + d0) =
      make_uint2(pk2(v.x * inv * wv.x, v.y * inv * wv.y),
                 pk2(v.z * inv * wv.z, v.w * inv * wv.w));
}

// ---------------------------------------------------------------------------
extern "C" void kernel_launch(void* const* d_in, const int* in_sizes, int n_in,
                              void* d_out, int out_size, void* d_ws, size_t ws_size,
                              hipStream_t stream)
{
  const int*   tokens  = (const int*)d_in[0];
  const float* embed   = (const float*)d_in[1];
  const float* ln_in_w = (const float*)d_in[2];
  const float* ln_out_w= (const float*)d_in[3];
  const float* W_route = (const float*)d_in[4];
  const float* cells   = (const float*)d_in[5];
  const float* W_in    = (const float*)d_in[6];
  const float* W_out   = (const float*)d_in[7];
  const float* sdec    = (const float*)d_in[8];
  const float* sgw     = (const float*)d_in[9];
  const float* sgb     = (const float*)d_in[10];
  const float* ssc     = (const float*)d_in[11];
  const float* csc     = (const float*)d_in[12];
  const float* Wg      = (const float*)d_in[13];
  const float* Wu      = (const float*)d_in[14];
  const float* Wd      = (const float*)d_in[15];
  const float* ffw     = (const float*)d_in[16];
  const float* nrw     = (const float*)d_in[17];
  float* out = (float*)d_out;
  (void)in_sizes; (void)n_in; (void)out_size;

  char* ws = (char*)d_ws;
  size_t off = 0;
  auto alloc = [&](size_t bytes) -> void* {
    void* p = ws + off;
    off += (bytes + 255) & ~(size_t)255;
    return p;
  };

  // ---- epoch 1 (layer loop scratch) ----
  float* scores = (float*)alloc((size_t)MTOK * NCELL * 4);
  u16*  act_bf  = (u16*)alloc((size_t)MTOK * DFF * 2);      // aliased with s_pre
  float* s_pre  = (float*)act_bf;
  float* x_f    = (float*)alloc((size_t)MTOK * DMODEL * 4);
  u16*  x_bf    = (u16*)alloc((size_t)MTOK * DMODEL * 2);
  u16*  h2_bf   = (u16*)alloc((size_t)MTOK * DMODEL * 2);
  float* tw     = (float*)alloc((size_t)MTOK * 8 * 4);
  int*  ti      = (int*)alloc((size_t)MTOK * 8 * 4);
  float* xin    = (float*)alloc((size_t)MTOK * DCELL * 4);
  u16*  r_bf    = (u16*)alloc((size_t)MTOK * DCELL * 2);
  float* cellout= (float*)alloc((size_t)MTOK * DMODEL * 4);
  u16*  WiT     = (u16*)alloc((size_t)DCELL * DMODEL * 2);
  u16*  WoT     = (u16*)alloc((size_t)DMODEL * DCELL * 2);
  u16*  WguT    = (u16*)alloc((size_t)8192 * DMODEL * 2);
  u16*  WdT     = (u16*)alloc((size_t)DMODEL * DFF * 2);
  u16*  WrB     = (u16*)alloc((size_t)NCELL * DMODEL * 2);  // bf16 W_route
  float* E      = (float*)alloc((size_t)32768 * 4);
  // ---- persistent tail (above embed_bf's 103 MB span) ----
  if (off < ((size_t)108 << 20)) off = (size_t)108 << 20;
  u16*  xf_bf   = (u16*)alloc((size_t)MTOK * DMODEL * 2);
  float* vpad   = (float*)alloc((size_t)MTOK * VPAD_LD * 4);   // 412 MB
  size_t need_pad = off;
  // ---- epoch 2 overlay (written only after layer loop) ----
  u16*  embed_bf = (u16*)ws;   // 102.9 MB, overlays dead epoch-1 scratch

  const bool use_pad = (ws_size >= need_pad);

  k_embed_norm<<<MTOK, 256, 0, stream>>>(tokens, embed, ln_in_w, x_f, x_bf);

  for (int lay = 0; lay < 8; ++lay) {
    const float* Wi_l = W_in  + (size_t)lay * DMODEL * DCELL;
    const float* Wo_l = W_out + (size_t)lay * DCELL * DMODEL;
    const float* Wg_l = Wg    + (size_t)lay * DMODEL * DFF;
    const float* Wu_l = Wu    + (size_t)lay * DMODEL * DFF;
    const float* Wd_l = Wd    + (size_t)lay * DFF * DMODEL;
    const float* Wr_l = W_route + (size_t)lay * NCELL * DMODEL;
    const float* cells_l = cells + (size_t)lay * NCELL * DCELL;

    k_transpose_layer<<<12800, 256, 0, stream>>>(Wi_l, Wo_l, Wg_l, Wu_l, Wd_l,
                                                 WiT, WoT, WguT, WdT);
    // W_route -> bf16
    k_f2bf<<<2048, 256, 0, stream>>>(Wr_l, WrB, NCELL * (DMODEL / 8));
    // scores = x @ Wr^T / 32   (512 blocks, v3 staging)
    k_gemm_v3<128, 0><<<512, 256, 0, stream>>>(x_bf, WrB, scores, nullptr, nullptr,
        NCELL, DMODEL, NCELL, 0.03125f);
    k_topk<<<512, 256, 0, stream>>>(scores, tw, ti);
    // x_in = x @ W_in
    k_gemm64<<<dim3(32, 4), 256, 0, stream>>>(x_bf, WiT, xin,
        DMODEL, DMODEL, DMODEL, DCELL);
    k_readout<<<MTOK, 256, 0, stream>>>(cells_l, ti, tw, xin, r_bf);
    // cell_out = (readout + x_in) @ W_out
    k_gemm64<<<dim3(32, 16), 256, 0, stream>>>(r_bf, WoT, cellout,
        DCELL, DCELL, DCELL, DMODEL);
    k_scan_a<<<128, 256, 0, stream>>>(x_f, E, sgw + lay * DMODEL,
        sgb + lay * DMODEL, sdec + lay);
    k_scan_b<<<128, 256, 0, stream>>>(x_f, cellout, E, s_pre, sgw + lay * DMODEL,
        sgb + lay * DMODEL, ssc + lay * DMODEL, sdec + lay, csc + lay);
    k_norm2<<<MTOK, 256, 0, stream>>>(s_pre, nrw + lay * DMODEL, ffw + lay * DMODEL,
        x_f, h2_bf);
    // act = silu(g)*u fused epilogue (1024 blocks, v3 staging)
    k_gemm_v3<128, 3><<<1024, 256, 0, stream>>>(h2_bf, WguT, nullptr, act_bf, nullptr,
        8192, DMODEL, 0, 1.0f);
    // x = x + act @ Wd  (256 blocks, v3 staging, residual epilogue)
    k_gemm_v3<64, 1><<<256, 256, 0, stream>>>(act_bf, WdT, x_f, x_bf, x_f,
        DMODEL, DFF, DMODEL, 1.0f);
  }

  k_norm_bf<<<MTOK, 256, 0, stream>>>(x_f, ln_out_w, xf_bf);
  // embed -> bf16 (overlays dead layer scratch)
  k_f2bf<<<(NVOCAB * (DMODEL / 8) + 255) / 256, 256, 0, stream>>>(
      embed, embed_bf, NVOCAB * (DMODEL / 8));
  // logits GEMM (v3 staging) -> aligned pad -> streaming copy
  if (use_pad) {
    k_gemm_v3<128, 0><<<6288, 256, 0, stream>>>(xf_bf, embed_bf, vpad, nullptr, nullptr,
        NVOCAB, DMODEL, VPAD_LD, 1.0f);
    k_copy_out<<<MTOK, 256, 0, stream>>>(vpad, out);
  } else {
    k_gemm_v3<128, 2><<<6288, 256, 0, stream>>>(xf_bf, embed_bf, out, nullptr, nullptr,
        NVOCAB, DMODEL, NVOCAB, 1.0f);
  }
}

// Round 9
// 2953.107 us; speedup vs baseline: 2.0046x; 1.0522x over previous
//
#include <hip/hip_runtime.h>
#include <stdint.h>

typedef __attribute__((ext_vector_type(8))) short bf16x8;
typedef __attribute__((ext_vector_type(4))) float f32x4;
typedef unsigned short u16;
typedef unsigned int u32;

#define MTOK 2048
#define DMODEL 1024
#define NCELL 4096
#define DCELL 256
#define DFF 4096
#define NVOCAB 50257
#define VPAD_LD 50304          // 393 * 128, aligned pad leading dim

struct __attribute__((packed, aligned(4))) f4u { float x, y, z, w; };

static __device__ __forceinline__ u16 f2bf(float f) {
  u32 u = __builtin_bit_cast(u32, f);
  u = (u + 0x7FFFu + ((u >> 16) & 1u)) >> 16;
  return (u16)u;
}
static __device__ __forceinline__ u32 pk2(float a, float b) {
  return (u32)f2bf(a) | ((u32)f2bf(b) << 16);
}
static __device__ __forceinline__ float sigm(float x) { return 1.0f / (1.0f + __expf(-x)); }

// async global->LDS, 16 B per lane; lds dest = wave-uniform base + lane*16
static __device__ __forceinline__ void glds16(const void* g, void* l) {
  __builtin_amdgcn_global_load_lds(
      (const __attribute__((address_space(1))) void*)g,
      (__attribute__((address_space(3))) void*)l, 16, 0, 0);
}

static __device__ __forceinline__ float blockReduceSum(float v) {
#pragma unroll
  for (int o = 32; o > 0; o >>= 1) v += __shfl_xor(v, o);
  __shared__ float sm[4];
  __syncthreads();
  if ((threadIdx.x & 63) == 0) sm[threadIdx.x >> 6] = v;
  __syncthreads();
  return sm[0] + sm[1] + sm[2] + sm[3];
}

// ---------------------------------------------------------------------------
// Generalized m97-style GEMM: C[2048,N] = A[2048,K](bf16) x B[N,K]^T(bf16)
// TM in {64,128}, TN in {64,128}. lda = ldb = K.
// global_load_lds (16B/lane) staging, 2 barriers per K-step.
// 1D grid = (2048/TM) * (N/TN), XCD-affine swizzle (grid % 8 == 0).
// 4 waves in 2x2; each wave owns (TM/2) x (TN/2).
// EPI 0: Cf[row*ldc+col] = alpha*acc
// EPI 1: r = Res[off]+acc; Cf[off]=r; Cb[off]=f2bf(r)   (ldc aligned)
// EPI 2: predicated col<NB f32 store (misaligned fallback)
// EPI 3: fused SwiGLU (B cols interleaved even=g odd=u) -> bf16 Cb[row*DFF+col/2]
// ---------------------------------------------------------------------------
template<int TM, int TN, int EPI>
__global__ __launch_bounds__(256, 3) void k_gemm_v3(
    const u16* __restrict__ A, const u16* __restrict__ B,
    float* __restrict__ Cf, u16* __restrict__ Cb, const float* __restrict__ Res,
    int NB, int K, int ldc, float alpha)
{
  __shared__ __align__(16) u16 As[TM * 64];
  __shared__ __align__(16) u16 Bs[TN * 64];
  constexpr int MI = TM / 32;           // mi tiles per wave
  constexpr int NI = TN / 32;           // ni tiles per wave
  constexpr int ACH = TM / 32;          // A staging chunks (32 rows each)
  constexpr int BCH = TN / 32;
  constexpr int MB = 2048 / TM;         // m-blocks
  const int tid = threadIdx.x;
  const int T = gridDim.x;
  const int bid = blockIdx.x;
  const int w = (bid & 7) * (T >> 3) + (bid >> 3);
  const int m0 = (w % MB) * TM;
  const int n0 = (w / MB) * TN;
  const int l = tid & 63;
  const int wv = tid >> 6;
  const int wm = wv >> 1, wn = wv & 1;
  const int lr = l & 15, lg = l >> 4;
  const int wbase = tid & ~63;          // wave-uniform LDS chunk base

  f32x4 acc[MI][NI] = {};

  const int row_ = tid >> 3;            // 0..31 within a 32-row chunk
  const int kc_ = (tid & 7) << 3;
  const int nk = K >> 6;

  for (int s = 0; s < nk; ++s) {
    const int k0 = s << 6;
#pragma unroll
    for (int c = 0; c < ACH; ++c) {
      int row = c * 32 + row_;
      glds16(&A[(size_t)(m0 + row) * K + k0 + kc_],
             &As[(size_t)(c * 256 + wbase) * 8]);
    }
#pragma unroll
    for (int c = 0; c < BCH; ++c) {
      int row = c * 32 + row_;
      int gr = n0 + row; if (gr > NB - 1) gr = NB - 1;
      glds16(&B[(size_t)gr * K + k0 + kc_],
             &Bs[(size_t)(c * 256 + wbase) * 8]);
    }
    __syncthreads();    // vmcnt(0) drain + barrier
#pragma unroll
    for (int kk = 0; kk < 2; ++kk) {
      bf16x8 fa[MI], fb[NI];
#pragma unroll
      for (int mi = 0; mi < MI; ++mi)
        fa[mi] = *(const bf16x8*)&As[(wm * (TM / 2) + mi * 16 + lr) * 64 + kk * 32 + lg * 8];
#pragma unroll
      for (int ni = 0; ni < NI; ++ni)
        fb[ni] = *(const bf16x8*)&Bs[(wn * (TN / 2) + ni * 16 + lr) * 64 + kk * 32 + lg * 8];
#pragma unroll
      for (int mi = 0; mi < MI; ++mi)
#pragma unroll
        for (int ni = 0; ni < NI; ++ni)
          acc[mi][ni] = __builtin_amdgcn_mfma_f32_16x16x32_bf16(fa[mi], fb[ni], acc[mi][ni], 0, 0, 0);
    }
    __syncthreads();    // LDS reads done before next overwrite
  }

#pragma unroll
  for (int mi = 0; mi < MI; ++mi)
#pragma unroll
    for (int ni = 0; ni < NI; ++ni) {
      int col = n0 + wn * (TN / 2) + ni * 16 + lr;
#pragma unroll
      for (int j = 0; j < 4; ++j) {
        int row = m0 + wm * (TM / 2) + mi * 16 + lg * 4 + j;
        float v = acc[mi][ni][j];
        if constexpr (EPI == 0) {
          Cf[(size_t)row * ldc + col] = v * alpha;
        } else if constexpr (EPI == 1) {
          size_t off = (size_t)row * ldc + col;
          float r = Res[off] + v;
          Cf[off] = r;
          Cb[off] = f2bf(r);
        } else if constexpr (EPI == 2) {
          if (col < NB) Cf[(size_t)row * ldc + col] = v;
        } else {  // EPI == 3
          float p = __shfl_xor(v, 1);
          float a = v * sigm(v) * p;          // valid on even lr
          float a2 = __shfl_xor(a, 2);
          if ((lr & 3) == 0)
            *(u32*)&Cb[(size_t)row * DFF + (col >> 1)] = pk2(a, a2);
        }
      }
    }
}

// Streaming copy pad[row][0:NVOCAB] -> out[row][*], one block per row.
__global__ __launch_bounds__(256) void k_copy_out(
    const float* __restrict__ pad, float* __restrict__ out)
{
  int row = blockIdx.x;
  const float* s = pad + (size_t)row * VPAD_LD;
  float* d = out + (size_t)row * NVOCAB;
  int t = threadIdx.x;
  int head = (int)((16 - (((size_t)d) & 15)) & 15) >> 2;
  if (t < head) d[t] = s[t];
  int nb = (NVOCAB - head) >> 2;
  const float* sb = s + head;
  float* db = d + head;
  for (int i = t; i < nb; i += 256) {
    f4u v = *(const f4u*)&sb[i * 4];
    *(float4*)&db[i * 4] = make_float4(v.x, v.y, v.z, v.w);
  }
  int t0 = head + nb * 4;
  int rem = NVOCAB - t0;
  if (t < rem) d[t0 + t] = s[t0 + t];
}

// ---------------------------------------------------------------------------
// 64x64 GEMM (NT), bf16 B, Cf = acc. For small Wi/Wo matmuls.
// ---------------------------------------------------------------------------
__global__ __launch_bounds__(256, 3) void k_gemm64(
    const u16* __restrict__ A, const u16* __restrict__ B,
    float* __restrict__ Cf, int K, int lda, int ldb, int ldc)
{
  __shared__ __align__(16) u16 As[64 * 64];
  __shared__ __align__(16) u16 Bs[64 * 64];
  const int tid = threadIdx.x;
  const int m0 = blockIdx.x * 64;
  const int n0 = blockIdx.y * 64;
  const int l = tid & 63;
  const int wv = tid >> 6;
  const int wm = wv >> 1, wn = wv & 1;
  const int lr = l & 15, lg = l >> 4;

  uint4 aR[2], bR[2];
  f32x4 acc[2][2] = {};
  const int nk = K >> 6;

  auto loadAB = [&](int k0) {
#pragma unroll
    for (int c = 0; c < 2; ++c) {
      int id = c * 256 + tid;
      int row = id >> 3, kc = (id & 7) << 3;
      aR[c] = *(const uint4*)&A[(size_t)(m0 + row) * lda + k0 + kc];
      bR[c] = *(const uint4*)&B[(size_t)(n0 + row) * ldb + k0 + kc];
    }
  };
  auto stage = [&]() {
#pragma unroll
    for (int c = 0; c < 2; ++c) {
      int id = c * 256 + tid;
      int row = id >> 3, kc = (id & 7) << 3;
      *(uint4*)&As[row * 64 + kc] = aR[c];
      *(uint4*)&Bs[row * 64 + kc] = bR[c];
    }
  };

  loadAB(0);
  for (int s = 0; s < nk; ++s) {
    __syncthreads();
    stage();
    __syncthreads();
    if (s + 1 < nk) loadAB((s + 1) << 6);
#pragma unroll
    for (int kk = 0; kk < 2; ++kk) {
      bf16x8 fa[2], fb[2];
#pragma unroll
      for (int mi = 0; mi < 2; ++mi)
        fa[mi] = *(const bf16x8*)&As[(wm * 32 + mi * 16 + lr) * 64 + kk * 32 + lg * 8];
#pragma unroll
      for (int ni = 0; ni < 2; ++ni)
        fb[ni] = *(const bf16x8*)&Bs[(wn * 32 + ni * 16 + lr) * 64 + kk * 32 + lg * 8];
#pragma unroll
      for (int mi = 0; mi < 2; ++mi)
#pragma unroll
        for (int ni = 0; ni < 2; ++ni)
          acc[mi][ni] = __builtin_amdgcn_mfma_f32_16x16x32_bf16(fa[mi], fb[ni], acc[mi][ni], 0, 0, 0);
    }
  }

#pragma unroll
  for (int mi = 0; mi < 2; ++mi)
#pragma unroll
    for (int ni = 0; ni < 2; ++ni) {
      int col = n0 + wn * 32 + ni * 16 + lr;
#pragma unroll
      for (int j = 0; j < 4; ++j) {
        int row = m0 + wm * 32 + mi * 16 + lg * 4 + j;
        Cf[(size_t)row * ldc + col] = acc[mi][ni][j];
      }
    }
}

// ---------------------------------------------------------------------------
// Per-layer weight transpose+convert fp32 [R,C] -> bf16 [C,R] (Wg/Wu
// interleave into WguT: dst row = 2c / 2c+1). Blocks >= 12800 do the
// flat fp32->bf16 convert of W_route (no transpose).
// ---------------------------------------------------------------------------
__global__ void k_transpose_layer(
    const float* __restrict__ Wi, const float* __restrict__ Wo,
    const float* __restrict__ Wg, const float* __restrict__ Wu,
    const float* __restrict__ Wd, const float* __restrict__ Wr,
    u16* __restrict__ WiT, u16* __restrict__ WoT,
    u16* __restrict__ WguT, u16* __restrict__ WdT, u16* __restrict__ WrB)
{
  int bid = blockIdx.x;
  if (bid >= 12800) {   // W_route flat convert: 2048 blocks cover 4096*1024
    int i = (bid - 12800) * 256 + threadIdx.x;   // 8-elem groups
    const float4* s = (const float4*)(Wr + (size_t)i * 8);
    float4 a = s[0], b = s[1];
    *(uint4*)(WrB + (size_t)i * 8) =
        make_uint4(pk2(a.x, a.y), pk2(a.z, a.w), pk2(b.x, b.y), pk2(b.z, b.w));
    return;
  }
  const float* src; u16* dst; int R, C, t0, mul, add;
  if (bid < 256)       { src = Wi; dst = WiT;  R = 1024; C = 256;  t0 = bid;        mul = 1; add = 0; }
  else if (bid < 512)  { src = Wo; dst = WoT;  R = 256;  C = 1024; t0 = bid - 256;  mul = 1; add = 0; }
  else if (bid < 4608) { src = Wg; dst = WguT; R = 1024; C = 4096; t0 = bid - 512;  mul = 2; add = 0; }
  else if (bid < 8704) { src = Wu; dst = WguT; R = 1024; C = 4096; t0 = bid - 4608; mul = 2; add = 1; }
  else                 { src = Wd; dst = WdT;  R = 4096; C = 1024; t0 = bid - 8704; mul = 1; add = 0; }
  int tC = C >> 5;
  int r0 = (t0 / tC) << 5, c0 = (t0 % tC) << 5;
  __shared__ float tile[32][33];
  int ty = threadIdx.x >> 3;
  int tx = (threadIdx.x & 7) << 2;
  float4 v = *(const float4*)&src[(size_t)(r0 + ty) * C + c0 + tx];
  tile[ty][tx] = v.x; tile[ty][tx + 1] = v.y; tile[ty][tx + 2] = v.z; tile[ty][tx + 3] = v.w;
  __syncthreads();
  float a = tile[tx][ty], b = tile[tx + 1][ty], c = tile[tx + 2][ty], d = tile[tx + 3][ty];
  *(uint2*)&dst[((size_t)(c0 + ty) * mul + add) * R + r0 + tx] = make_uint2(pk2(a, b), pk2(c, d));
}

// fp32 -> bf16 flat convert (n8 = count of 8-element groups)
__global__ void k_f2bf(const float* __restrict__ src, u16* __restrict__ dst, int n8)
{
  int i = blockIdx.x * 256 + threadIdx.x;
  if (i >= n8) return;
  const float4* s = (const float4*)(src + (size_t)i * 8);
  float4 a = s[0], b = s[1];
  *(uint4*)(dst + (size_t)i * 8) =
      make_uint4(pk2(a.x, a.y), pk2(a.z, a.w), pk2(b.x, b.y), pk2(b.z, b.w));
}

__global__ void k_embed_norm(const int* __restrict__ tok, const float* __restrict__ emb,
                             const float* __restrict__ w, float* __restrict__ xf,
                             u16* __restrict__ xb)
{
  int row = blockIdx.x;
  int t = tok[row];
  float4 v = ((const float4*)(emb + (size_t)t * DMODEL))[threadIdx.x];
  float tot = blockReduceSum(v.x * v.x + v.y * v.y + v.z * v.z + v.w * v.w);
  float inv = rsqrtf(tot * (1.0f / DMODEL) + 1e-6f);
  int d0 = threadIdx.x << 2;
  float4 wv = *(const float4*)(w + d0);
  float4 o;
  o.x = v.x * inv * wv.x; o.y = v.y * inv * wv.y;
  o.z = v.z * inv * wv.z; o.w = v.w * inv * wv.w;
  *(float4*)(xf + (size_t)row * DMODEL + d0) = o;
  *(uint2*)(xb + (size_t)row * DMODEL + d0) = make_uint2(pk2(o.x, o.y), pk2(o.z, o.w));
}

__global__ __launch_bounds__(256) void k_topk(const float* __restrict__ scores,
                                              float* __restrict__ wout, int* __restrict__ iout)
{
  int row = blockIdx.x * 4 + (threadIdx.x >> 6);
  int l = threadIdx.x & 63;
  const float* s = scores + (size_t)row * NCELL;
  float v[8]; int ix[8];
#pragma unroll
  for (int i = 0; i < 8; ++i) { v[i] = -3.4e38f; ix[i] = 0x7fffffff; }
  for (int j = 0; j < 64; ++j) {
    float x = s[j * 64 + l];
    if (x > v[7]) {
      v[7] = x; ix[7] = j * 64 + l;
#pragma unroll
      for (int q = 7; q > 0; --q) {
        if (v[q] > v[q - 1]) {
          float tv = v[q]; v[q] = v[q - 1]; v[q - 1] = tv;
          int tt = ix[q]; ix[q] = ix[q - 1]; ix[q - 1] = tt;
        }
      }
    }
  }
  float ov[8]; int oi[8];
#pragma unroll
  for (int r = 0; r < 8; ++r) {
    float bv = v[0]; int bi = ix[0];
#pragma unroll
    for (int o = 32; o > 0; o >>= 1) {
      float tv = __shfl_xor(bv, o);
      int tb = __shfl_xor(bi, o);
      if (tv > bv || (tv == bv && tb < bi)) { bv = tv; bi = tb; }
    }
    ov[r] = bv; oi[r] = bi;
    if (bi == ix[0]) {
#pragma unroll
      for (int q = 0; q < 7; ++q) { v[q] = v[q + 1]; ix[q] = ix[q + 1]; }
      v[7] = -3.4e38f; ix[7] = 0x7fffffff;
    }
  }
  if (l == 0) {
    float m = ov[0], sum = 0.f, e[8];
#pragma unroll
    for (int r = 0; r < 8; ++r) { e[r] = __expf(ov[r] - m); sum += e[r]; }
    float inv = 1.0f / sum;
#pragma unroll
    for (int r = 0; r < 8; ++r) {
      wout[(size_t)row * 8 + r] = e[r] * inv;
      iout[(size_t)row * 8 + r] = oi[r];
    }
  }
}

__global__ void k_readout(const float* __restrict__ cells, const int* __restrict__ ti,
                          const float* __restrict__ tw, const float* __restrict__ xin,
                          u16* __restrict__ rb)
{
  int row = blockIdx.x, d = threadIdx.x;
  float acc = xin[(size_t)row * DCELL + d];
#pragma unroll
  for (int k = 0; k < 8; ++k) {
    int ci = ti[row * 8 + k];
    float wk = tw[row * 8 + k];
    acc += wk * cells[(size_t)ci * DCELL + d];
  }
  rb[(size_t)row * DCELL + d] = f2bf(acc);
}

// Chunked decay scan: pass A computes per-chunk end states E[b][c][d]
__global__ void k_scan_a(const float* __restrict__ x, float* __restrict__ E,
                         const float* __restrict__ sgw, const float* __restrict__ sgb,
                         const float* __restrict__ sdec)
{
  int tid = blockIdx.x * 256 + threadIdx.x;   // 32768 = 8b * 4c * 1024d
  int d = tid & 1023, bc = tid >> 10;
  int b = bc >> 2, c = bc & 3;
  float dec = sigm(sdec[0]);
  dec = fminf(fmaxf(dec, 0.01f), 0.99f);
  float gw = sgw[d], gb = sgb[d];
  size_t base = ((size_t)b * 256 + c * 64) * DMODEL + d;
  float h = 0.f;
  for (int t = 0; t < 64; ++t) {
    float xv = x[base + (size_t)t * DMODEL];
    h = h * dec + sigm(xv * gw + gb) * xv;
  }
  E[tid] = h;
}

// pass B: combine carries, write pre = x + cs*co + sc*h
__global__ void k_scan_b(const float* __restrict__ x, const float* __restrict__ co,
                         const float* __restrict__ E, float* __restrict__ pre,
                         const float* __restrict__ sgw, const float* __restrict__ sgb,
                         const float* __restrict__ ssc, const float* __restrict__ sdec,
                         const float* __restrict__ csc)
{
  int tid = blockIdx.x * 256 + threadIdx.x;
  int d = tid & 1023, bc = tid >> 10;
  int b = bc >> 2, c = bc & 3;
  float dec = sigm(sdec[0]);
  dec = fminf(fmaxf(dec, 0.01f), 0.99f);
  float d2 = dec * dec, d4 = d2 * d2, d8 = d4 * d4, d16 = d8 * d8, d32 = d16 * d16;
  float d64 = d32 * d32;
  float cs = csc[0];
  float gw = sgw[d], gb = sgb[d], sc = ssc[d];
  float h = 0.f;
  for (int cc = 0; cc < c; ++cc) h = h * d64 + E[((b << 2) + cc) * 1024 + d];
  size_t base = ((size_t)b * 256 + c * 64) * DMODEL + d;
  for (int t = 0; t < 64; ++t) {
    size_t o = base + (size_t)t * DMODEL;
    float xv = x[o];
    float g = sigm(xv * gw + gb);
    h = h * dec + g * xv;
    pre[o] = xv + cs * co[o] + h * sc;
  }
}

__global__ void k_norm2(const float* __restrict__ pre, const float* __restrict__ nw,
                        const float* __restrict__ fw, float* __restrict__ xf,
                        u16* __restrict__ h2b)
{
  int row = blockIdx.x;
  float4 v = ((const float4*)(pre + (size_t)row * DMODEL))[threadIdx.x];
  float tot = blockReduceSum(v.x * v.x + v.y * v.y + v.z * v.z + v.w * v.w);
  float inv = rsqrtf(tot * (1.0f / DMODEL) + 1e-6f);
  int d0 = threadIdx.x << 2;
  float4 wv = *(const float4*)(nw + d0);
  float4 x1;
  x1.x = v.x * inv * wv.x; x1.y = v.y * inv * wv.y;
  x1.z = v.z * inv * wv.z; x1.w = v.w * inv * wv.w;
  *(float4*)(xf + (size_t)row * DMODEL + d0) = x1;
  float tot2 = blockReduceSum(x1.x * x1.x + x1.y * x1.y + x1.z * x1.z + x1.w * x1.w);
  float inv2 = rsqrtf(tot2 * (1.0f / DMODEL) + 1e-6f);
  float4 fv = *(const float4*)(fw + d0);
  *(uint2*)(h2b + (size_t)row * DMODEL + d0) =
      make_uint2(pk2(x1.x * inv2 * fv.x, x1.y * inv2 * fv.y),
                 pk2(x1.z * inv2 * fv.z, x1.w * inv2 * fv.w));
}

__global__ void k_norm_bf(const float* __restrict__ in, const float* __restrict__ w,
                          u16* __restrict__ ob)
{
  int row = blockIdx.x;
  float4 v = ((const float4*)(in + (size_t)row * DMODEL))[threadIdx.x];
  float tot = blockReduceSum(v.x * v.x + v.y * v.y + v.z * v.z + v.w * v.w);
  float inv = rsqrtf(tot * (1.0f / DMODEL) + 1e-6f);
  int d0 = threadIdx.x << 2;
  float4 wv = *(const float4*)(w + d0);
  *(uint2*)(ob + (size_t)row * DMODEL + d0) =
      make_uint2(pk2(v.x * inv * wv.x, v.y * inv * wv.y),
                 pk2(v.z * inv * wv.z, v.w * inv * wv.w));
}

// ---------------------------------------------------------------------------
extern "C" void kernel_launch(void* const* d_in, const int* in_sizes, int n_in,
                              void* d_out, int out_size, void* d_ws, size_t ws_size,
                              hipStream_t stream)
{
  const int*   tokens  = (const int*)d_in[0];
  const float* embed   = (const float*)d_in[1];
  const float* ln_in_w = (const float*)d_in[2];
  const float* ln_out_w= (const float*)d_in[3];
  const float* W_route = (const float*)d_in[4];
  const float* cells   = (const float*)d_in[5];
  const float* W_in    = (const float*)d_in[6];
  const float* W_out   = (const float*)d_in[7];
  const float* sdec    = (const float*)d_in[8];
  const float* sgw     = (const float*)d_in[9];
  const float* sgb     = (const float*)d_in[10];
  const float* ssc     = (const float*)d_in[11];
  const float* csc     = (const float*)d_in[12];
  const float* Wg      = (const float*)d_in[13];
  const float* Wu      = (const float*)d_in[14];
  const float* Wd      = (const float*)d_in[15];
  const float* ffw     = (const float*)d_in[16];
  const float* nrw     = (const float*)d_in[17];
  float* out = (float*)d_out;
  (void)in_sizes; (void)n_in; (void)out_size;

  char* ws = (char*)d_ws;
  size_t off = 0;
  auto alloc = [&](size_t bytes) -> void* {
    void* p = ws + off;
    off += (bytes + 255) & ~(size_t)255;
    return p;
  };

  // ---- epoch 1 (layer loop scratch) ----
  float* scores = (float*)alloc((size_t)MTOK * NCELL * 4);
  u16*  act_bf  = (u16*)alloc((size_t)MTOK * DFF * 2);      // aliased with s_pre
  float* s_pre  = (float*)act_bf;
  float* x_f    = (float*)alloc((size_t)MTOK * DMODEL * 4);
  u16*  x_bf    = (u16*)alloc((size_t)MTOK * DMODEL * 2);
  u16*  h2_bf   = (u16*)alloc((size_t)MTOK * DMODEL * 2);
  float* tw     = (float*)alloc((size_t)MTOK * 8 * 4);
  int*  ti      = (int*)alloc((size_t)MTOK * 8 * 4);
  float* xin    = (float*)alloc((size_t)MTOK * DCELL * 4);
  u16*  r_bf    = (u16*)alloc((size_t)MTOK * DCELL * 2);
  float* cellout= (float*)alloc((size_t)MTOK * DMODEL * 4);
  u16*  WiT     = (u16*)alloc((size_t)DCELL * DMODEL * 2);
  u16*  WoT     = (u16*)alloc((size_t)DMODEL * DCELL * 2);
  u16*  WguT    = (u16*)alloc((size_t)8192 * DMODEL * 2);
  u16*  WdT     = (u16*)alloc((size_t)DMODEL * DFF * 2);
  u16*  WrB     = (u16*)alloc((size_t)NCELL * DMODEL * 2);  // bf16 W_route
  float* E      = (float*)alloc((size_t)32768 * 4);
  // ---- persistent tail (above embed_bf's 103 MB span) ----
  if (off < ((size_t)108 << 20)) off = (size_t)108 << 20;
  u16*  xf_bf   = (u16*)alloc((size_t)MTOK * DMODEL * 2);
  float* vpad   = (float*)alloc((size_t)MTOK * VPAD_LD * 4);   // 412 MB
  size_t need_pad = off;
  // ---- epoch 2 overlay (written only after layer loop) ----
  u16*  embed_bf = (u16*)ws;   // 102.9 MB, overlays dead epoch-1 scratch

  const bool use_pad = (ws_size >= need_pad);

  k_embed_norm<<<MTOK, 256, 0, stream>>>(tokens, embed, ln_in_w, x_f, x_bf);

  for (int lay = 0; lay < 8; ++lay) {
    const float* Wi_l = W_in  + (size_t)lay * DMODEL * DCELL;
    const float* Wo_l = W_out + (size_t)lay * DCELL * DMODEL;
    const float* Wg_l = Wg    + (size_t)lay * DMODEL * DFF;
    const float* Wu_l = Wu    + (size_t)lay * DMODEL * DFF;
    const float* Wd_l = Wd    + (size_t)lay * DFF * DMODEL;
    const float* Wr_l = W_route + (size_t)lay * NCELL * DMODEL;
    const float* cells_l = cells + (size_t)lay * NCELL * DCELL;

    // weight prep: transposes + W_route bf16 convert, one kernel
    k_transpose_layer<<<14848, 256, 0, stream>>>(Wi_l, Wo_l, Wg_l, Wu_l, Wd_l,
                                                 Wr_l, WiT, WoT, WguT, WdT, WrB);
    // scores = x @ Wr^T / 32
    k_gemm_v3<128, 128, 0><<<512, 256, 0, stream>>>(x_bf, WrB, scores, nullptr,
        nullptr, NCELL, DMODEL, NCELL, 0.03125f);
    k_topk<<<512, 256, 0, stream>>>(scores, tw, ti);
    // x_in = x @ W_in
    k_gemm64<<<dim3(32, 4), 256, 0, stream>>>(x_bf, WiT, xin,
        DMODEL, DMODEL, DMODEL, DCELL);
    k_readout<<<MTOK, 256, 0, stream>>>(cells_l, ti, tw, xin, r_bf);
    // cell_out = (readout + x_in) @ W_out
    k_gemm64<<<dim3(32, 16), 256, 0, stream>>>(r_bf, WoT, cellout,
        DCELL, DCELL, DCELL, DMODEL);
    k_scan_a<<<128, 256, 0, stream>>>(x_f, E, sgw + lay * DMODEL,
        sgb + lay * DMODEL, sdec + lay);
    k_scan_b<<<128, 256, 0, stream>>>(x_f, cellout, E, s_pre, sgw + lay * DMODEL,
        sgb + lay * DMODEL, ssc + lay * DMODEL, sdec + lay, csc + lay);
    k_norm2<<<MTOK, 256, 0, stream>>>(s_pre, nrw + lay * DMODEL, ffw + lay * DMODEL,
        x_f, h2_bf);
    // act = silu(g)*u fused epilogue
    k_gemm_v3<128, 128, 3><<<1024, 256, 0, stream>>>(h2_bf, WguT, nullptr, act_bf,
        nullptr, 8192, DMODEL, 0, 1.0f);
    // x = x + act @ Wd  (TM=64 x TN=64 -> 512 blocks for occupancy)
    k_gemm_v3<64, 64, 1><<<512, 256, 0, stream>>>(act_bf, WdT, x_f, x_bf, x_f,
        DMODEL, DFF, DMODEL, 1.0f);
  }

  k_norm_bf<<<MTOK, 256, 0, stream>>>(x_f, ln_out_w, xf_bf);
  // embed -> bf16 (overlays dead layer scratch)
  k_f2bf<<<(NVOCAB * (DMODEL / 8) + 255) / 256, 256, 0, stream>>>(
      embed, embed_bf, NVOCAB * (DMODEL / 8));
  // logits GEMM -> aligned pad -> streaming copy
  if (use_pad) {
    k_gemm_v3<128, 128, 0><<<6288, 256, 0, stream>>>(xf_bf, embed_bf, vpad, nullptr,
        nullptr, NVOCAB, DMODEL, VPAD_LD, 1.0f);
    k_copy_out<<<MTOK, 256, 0, stream>>>(vpad, out);
  } else {
    k_gemm_v3<128, 128, 2><<<6288, 256, 0, stream>>>(xf_bf, embed_bf, out, nullptr,
        nullptr, NVOCAB, DMODEL, NVOCAB, 1.0f);
  }
}

// Round 11
// 2906.039 us; speedup vs baseline: 2.0371x; 1.0162x over previous
//
#include <hip/hip_runtime.h>
#include <stdint.h>

typedef __attribute__((ext_vector_type(8))) short bf16x8;
typedef __attribute__((ext_vector_type(4))) float f32x4;
typedef unsigned short u16;
typedef unsigned int u32;

#define MTOK 2048
#define DMODEL 1024
#define NCELL 4096
#define DCELL 256
#define DFF 4096
#define NVOCAB 50257
#define VPAD_LD 50304          // 393 * 128, aligned pad leading dim

static __device__ __forceinline__ u16 f2bf(float f) {
  u32 u = __builtin_bit_cast(u32, f);
  u = (u + 0x7FFFu + ((u >> 16) & 1u)) >> 16;
  return (u16)u;
}
static __device__ __forceinline__ u32 pk2(float a, float b) {
  return (u32)f2bf(a) | ((u32)f2bf(b) << 16);
}
static __device__ __forceinline__ float sigm(float x) { return 1.0f / (1.0f + __expf(-x)); }

// async global->LDS, 16 B per lane; lds dest = wave-uniform base + lane*16
static __device__ __forceinline__ void glds16(const void* g, void* l) {
  __builtin_amdgcn_global_load_lds(
      (const __attribute__((address_space(1))) void*)g,
      (__attribute__((address_space(3))) void*)l, 16, 0, 0);
}

static __device__ __forceinline__ float blockReduceSum(float v) {
#pragma unroll
  for (int o = 32; o > 0; o >>= 1) v += __shfl_xor(v, o);
  __shared__ float sm[4];
  __syncthreads();
  if ((threadIdx.x & 63) == 0) sm[threadIdx.x >> 6] = v;
  __syncthreads();
  return sm[0] + sm[1] + sm[2] + sm[3];
}

// 1024-thread block reduce (16 waves)
static __device__ __forceinline__ float blockReduce1024(float v, float* sm) {
#pragma unroll
  for (int o = 32; o > 0; o >>= 1) v += __shfl_xor(v, o);
  if ((threadIdx.x & 63) == 0) sm[threadIdx.x >> 6] = v;
  __syncthreads();
  float r = 0.f;
#pragma unroll
  for (int i = 0; i < 16; ++i) r += sm[i];
  __syncthreads();
  return r;
}

// ---------------------------------------------------------------------------
// Generalized m97-style GEMM: C[2048,N] = A[2048,K](bf16) x B[N,K]^T(bf16)
// TM,TN in {64,128}. global_load_lds staging, 2 barriers per K-step.
// 1D grid = (2048/TM)*(N/TN), XCD-affine swizzle. 4 waves 2x2.
// EPI 0: Cf = alpha*acc          EPI 1: residual r=Res+acc -> Cf,f2bf->Cb
// EPI 2: predicated col<NB       EPI 3: fused SwiGLU -> bf16 Cb
// EPI 4: nontemporal aligned f32 store (vpad)
// ---------------------------------------------------------------------------
template<int TM, int TN, int EPI>
__global__ __launch_bounds__(256, 3) void k_gemm_v3(
    const u16* __restrict__ A, const u16* __restrict__ B,
    float* __restrict__ Cf, u16* __restrict__ Cb, const float* __restrict__ Res,
    int NB, int K, int ldc, float alpha)
{
  __shared__ __align__(16) u16 As[TM * 64];
  __shared__ __align__(16) u16 Bs[TN * 64];
  constexpr int MI = TM / 32;
  constexpr int NI = TN / 32;
  constexpr int ACH = TM / 32;
  constexpr int BCH = TN / 32;
  constexpr int MB = 2048 / TM;
  const int tid = threadIdx.x;
  const int T = gridDim.x;
  const int bid = blockIdx.x;
  const int w = (bid & 7) * (T >> 3) + (bid >> 3);
  const int m0 = (w % MB) * TM;
  const int n0 = (w / MB) * TN;
  const int l = tid & 63;
  const int wv = tid >> 6;
  const int wm = wv >> 1, wn = wv & 1;
  const int lr = l & 15, lg = l >> 4;
  const int wbase = tid & ~63;

  f32x4 acc[MI][NI] = {};

  const int row_ = tid >> 3;
  const int kc_ = (tid & 7) << 3;
  const int nk = K >> 6;

  for (int s = 0; s < nk; ++s) {
    const int k0 = s << 6;
#pragma unroll
    for (int c = 0; c < ACH; ++c) {
      int row = c * 32 + row_;
      glds16(&A[(size_t)(m0 + row) * K + k0 + kc_],
             &As[(size_t)(c * 256 + wbase) * 8]);
    }
#pragma unroll
    for (int c = 0; c < BCH; ++c) {
      int row = c * 32 + row_;
      int gr = n0 + row; if (gr > NB - 1) gr = NB - 1;
      glds16(&B[(size_t)gr * K + k0 + kc_],
             &Bs[(size_t)(c * 256 + wbase) * 8]);
    }
    __syncthreads();
#pragma unroll
    for (int kk = 0; kk < 2; ++kk) {
      bf16x8 fa[MI], fb[NI];
#pragma unroll
      for (int mi = 0; mi < MI; ++mi)
        fa[mi] = *(const bf16x8*)&As[(wm * (TM / 2) + mi * 16 + lr) * 64 + kk * 32 + lg * 8];
#pragma unroll
      for (int ni = 0; ni < NI; ++ni)
        fb[ni] = *(const bf16x8*)&Bs[(wn * (TN / 2) + ni * 16 + lr) * 64 + kk * 32 + lg * 8];
#pragma unroll
      for (int mi = 0; mi < MI; ++mi)
#pragma unroll
        for (int ni = 0; ni < NI; ++ni)
          acc[mi][ni] = __builtin_amdgcn_mfma_f32_16x16x32_bf16(fa[mi], fb[ni], acc[mi][ni], 0, 0, 0);
    }
    __syncthreads();
  }

#pragma unroll
  for (int mi = 0; mi < MI; ++mi)
#pragma unroll
    for (int ni = 0; ni < NI; ++ni) {
      int col = n0 + wn * (TN / 2) + ni * 16 + lr;
#pragma unroll
      for (int j = 0; j < 4; ++j) {
        int row = m0 + wm * (TM / 2) + mi * 16 + lg * 4 + j;
        float v = acc[mi][ni][j];
        if constexpr (EPI == 0) {
          Cf[(size_t)row * ldc + col] = v * alpha;
        } else if constexpr (EPI == 1) {
          size_t off = (size_t)row * ldc + col;
          float r = Res[off] + v;
          Cf[off] = r;
          Cb[off] = f2bf(r);
        } else if constexpr (EPI == 2) {
          if (col < NB) Cf[(size_t)row * ldc + col] = v;
        } else if constexpr (EPI == 3) {
          float p = __shfl_xor(v, 1);
          float a = v * sigm(v) * p;
          float a2 = __shfl_xor(a, 2);
          if ((lr & 3) == 0)
            *(u32*)&Cb[(size_t)row * DFF + (col >> 1)] = pk2(a, a2);
        } else {  // EPI == 4: nontemporal store (keep B L3-resident)
          __builtin_nontemporal_store(v, &Cf[(size_t)row * ldc + col]);
        }
      }
    }
}

// Streaming copy pad[row][0:NVOCAB] -> out[row][*], NT load+store.
__global__ __launch_bounds__(256) void k_copy_out(
    const float* __restrict__ pad, float* __restrict__ out)
{
  int row = blockIdx.x;
  const float* s = pad + (size_t)row * VPAD_LD;
  float* d = out + (size_t)row * NVOCAB;
  int t = threadIdx.x;
  int head = (int)((16 - (((size_t)d) & 15)) & 15) >> 2;
  if (t < head) d[t] = s[t];
  int nb = (NVOCAB - head) >> 2;
  const float* sb = s + head;
  float* db = d + head;
  for (int i = t; i < nb; i += 256) {
    f32x4 v;
    v.x = __builtin_nontemporal_load(&sb[i * 4 + 0]);
    v.y = __builtin_nontemporal_load(&sb[i * 4 + 1]);
    v.z = __builtin_nontemporal_load(&sb[i * 4 + 2]);
    v.w = __builtin_nontemporal_load(&sb[i * 4 + 3]);
    __builtin_nontemporal_store(v, (f32x4*)&db[i * 4]);
  }
  int t0 = head + nb * 4;
  int rem = NVOCAB - t0;
  if (t < rem) d[t0 + t] = s[t0 + t];
}

// ---------------------------------------------------------------------------
// 64x64 GEMM device body (NT, bf16), Cf = acc.
// ---------------------------------------------------------------------------
static __device__ __forceinline__ void gemm64_body(
    const u16* A, const u16* B, float* Cf,
    int m0, int n0, int K, int lda, int ldb, int ldc, char* smem)
{
  u16* As = (u16*)smem;
  u16* Bs = (u16*)(smem + 64 * 64 * 2);
  const int tid = threadIdx.x;
  const int l = tid & 63;
  const int wv = tid >> 6;
  const int wm = wv >> 1, wn = wv & 1;
  const int lr = l & 15, lg = l >> 4;

  uint4 aR[2], bR[2];
  f32x4 acc[2][2] = {};
  const int nk = K >> 6;

  auto loadAB = [&](int k0) {
#pragma unroll
    for (int c = 0; c < 2; ++c) {
      int id = c * 256 + tid;
      int row = id >> 3, kc = (id & 7) << 3;
      aR[c] = *(const uint4*)&A[(size_t)(m0 + row) * lda + k0 + kc];
      bR[c] = *(const uint4*)&B[(size_t)(n0 + row) * ldb + k0 + kc];
    }
  };
  auto stage = [&]() {
#pragma unroll
    for (int c = 0; c < 2; ++c) {
      int id = c * 256 + tid;
      int row = id >> 3, kc = (id & 7) << 3;
      *(uint4*)&As[row * 64 + kc] = aR[c];
      *(uint4*)&Bs[row * 64 + kc] = bR[c];
    }
  };

  loadAB(0);
  for (int s = 0; s < nk; ++s) {
    __syncthreads();
    stage();
    __syncthreads();
    if (s + 1 < nk) loadAB((s + 1) << 6);
#pragma unroll
    for (int kk = 0; kk < 2; ++kk) {
      bf16x8 fa[2], fb[2];
#pragma unroll
      for (int mi = 0; mi < 2; ++mi)
        fa[mi] = *(const bf16x8*)&As[(wm * 32 + mi * 16 + lr) * 64 + kk * 32 + lg * 8];
#pragma unroll
      for (int ni = 0; ni < 2; ++ni)
        fb[ni] = *(const bf16x8*)&Bs[(wn * 32 + ni * 16 + lr) * 64 + kk * 32 + lg * 8];
#pragma unroll
      for (int mi = 0; mi < 2; ++mi)
#pragma unroll
        for (int ni = 0; ni < 2; ++ni)
          acc[mi][ni] = __builtin_amdgcn_mfma_f32_16x16x32_bf16(fa[mi], fb[ni], acc[mi][ni], 0, 0, 0);
    }
  }

#pragma unroll
  for (int mi = 0; mi < 2; ++mi)
#pragma unroll
    for (int ni = 0; ni < 2; ++ni) {
      int col = n0 + wn * 32 + ni * 16 + lr;
#pragma unroll
      for (int j = 0; j < 4; ++j) {
        int row = m0 + wm * 32 + mi * 16 + lg * 4 + j;
        Cf[(size_t)row * ldc + col] = acc[mi][ni][j];
      }
    }
}

__global__ __launch_bounds__(256, 3) void k_gemm64(
    const u16* __restrict__ A, const u16* __restrict__ B,
    float* __restrict__ Cf, int K, int lda, int ldb, int ldc)
{
  __shared__ __align__(16) char smem[16384];
  gemm64_body(A, B, Cf, blockIdx.x * 64, blockIdx.y * 64, K, lda, ldb, ldc, smem);
}

// ---------------------------------------------------------------------------
// Fused: blocks [0,128) = gemm64 xin (x_bf @ WiT);
//        blocks [128,384) = scan_a (8 chunks of 32: E[b][c][d] end states)
// ---------------------------------------------------------------------------
__global__ __launch_bounds__(256, 3) void k_prep_fused(
    const u16* __restrict__ x_bf, const u16* __restrict__ WiT,
    float* __restrict__ xin,
    const float* __restrict__ x_f, float* __restrict__ E,
    const float* __restrict__ sgw, const float* __restrict__ sgb,
    const float* __restrict__ sdec)
{
  __shared__ __align__(16) char smem[16384];
  int bid = blockIdx.x;
  if (bid < 128) {
    gemm64_body(x_bf, WiT, xin, (bid & 31) * 64, (bid >> 5) * 64,
                DMODEL, DMODEL, DMODEL, DCELL, smem);
    return;
  }
  int tid = (bid - 128) * 256 + threadIdx.x;   // 65536 = 8b * 8c * 1024d
  int d = tid & 1023, bc = tid >> 10;
  int b = bc >> 3, c = bc & 7;
  float dec = sigm(sdec[0]);
  dec = fminf(fmaxf(dec, 0.01f), 0.99f);
  float gw = sgw[d], gb = sgb[d];
  size_t base = ((size_t)b * 256 + c * 32) * DMODEL + d;
  float h = 0.f;
  for (int t = 0; t < 32; ++t) {
    float xv = x_f[base + (size_t)t * DMODEL];
    h = h * dec + sigm(xv * gw + gb) * xv;
  }
  E[tid] = h;
}

// ---------------------------------------------------------------------------
// Fused top-8 + softmax + readout. Block = 4 rows; wave v owns row v (topk),
// then all 256 threads do readout (r_bf = xin + sum w_k cells[idx_k]).
// ---------------------------------------------------------------------------
__global__ __launch_bounds__(256) void k_cell_fused(
    const float* __restrict__ scores, const float* __restrict__ cells,
    const float* __restrict__ xin, u16* __restrict__ rb)
{
  __shared__ float sw[4][8];
  __shared__ int si[4][8];
  int row0 = blockIdx.x * 4;
  int wvid = threadIdx.x >> 6;
  int row = row0 + wvid;
  int l = threadIdx.x & 63;
  const float* s = scores + (size_t)row * NCELL;
  float v[8]; int ix[8];
#pragma unroll
  for (int i = 0; i < 8; ++i) { v[i] = -3.4e38f; ix[i] = 0x7fffffff; }
  for (int j = 0; j < 64; ++j) {
    float x = s[j * 64 + l];
    if (x > v[7]) {
      v[7] = x; ix[7] = j * 64 + l;
#pragma unroll
      for (int q = 7; q > 0; --q) {
        if (v[q] > v[q - 1]) {
          float tv = v[q]; v[q] = v[q - 1]; v[q - 1] = tv;
          int tt = ix[q]; ix[q] = ix[q - 1]; ix[q - 1] = tt;
        }
      }
    }
  }
  float ov[8]; int oi[8];
#pragma unroll
  for (int r = 0; r < 8; ++r) {
    float bv = v[0]; int bi = ix[0];
#pragma unroll
    for (int o = 32; o > 0; o >>= 1) {
      float tv = __shfl_xor(bv, o);
      int tb = __shfl_xor(bi, o);
      if (tv > bv || (tv == bv && tb < bi)) { bv = tv; bi = tb; }
    }
    ov[r] = bv; oi[r] = bi;
    if (bi == ix[0]) {
#pragma unroll
      for (int q = 0; q < 7; ++q) { v[q] = v[q + 1]; ix[q] = ix[q + 1]; }
      v[7] = -3.4e38f; ix[7] = 0x7fffffff;
    }
  }
  if (l == 0) {
    float m = ov[0], sum = 0.f, e[8];
#pragma unroll
    for (int r = 0; r < 8; ++r) { e[r] = __expf(ov[r] - m); sum += e[r]; }
    float inv = 1.0f / sum;
#pragma unroll
    for (int r = 0; r < 8; ++r) { sw[wvid][r] = e[r] * inv; si[wvid][r] = oi[r]; }
  }
  __syncthreads();
  int d = threadIdx.x;
#pragma unroll
  for (int r = 0; r < 4; ++r) {
    int rr = row0 + r;
    float acc = xin[(size_t)rr * DCELL + d];
#pragma unroll
    for (int k = 0; k < 8; ++k)
      acc += sw[r][k] * cells[(size_t)si[r][k] * DCELL + d];
    rb[(size_t)rr * DCELL + d] = f2bf(acc);
  }
}

// ---------------------------------------------------------------------------
// Fused scan_b + double rmsnorm. Block = (b,c): 1024 threads own a full
// d-row; 32 t-steps; per step, in-block reduces give both norms.
// x_f := rmsnorm(pre, nw); h2b := rmsnorm(x_f, fw) in bf16.
// ---------------------------------------------------------------------------
__global__ __launch_bounds__(1024) void k_scan_norm(
    float* __restrict__ x_f, const float* __restrict__ co,
    const float* __restrict__ E, u16* __restrict__ h2b,
    const float* __restrict__ sgw, const float* __restrict__ sgb,
    const float* __restrict__ ssc, const float* __restrict__ sdec,
    const float* __restrict__ csc, const float* __restrict__ nw,
    const float* __restrict__ fw)
{
  __shared__ float sm[16];
  int b = blockIdx.x >> 3, c = blockIdx.x & 7;
  int d = threadIdx.x;
  float dec = sigm(sdec[0]);
  dec = fminf(fmaxf(dec, 0.01f), 0.99f);
  float d2 = dec * dec, d4 = d2 * d2, d8 = d4 * d4, d16 = d8 * d8;
  float d32 = d16 * d16;
  float cs = csc[0];
  float gw = sgw[d], gb = sgb[d], sc = ssc[d];
  float nwd = nw[d], fwd = fw[d];
  float h = 0.f;
  for (int cc = 0; cc < c; ++cc) h = h * d32 + E[((b << 3) + cc) * 1024 + d];
  size_t base = ((size_t)b * 256 + c * 32) * DMODEL + d;
  for (int t = 0; t < 32; ++t) {
    size_t o = base + (size_t)t * DMODEL;
    float xv = x_f[o];
    float g = sigm(xv * gw + gb);
    h = h * dec + g * xv;
    float pre = xv + cs * co[o] + h * sc;
    float s1 = blockReduce1024(pre * pre, sm);
    float inv = rsqrtf(s1 * (1.0f / DMODEL) + 1e-6f);
    float x1 = pre * inv * nwd;
    float s2 = blockReduce1024(x1 * x1, sm);
    float inv2 = rsqrtf(s2 * (1.0f / DMODEL) + 1e-6f);
    x_f[o] = x1;
    h2b[o] = f2bf(x1 * inv2 * fwd);
  }
}

// ---------------------------------------------------------------------------
// Per-layer weight transpose+convert fp32 [R,C] -> bf16 [C,R]; blocks >=
// 12800 flat-convert W_route.
// ---------------------------------------------------------------------------
__global__ void k_transpose_layer(
    const float* __restrict__ Wi, const float* __restrict__ Wo,
    const float* __restrict__ Wg, const float* __restrict__ Wu,
    const float* __restrict__ Wd, const float* __restrict__ Wr,
    u16* __restrict__ WiT, u16* __restrict__ WoT,
    u16* __restrict__ WguT, u16* __restrict__ WdT, u16* __restrict__ WrB)
{
  int bid = blockIdx.x;
  if (bid >= 12800) {
    int i = (bid - 12800) * 256 + threadIdx.x;
    const float4* s = (const float4*)(Wr + (size_t)i * 8);
    float4 a = s[0], b = s[1];
    *(uint4*)(WrB + (size_t)i * 8) =
        make_uint4(pk2(a.x, a.y), pk2(a.z, a.w), pk2(b.x, b.y), pk2(b.z, b.w));
    return;
  }
  const float* src; u16* dst; int R, C, t0, mul, add;
  if (bid < 256)       { src = Wi; dst = WiT;  R = 1024; C = 256;  t0 = bid;        mul = 1; add = 0; }
  else if (bid < 512)  { src = Wo; dst = WoT;  R = 256;  C = 1024; t0 = bid - 256;  mul = 1; add = 0; }
  else if (bid < 4608) { src = Wg; dst = WguT; R = 1024; C = 4096; t0 = bid - 512;  mul = 2; add = 0; }
  else if (bid < 8704) { src = Wu; dst = WguT; R = 1024; C = 4096; t0 = bid - 4608; mul = 2; add = 1; }
  else                 { src = Wd; dst = WdT;  R = 4096; C = 1024; t0 = bid - 8704; mul = 1; add = 0; }
  int tC = C >> 5;
  int r0 = (t0 / tC) << 5, c0 = (t0 % tC) << 5;
  __shared__ float tile[32][33];
  int ty = threadIdx.x >> 3;
  int tx = (threadIdx.x & 7) << 2;
  float4 v = *(const float4*)&src[(size_t)(r0 + ty) * C + c0 + tx];
  tile[ty][tx] = v.x; tile[ty][tx + 1] = v.y; tile[ty][tx + 2] = v.z; tile[ty][tx + 3] = v.w;
  __syncthreads();
  float a = tile[tx][ty], b = tile[tx + 1][ty], c = tile[tx + 2][ty], d = tile[tx + 3][ty];
  *(uint2*)&dst[((size_t)(c0 + ty) * mul + add) * R + r0 + tx] = make_uint2(pk2(a, b), pk2(c, d));
}

__global__ void k_embed_norm(const int* __restrict__ tok, const float* __restrict__ emb,
                             const float* __restrict__ w, float* __restrict__ xf,
                             u16* __restrict__ xb)
{
  int row = blockIdx.x;
  int t = tok[row];
  float4 v = ((const float4*)(emb + (size_t)t * DMODEL))[threadIdx.x];
  float tot = blockReduceSum(v.x * v.x + v.y * v.y + v.z * v.z + v.w * v.w);
  float inv = rsqrtf(tot * (1.0f / DMODEL) + 1e-6f);
  int d0 = threadIdx.x << 2;
  float4 wv = *(const float4*)(w + d0);
  float4 o;
  o.x = v.x * inv * wv.x; o.y = v.y * inv * wv.y;
  o.z = v.z * inv * wv.z; o.w = v.w * inv * wv.w;
  *(float4*)(xf + (size_t)row * DMODEL + d0) = o;
  *(uint2*)(xb + (size_t)row * DMODEL + d0) = make_uint2(pk2(o.x, o.y), pk2(o.z, o.w));
}

// Tail fused: blocks [0,2048) rmsnorm(x_f)*ln_out -> xf_bf;
// blocks [2048, ...) embed fp32->bf16 flat convert.
__global__ __launch_bounds__(256) void k_tail(
    const float* __restrict__ xf, const float* __restrict__ w,
    u16* __restrict__ ob, const float* __restrict__ emb,
    u16* __restrict__ emb_bf)
{
  int bid = blockIdx.x;
  if (bid >= 2048) {
    int i = (bid - 2048) * 256 + threadIdx.x;
    if (i >= NVOCAB * (DMODEL / 8)) return;
    const float4* s = (const float4*)(emb + (size_t)i * 8);
    float4 a = s[0], b = s[1];
    *(uint4*)(emb_bf + (size_t)i * 8) =
        make_uint4(pk2(a.x, a.y), pk2(a.z, a.w), pk2(b.x, b.y), pk2(b.z, b.w));
    return;
  }
  int row = bid;
  float4 v = ((const float4*)(xf + (size_t)row * DMODEL))[threadIdx.x];
  float tot = blockReduceSum(v.x * v.x + v.y * v.y + v.z * v.z + v.w * v.w);
  float inv = rsqrtf(tot * (1.0f / DMODEL) + 1e-6f);
  int d0 = threadIdx.x << 2;
  float4 wv = *(const float4*)(w + d0);
  *(uint2*)(ob + (size_t)row * DMODEL + d0) =
      make_uint2(pk2(v.x * inv * wv.x, v.y * inv * wv.y),
                 pk2(v.z * inv * wv.z, v.w * inv * wv.w));
}

// ---------------------------------------------------------------------------
extern "C" void kernel_launch(void* const* d_in, const int* in_sizes, int n_in,
                              void* d_out, int out_size, void* d_ws, size_t ws_size,
                              hipStream_t stream)
{
  const int*   tokens  = (const int*)d_in[0];
  const float* embed   = (const float*)d_in[1];
  const float* ln_in_w = (const float*)d_in[2];
  const float* ln_out_w= (const float*)d_in[3];
  const float* W_route = (const float*)d_in[4];
  const float* cells   = (const float*)d_in[5];
  const float* W_in    = (const float*)d_in[6];
  const float* W_out   = (const float*)d_in[7];
  const float* sdec    = (const float*)d_in[8];
  const float* sgw     = (const float*)d_in[9];
  const float* sgb     = (const float*)d_in[10];
  const float* ssc     = (const float*)d_in[11];
  const float* csc     = (const float*)d_in[12];
  const float* Wg      = (const float*)d_in[13];
  const float* Wu      = (const float*)d_in[14];
  const float* Wd      = (const float*)d_in[15];
  const float* ffw     = (const float*)d_in[16];
  const float* nrw     = (const float*)d_in[17];
  float* out = (float*)d_out;
  (void)in_sizes; (void)n_in; (void)out_size;

  char* ws = (char*)d_ws;
  size_t off = 0;
  auto alloc = [&](size_t bytes) -> void* {
    void* p = ws + off;
    off += (bytes + 255) & ~(size_t)255;
    return p;
  };

  // ---- epoch 1 (layer loop scratch) ----
  float* scores = (float*)alloc((size_t)MTOK * NCELL * 4);
  u16*  act_bf  = (u16*)alloc((size_t)MTOK * DFF * 2);
  float* x_f    = (float*)alloc((size_t)MTOK * DMODEL * 4);
  u16*  x_bf    = (u16*)alloc((size_t)MTOK * DMODEL * 2);
  u16*  h2_bf   = (u16*)alloc((size_t)MTOK * DMODEL * 2);
  float* xin    = (float*)alloc((size_t)MTOK * DCELL * 4);
  u16*  r_bf    = (u16*)alloc((size_t)MTOK * DCELL * 2);
  float* cellout= (float*)alloc((size_t)MTOK * DMODEL * 4);
  u16*  WiT     = (u16*)alloc((size_t)DCELL * DMODEL * 2);
  u16*  WoT     = (u16*)alloc((size_t)DMODEL * DCELL * 2);
  u16*  WguT    = (u16*)alloc((size_t)8192 * DMODEL * 2);
  u16*  WdT     = (u16*)alloc((size_t)DMODEL * DFF * 2);
  u16*  WrB     = (u16*)alloc((size_t)NCELL * DMODEL * 2);
  float* E      = (float*)alloc((size_t)65536 * 4);
  // ---- persistent tail (above embed_bf's 103 MB span) ----
  if (off < ((size_t)108 << 20)) off = (size_t)108 << 20;
  u16*  xf_bf   = (u16*)alloc((size_t)MTOK * DMODEL * 2);
  float* vpad   = (float*)alloc((size_t)MTOK * VPAD_LD * 4);   // 412 MB
  size_t need_pad = off;
  // ---- epoch 2 overlay (written only after layer loop) ----
  u16*  embed_bf = (u16*)ws;

  const bool use_pad = (ws_size >= need_pad);

  k_embed_norm<<<MTOK, 256, 0, stream>>>(tokens, embed, ln_in_w, x_f, x_bf);

  for (int lay = 0; lay < 8; ++lay) {
    const float* Wi_l = W_in  + (size_t)lay * DMODEL * DCELL;
    const float* Wo_l = W_out + (size_t)lay * DCELL * DMODEL;
    const float* Wg_l = Wg    + (size_t)lay * DMODEL * DFF;
    const float* Wu_l = Wu    + (size_t)lay * DMODEL * DFF;
    const float* Wd_l = Wd    + (size_t)lay * DFF * DMODEL;
    const float* Wr_l = W_route + (size_t)lay * NCELL * DMODEL;
    const float* cells_l = cells + (size_t)lay * NCELL * DCELL;

    // weight prep: transposes + W_route bf16 convert
    k_transpose_layer<<<14848, 256, 0, stream>>>(Wi_l, Wo_l, Wg_l, Wu_l, Wd_l,
                                                 Wr_l, WiT, WoT, WguT, WdT, WrB);
    // scores = x @ Wr^T / 32
    k_gemm_v3<128, 128, 0><<<512, 256, 0, stream>>>(x_bf, WrB, scores, nullptr,
        nullptr, NCELL, DMODEL, NCELL, 0.03125f);
    // xin GEMM + scan pass A (independent, fused)
    k_prep_fused<<<384, 256, 0, stream>>>(x_bf, WiT, xin, x_f, E,
        sgw + lay * DMODEL, sgb + lay * DMODEL, sdec + lay);
    // top-8 + softmax + readout
    k_cell_fused<<<512, 256, 0, stream>>>(scores, cells_l, xin, r_bf);
    // cell_out = readout @ W_out
    k_gemm64<<<dim3(32, 16), 256, 0, stream>>>(r_bf, WoT, cellout,
        DCELL, DCELL, DCELL, DMODEL);
    // scan pass B + both rmsnorms (fused; x_f := normed x, h2_bf := ffn input)
    k_scan_norm<<<64, 1024, 0, stream>>>(x_f, cellout, E, h2_bf,
        sgw + lay * DMODEL, sgb + lay * DMODEL, ssc + lay * DMODEL,
        sdec + lay, csc + lay, nrw + lay * DMODEL, ffw + lay * DMODEL);
    // act = silu(g)*u fused epilogue
    k_gemm_v3<128, 128, 3><<<1024, 256, 0, stream>>>(h2_bf, WguT, nullptr, act_bf,
        nullptr, 8192, DMODEL, 0, 1.0f);
    // x = x + act @ Wd
    k_gemm_v3<64, 64, 1><<<512, 256, 0, stream>>>(act_bf, WdT, x_f, x_bf, x_f,
        DMODEL, DFF, DMODEL, 1.0f);
  }

  // tail: final norm + embed bf16 convert (fused)
  k_tail<<<2048 + 25129, 256, 0, stream>>>(x_f, ln_out_w, xf_bf, embed, embed_bf);
  // logits GEMM -> aligned pad (NT stores) -> streaming copy
  if (use_pad) {
    k_gemm_v3<128, 128, 4><<<6288, 256, 0, stream>>>(xf_bf, embed_bf, vpad, nullptr,
        nullptr, NVOCAB, DMODEL, VPAD_LD, 1.0f);
    k_copy_out<<<MTOK, 256, 0, stream>>>(vpad, out);
  } else {
    k_gemm_v3<128, 128, 2><<<6288, 256, 0, stream>>>(xf_bf, embed_bf, out, nullptr,
        nullptr, NVOCAB, DMODEL, NVOCAB, 1.0f);
  }
}

// Round 12
// 2778.998 us; speedup vs baseline: 2.1302x; 1.0457x over previous
//
#include <hip/hip_runtime.h>
#include <stdint.h>

typedef __attribute__((ext_vector_type(8))) short bf16x8;
typedef __attribute__((ext_vector_type(4))) float f32x4;
typedef unsigned short u16;
typedef unsigned int u32;

#define MTOK 2048
#define DMODEL 1024
#define NCELL 4096
#define DCELL 256
#define DFF 4096
#define NVOCAB 50257
#define VPAD_LD 50304          // 393 * 128, aligned pad leading dim

static __device__ __forceinline__ u16 f2bf(float f) {
  u32 u = __builtin_bit_cast(u32, f);
  u = (u + 0x7FFFu + ((u >> 16) & 1u)) >> 16;
  return (u16)u;
}
static __device__ __forceinline__ u32 pk2(float a, float b) {
  return (u32)f2bf(a) | ((u32)f2bf(b) << 16);
}
static __device__ __forceinline__ float sigm(float x) { return 1.0f / (1.0f + __expf(-x)); }

// async global->LDS, 16 B per lane; lds dest = wave-uniform base + lane*16
static __device__ __forceinline__ void glds16(const void* g, void* l) {
  __builtin_amdgcn_global_load_lds(
      (const __attribute__((address_space(1))) void*)g,
      (__attribute__((address_space(3))) void*)l, 16, 0, 0);
}

static __device__ __forceinline__ float blockReduceSum(float v) {
#pragma unroll
  for (int o = 32; o > 0; o >>= 1) v += __shfl_xor(v, o);
  __shared__ float sm[4];
  __syncthreads();
  if ((threadIdx.x & 63) == 0) sm[threadIdx.x >> 6] = v;
  __syncthreads();
  return sm[0] + sm[1] + sm[2] + sm[3];
}

// 1024-thread block reduce (16 waves)
static __device__ __forceinline__ float blockReduce1024(float v, float* sm) {
#pragma unroll
  for (int o = 32; o > 0; o >>= 1) v += __shfl_xor(v, o);
  if ((threadIdx.x & 63) == 0) sm[threadIdx.x >> 6] = v;
  __syncthreads();
  float r = 0.f;
#pragma unroll
  for (int i = 0; i < 16; ++i) r += sm[i];
  __syncthreads();
  return r;
}

// ---------------------------------------------------------------------------
// Generalized m97-style GEMM: C[2048,N] = A[2048,K](bf16) x B[N,K]^T(bf16)
// TM in {64,128}, TN in {64,128}. global_load_lds staging, 2 barriers/K-step.
// 1D grid = (2048/TM)*(N/TN), XCD-affine swizzle. 4 waves 2x2.
// EPI 0: Cf = alpha*acc          EPI 1: residual r=Res+acc -> Cf,f2bf->Cb
// EPI 2: predicated col<NB       EPI 3: fused SwiGLU -> bf16 Cb
// EPI 4: nontemporal aligned f32 store (vpad)
// ---------------------------------------------------------------------------
template<int TM, int TN, int EPI>
__global__ __launch_bounds__(256, 3) void k_gemm_v3(
    const u16* __restrict__ A, const u16* __restrict__ B,
    float* __restrict__ Cf, u16* __restrict__ Cb, const float* __restrict__ Res,
    int NB, int K, int ldc, float alpha)
{
  __shared__ __align__(16) u16 As[TM * 64];
  __shared__ __align__(16) u16 Bs[TN * 64];
  constexpr int MI = TM / 32;
  constexpr int NI = TN / 32;
  constexpr int ACH = TM / 32;
  constexpr int BCH = TN / 32;
  constexpr int MB = 2048 / TM;
  const int tid = threadIdx.x;
  const int T = gridDim.x;
  const int bid = blockIdx.x;
  const int w = (bid & 7) * (T >> 3) + (bid >> 3);
  const int m0 = (w % MB) * TM;
  const int n0 = (w / MB) * TN;
  const int l = tid & 63;
  const int wv = tid >> 6;
  const int wm = wv >> 1, wn = wv & 1;
  const int lr = l & 15, lg = l >> 4;
  const int wbase = tid & ~63;

  f32x4 acc[MI][NI] = {};

  const int row_ = tid >> 3;
  const int kc_ = (tid & 7) << 3;
  const int nk = K >> 6;

  for (int s = 0; s < nk; ++s) {
    const int k0 = s << 6;
#pragma unroll
    for (int c = 0; c < ACH; ++c) {
      int row = c * 32 + row_;
      glds16(&A[(size_t)(m0 + row) * K + k0 + kc_],
             &As[(size_t)(c * 256 + wbase) * 8]);
    }
#pragma unroll
    for (int c = 0; c < BCH; ++c) {
      int row = c * 32 + row_;
      int gr = n0 + row; if (gr > NB - 1) gr = NB - 1;
      glds16(&B[(size_t)gr * K + k0 + kc_],
             &Bs[(size_t)(c * 256 + wbase) * 8]);
    }
    __syncthreads();
#pragma unroll
    for (int kk = 0; kk < 2; ++kk) {
      bf16x8 fa[MI], fb[NI];
#pragma unroll
      for (int mi = 0; mi < MI; ++mi)
        fa[mi] = *(const bf16x8*)&As[(wm * (TM / 2) + mi * 16 + lr) * 64 + kk * 32 + lg * 8];
#pragma unroll
      for (int ni = 0; ni < NI; ++ni)
        fb[ni] = *(const bf16x8*)&Bs[(wn * (TN / 2) + ni * 16 + lr) * 64 + kk * 32 + lg * 8];
#pragma unroll
      for (int mi = 0; mi < MI; ++mi)
#pragma unroll
        for (int ni = 0; ni < NI; ++ni)
          acc[mi][ni] = __builtin_amdgcn_mfma_f32_16x16x32_bf16(fa[mi], fb[ni], acc[mi][ni], 0, 0, 0);
    }
    __syncthreads();
  }

#pragma unroll
  for (int mi = 0; mi < MI; ++mi)
#pragma unroll
    for (int ni = 0; ni < NI; ++ni) {
      int col = n0 + wn * (TN / 2) + ni * 16 + lr;
#pragma unroll
      for (int j = 0; j < 4; ++j) {
        int row = m0 + wm * (TM / 2) + mi * 16 + lg * 4 + j;
        float v = acc[mi][ni][j];
        if constexpr (EPI == 0) {
          Cf[(size_t)row * ldc + col] = v * alpha;
        } else if constexpr (EPI == 1) {
          size_t off = (size_t)row * ldc + col;
          float r = Res[off] + v;
          Cf[off] = r;
          Cb[off] = f2bf(r);
        } else if constexpr (EPI == 2) {
          if (col < NB) Cf[(size_t)row * ldc + col] = v;
        } else if constexpr (EPI == 3) {
          float p = __shfl_xor(v, 1);
          float a = v * sigm(v) * p;
          float a2 = __shfl_xor(a, 2);
          if ((lr & 3) == 0)
            *(u32*)&Cb[(size_t)row * DFF + (col >> 1)] = pk2(a, a2);
        } else {  // EPI == 4: nontemporal store (keep B L3-resident)
          __builtin_nontemporal_store(v, &Cf[(size_t)row * ldc + col]);
        }
      }
    }
}

// Streaming copy pad[row][0:NVOCAB] -> out[row][*], NT load+store.
__global__ __launch_bounds__(256) void k_copy_out(
    const float* __restrict__ pad, float* __restrict__ out)
{
  int row = blockIdx.x;
  const float* s = pad + (size_t)row * VPAD_LD;
  float* d = out + (size_t)row * NVOCAB;
  int t = threadIdx.x;
  int head = (int)((16 - (((size_t)d) & 15)) & 15) >> 2;
  if (t < head) d[t] = s[t];
  int nb = (NVOCAB - head) >> 2;
  const float* sb = s + head;
  float* db = d + head;
  for (int i = t; i < nb; i += 256) {
    f32x4 v;
    v.x = __builtin_nontemporal_load(&sb[i * 4 + 0]);
    v.y = __builtin_nontemporal_load(&sb[i * 4 + 1]);
    v.z = __builtin_nontemporal_load(&sb[i * 4 + 2]);
    v.w = __builtin_nontemporal_load(&sb[i * 4 + 3]);
    __builtin_nontemporal_store(v, (f32x4*)&db[i * 4]);
  }
  int t0 = head + nb * 4;
  int rem = NVOCAB - t0;
  if (t < rem) d[t0 + t] = s[t0 + t];
}

// ---------------------------------------------------------------------------
// 64x64 GEMM device body (NT, bf16), Cf = acc.
// ---------------------------------------------------------------------------
static __device__ __forceinline__ void gemm64_body(
    const u16* A, const u16* B, float* Cf,
    int m0, int n0, int K, int lda, int ldb, int ldc, char* smem)
{
  u16* As = (u16*)smem;
  u16* Bs = (u16*)(smem + 64 * 64 * 2);
  const int tid = threadIdx.x;
  const int l = tid & 63;
  const int wv = tid >> 6;
  const int wm = wv >> 1, wn = wv & 1;
  const int lr = l & 15, lg = l >> 4;

  uint4 aR[2], bR[2];
  f32x4 acc[2][2] = {};
  const int nk = K >> 6;

  auto loadAB = [&](int k0) {
#pragma unroll
    for (int c = 0; c < 2; ++c) {
      int id = c * 256 + tid;
      int row = id >> 3, kc = (id & 7) << 3;
      aR[c] = *(const uint4*)&A[(size_t)(m0 + row) * lda + k0 + kc];
      bR[c] = *(const uint4*)&B[(size_t)(n0 + row) * ldb + k0 + kc];
    }
  };
  auto stage = [&]() {
#pragma unroll
    for (int c = 0; c < 2; ++c) {
      int id = c * 256 + tid;
      int row = id >> 3, kc = (id & 7) << 3;
      *(uint4*)&As[row * 64 + kc] = aR[c];
      *(uint4*)&Bs[row * 64 + kc] = bR[c];
    }
  };

  loadAB(0);
  for (int s = 0; s < nk; ++s) {
    __syncthreads();
    stage();
    __syncthreads();
    if (s + 1 < nk) loadAB((s + 1) << 6);
#pragma unroll
    for (int kk = 0; kk < 2; ++kk) {
      bf16x8 fa[2], fb[2];
#pragma unroll
      for (int mi = 0; mi < 2; ++mi)
        fa[mi] = *(const bf16x8*)&As[(wm * 32 + mi * 16 + lr) * 64 + kk * 32 + lg * 8];
#pragma unroll
      for (int ni = 0; ni < 2; ++ni)
        fb[ni] = *(const bf16x8*)&Bs[(wn * 32 + ni * 16 + lr) * 64 + kk * 32 + lg * 8];
#pragma unroll
      for (int mi = 0; mi < 2; ++mi)
#pragma unroll
        for (int ni = 0; ni < 2; ++ni)
          acc[mi][ni] = __builtin_amdgcn_mfma_f32_16x16x32_bf16(fa[mi], fb[ni], acc[mi][ni], 0, 0, 0);
    }
  }

#pragma unroll
  for (int mi = 0; mi < 2; ++mi)
#pragma unroll
    for (int ni = 0; ni < 2; ++ni) {
      int col = n0 + wn * 32 + ni * 16 + lr;
#pragma unroll
      for (int j = 0; j < 4; ++j) {
        int row = m0 + wm * 32 + mi * 16 + lg * 4 + j;
        Cf[(size_t)row * ldc + col] = acc[mi][ni][j];
      }
    }
}

__global__ __launch_bounds__(256, 3) void k_gemm64(
    const u16* __restrict__ A, const u16* __restrict__ B,
    float* __restrict__ Cf, int K, int lda, int ldb, int ldc)
{
  __shared__ __align__(16) char smem[16384];
  gemm64_body(A, B, Cf, blockIdx.x * 64, blockIdx.y * 64, K, lda, ldb, ldc, smem);
}

// ---------------------------------------------------------------------------
// Fused: blocks [0,128) = gemm64 xin (x_bf @ WiT);
//        blocks [128,640) = scan_a (16 chunks of 16: E[b][c][d] end states)
// ---------------------------------------------------------------------------
__global__ __launch_bounds__(256, 3) void k_prep_fused(
    const u16* __restrict__ x_bf, const u16* __restrict__ WiT,
    float* __restrict__ xin,
    const float* __restrict__ x_f, float* __restrict__ E,
    const float* __restrict__ sgw, const float* __restrict__ sgb,
    const float* __restrict__ sdec)
{
  __shared__ __align__(16) char smem[16384];
  int bid = blockIdx.x;
  if (bid < 128) {
    gemm64_body(x_bf, WiT, xin, (bid & 31) * 64, (bid >> 5) * 64,
                DMODEL, DMODEL, DMODEL, DCELL, smem);
    return;
  }
  int tid = (bid - 128) * 256 + threadIdx.x;   // 131072 = 8b * 16c * 1024d
  int d = tid & 1023, bc = tid >> 10;
  int b = bc >> 4, c = bc & 15;
  float dec = sigm(sdec[0]);
  dec = fminf(fmaxf(dec, 0.01f), 0.99f);
  float gw = sgw[d], gb = sgb[d];
  size_t base = ((size_t)b * 256 + c * 16) * DMODEL + d;
  float h = 0.f;
  for (int t = 0; t < 16; ++t) {
    float xv = x_f[base + (size_t)t * DMODEL];
    h = h * dec + sigm(xv * gw + gb) * xv;
  }
  E[tid] = h;
}

// ---------------------------------------------------------------------------
// Fused top-8 + softmax + readout. Block = 4 rows; wave v owns row v (topk),
// then all 256 threads do readout (r_bf = xin + sum w_k cells[idx_k]).
// ---------------------------------------------------------------------------
__global__ __launch_bounds__(256) void k_cell_fused(
    const float* __restrict__ scores, const float* __restrict__ cells,
    const float* __restrict__ xin, u16* __restrict__ rb)
{
  __shared__ float sw[4][8];
  __shared__ int si[4][8];
  int row0 = blockIdx.x * 4;
  int wvid = threadIdx.x >> 6;
  int row = row0 + wvid;
  int l = threadIdx.x & 63;
  const float* s = scores + (size_t)row * NCELL;
  float v[8]; int ix[8];
#pragma unroll
  for (int i = 0; i < 8; ++i) { v[i] = -3.4e38f; ix[i] = 0x7fffffff; }
  for (int j = 0; j < 64; ++j) {
    float x = s[j * 64 + l];
    if (x > v[7]) {
      v[7] = x; ix[7] = j * 64 + l;
#pragma unroll
      for (int q = 7; q > 0; --q) {
        if (v[q] > v[q - 1]) {
          float tv = v[q]; v[q] = v[q - 1]; v[q - 1] = tv;
          int tt = ix[q]; ix[q] = ix[q - 1]; ix[q - 1] = tt;
        }
      }
    }
  }
  float ov[8]; int oi[8];
#pragma unroll
  for (int r = 0; r < 8; ++r) {
    float bv = v[0]; int bi = ix[0];
#pragma unroll
    for (int o = 32; o > 0; o >>= 1) {
      float tv = __shfl_xor(bv, o);
      int tb = __shfl_xor(bi, o);
      if (tv > bv || (tv == bv && tb < bi)) { bv = tv; bi = tb; }
    }
    ov[r] = bv; oi[r] = bi;
    if (bi == ix[0]) {
#pragma unroll
      for (int q = 0; q < 7; ++q) { v[q] = v[q + 1]; ix[q] = ix[q + 1]; }
      v[7] = -3.4e38f; ix[7] = 0x7fffffff;
    }
  }
  if (l == 0) {
    float m = ov[0], sum = 0.f, e[8];
#pragma unroll
    for (int r = 0; r < 8; ++r) { e[r] = __expf(ov[r] - m); sum += e[r]; }
    float inv = 1.0f / sum;
#pragma unroll
    for (int r = 0; r < 8; ++r) { sw[wvid][r] = e[r] * inv; si[wvid][r] = oi[r]; }
  }
  __syncthreads();
  int d = threadIdx.x;
#pragma unroll
  for (int r = 0; r < 4; ++r) {
    int rr = row0 + r;
    float acc = xin[(size_t)rr * DCELL + d];
#pragma unroll
    for (int k = 0; k < 8; ++k)
      acc += sw[r][k] * cells[(size_t)si[r][k] * DCELL + d];
    rb[(size_t)rr * DCELL + d] = f2bf(acc);
  }
}

// ---------------------------------------------------------------------------
// Fused scan_b + double rmsnorm. Block = (b,c): 16 chunks of 16 t-steps.
// x_f := rmsnorm(pre, nw); h2b := rmsnorm(x_f, fw) in bf16.
// ---------------------------------------------------------------------------
__global__ __launch_bounds__(1024) void k_scan_norm(
    float* __restrict__ x_f, const float* __restrict__ co,
    const float* __restrict__ E, u16* __restrict__ h2b,
    const float* __restrict__ sgw, const float* __restrict__ sgb,
    const float* __restrict__ ssc, const float* __restrict__ sdec,
    const float* __restrict__ csc, const float* __restrict__ nw,
    const float* __restrict__ fw)
{
  __shared__ float sm[16];
  int b = blockIdx.x >> 4, c = blockIdx.x & 15;
  int d = threadIdx.x;
  float dec = sigm(sdec[0]);
  dec = fminf(fmaxf(dec, 0.01f), 0.99f);
  float d2 = dec * dec, d4 = d2 * d2, d8 = d4 * d4;
  float d16 = d8 * d8;
  float cs = csc[0];
  float gw = sgw[d], gb = sgb[d], sc = ssc[d];
  float nwd = nw[d], fwd = fw[d];
  float h = 0.f;
  for (int cc = 0; cc < c; ++cc) h = h * d16 + E[((b << 4) + cc) * 1024 + d];
  size_t base = ((size_t)b * 256 + c * 16) * DMODEL + d;
  for (int t = 0; t < 16; ++t) {
    size_t o = base + (size_t)t * DMODEL;
    float xv = x_f[o];
    float g = sigm(xv * gw + gb);
    h = h * dec + g * xv;
    float pre = xv + cs * co[o] + h * sc;
    float s1 = blockReduce1024(pre * pre, sm);
    float inv = rsqrtf(s1 * (1.0f / DMODEL) + 1e-6f);
    float x1 = pre * inv * nwd;
    float s2 = blockReduce1024(x1 * x1, sm);
    float inv2 = rsqrtf(s2 * (1.0f / DMODEL) + 1e-6f);
    x_f[o] = x1;
    h2b[o] = f2bf(x1 * inv2 * fwd);
  }
}

// ---------------------------------------------------------------------------
// Per-layer weight transpose+convert fp32 [R,C] -> bf16 [C,R]; blocks >=
// 12800 flat-convert W_route.
// ---------------------------------------------------------------------------
__global__ void k_transpose_layer(
    const float* __restrict__ Wi, const float* __restrict__ Wo,
    const float* __restrict__ Wg, const float* __restrict__ Wu,
    const float* __restrict__ Wd, const float* __restrict__ Wr,
    u16* __restrict__ WiT, u16* __restrict__ WoT,
    u16* __restrict__ WguT, u16* __restrict__ WdT, u16* __restrict__ WrB)
{
  int bid = blockIdx.x;
  if (bid >= 12800) {
    int i = (bid - 12800) * 256 + threadIdx.x;
    const float4* s = (const float4*)(Wr + (size_t)i * 8);
    float4 a = s[0], b = s[1];
    *(uint4*)(WrB + (size_t)i * 8) =
        make_uint4(pk2(a.x, a.y), pk2(a.z, a.w), pk2(b.x, b.y), pk2(b.z, b.w));
    return;
  }
  const float* src; u16* dst; int R, C, t0, mul, add;
  if (bid < 256)       { src = Wi; dst = WiT;  R = 1024; C = 256;  t0 = bid;        mul = 1; add = 0; }
  else if (bid < 512)  { src = Wo; dst = WoT;  R = 256;  C = 1024; t0 = bid - 256;  mul = 1; add = 0; }
  else if (bid < 4608) { src = Wg; dst = WguT; R = 1024; C = 4096; t0 = bid - 512;  mul = 2; add = 0; }
  else if (bid < 8704) { src = Wu; dst = WguT; R = 1024; C = 4096; t0 = bid - 4608; mul = 2; add = 1; }
  else                 { src = Wd; dst = WdT;  R = 4096; C = 1024; t0 = bid - 8704; mul = 1; add = 0; }
  int tC = C >> 5;
  int r0 = (t0 / tC) << 5, c0 = (t0 % tC) << 5;
  __shared__ float tile[32][33];
  int ty = threadIdx.x >> 3;
  int tx = (threadIdx.x & 7) << 2;
  float4 v = *(const float4*)&src[(size_t)(r0 + ty) * C + c0 + tx];
  tile[ty][tx] = v.x; tile[ty][tx + 1] = v.y; tile[ty][tx + 2] = v.z; tile[ty][tx + 3] = v.w;
  __syncthreads();
  float a = tile[tx][ty], b = tile[tx + 1][ty], c = tile[tx + 2][ty], d = tile[tx + 3][ty];
  *(uint2*)&dst[((size_t)(c0 + ty) * mul + add) * R + r0 + tx] = make_uint2(pk2(a, b), pk2(c, d));
}

__global__ void k_embed_norm(const int* __restrict__ tok, const float* __restrict__ emb,
                             const float* __restrict__ w, float* __restrict__ xf,
                             u16* __restrict__ xb)
{
  int row = blockIdx.x;
  int t = tok[row];
  float4 v = ((const float4*)(emb + (size_t)t * DMODEL))[threadIdx.x];
  float tot = blockReduceSum(v.x * v.x + v.y * v.y + v.z * v.z + v.w * v.w);
  float inv = rsqrtf(tot * (1.0f / DMODEL) + 1e-6f);
  int d0 = threadIdx.x << 2;
  float4 wv = *(const float4*)(w + d0);
  float4 o;
  o.x = v.x * inv * wv.x; o.y = v.y * inv * wv.y;
  o.z = v.z * inv * wv.z; o.w = v.w * inv * wv.w;
  *(float4*)(xf + (size_t)row * DMODEL + d0) = o;
  *(uint2*)(xb + (size_t)row * DMODEL + d0) = make_uint2(pk2(o.x, o.y), pk2(o.z, o.w));
}

// Tail fused: blocks [0,2048) rmsnorm(x_f)*ln_out -> xf_bf;
// blocks [2048, ...) embed fp32->bf16 flat convert.
__global__ __launch_bounds__(256) void k_tail(
    const float* __restrict__ xf, const float* __restrict__ w,
    u16* __restrict__ ob, const float* __restrict__ emb,
    u16* __restrict__ emb_bf)
{
  int bid = blockIdx.x;
  if (bid >= 2048) {
    int i = (bid - 2048) * 256 + threadIdx.x;
    if (i >= NVOCAB * (DMODEL / 8)) return;
    const float4* s = (const float4*)(emb + (size_t)i * 8);
    float4 a = s[0], b = s[1];
    *(uint4*)(emb_bf + (size_t)i * 8) =
        make_uint4(pk2(a.x, a.y), pk2(a.z, a.w), pk2(b.x, b.y), pk2(b.z, b.w));
    return;
  }
  int row = bid;
  float4 v = ((const float4*)(xf + (size_t)row * DMODEL))[threadIdx.x];
  float tot = blockReduceSum(v.x * v.x + v.y * v.y + v.z * v.z + v.w * v.w);
  float inv = rsqrtf(tot * (1.0f / DMODEL) + 1e-6f);
  int d0 = threadIdx.x << 2;
  float4 wv = *(const float4*)(w + d0);
  *(uint2*)(ob + (size_t)row * DMODEL + d0) =
      make_uint2(pk2(v.x * inv * wv.x, v.y * inv * wv.y),
                 pk2(v.z * inv * wv.z, v.w * inv * wv.w));
}

// ---------------------------------------------------------------------------
extern "C" void kernel_launch(void* const* d_in, const int* in_sizes, int n_in,
                              void* d_out, int out_size, void* d_ws, size_t ws_size,
                              hipStream_t stream)
{
  const int*   tokens  = (const int*)d_in[0];
  const float* embed   = (const float*)d_in[1];
  const float* ln_in_w = (const float*)d_in[2];
  const float* ln_out_w= (const float*)d_in[3];
  const float* W_route = (const float*)d_in[4];
  const float* cells   = (const float*)d_in[5];
  const float* W_in    = (const float*)d_in[6];
  const float* W_out   = (const float*)d_in[7];
  const float* sdec    = (const float*)d_in[8];
  const float* sgw     = (const float*)d_in[9];
  const float* sgb     = (const float*)d_in[10];
  const float* ssc     = (const float*)d_in[11];
  const float* csc     = (const float*)d_in[12];
  const float* Wg      = (const float*)d_in[13];
  const float* Wu      = (const float*)d_in[14];
  const float* Wd      = (const float*)d_in[15];
  const float* ffw     = (const float*)d_in[16];
  const float* nrw     = (const float*)d_in[17];
  float* out = (float*)d_out;
  (void)in_sizes; (void)n_in; (void)out_size;

  char* ws = (char*)d_ws;
  size_t off = 0;
  auto alloc = [&](size_t bytes) -> void* {
    void* p = ws + off;
    off += (bytes + 255) & ~(size_t)255;
    return p;
  };

  // ---- epoch 1 (layer loop scratch) ----
  float* scores = (float*)alloc((size_t)MTOK * NCELL * 4);
  u16*  act_bf  = (u16*)alloc((size_t)MTOK * DFF * 2);
  float* x_f    = (float*)alloc((size_t)MTOK * DMODEL * 4);
  u16*  x_bf    = (u16*)alloc((size_t)MTOK * DMODEL * 2);
  u16*  h2_bf   = (u16*)alloc((size_t)MTOK * DMODEL * 2);
  float* xin    = (float*)alloc((size_t)MTOK * DCELL * 4);
  u16*  r_bf    = (u16*)alloc((size_t)MTOK * DCELL * 2);
  float* cellout= (float*)alloc((size_t)MTOK * DMODEL * 4);
  u16*  WiT     = (u16*)alloc((size_t)DCELL * DMODEL * 2);
  u16*  WoT     = (u16*)alloc((size_t)DMODEL * DCELL * 2);
  u16*  WguT    = (u16*)alloc((size_t)8192 * DMODEL * 2);
  u16*  WdT     = (u16*)alloc((size_t)DMODEL * DFF * 2);
  u16*  WrB     = (u16*)alloc((size_t)NCELL * DMODEL * 2);
  float* E      = (float*)alloc((size_t)131072 * 4);
  // ---- persistent tail (above embed_bf's 103 MB span) ----
  if (off < ((size_t)108 << 20)) off = (size_t)108 << 20;
  u16*  xf_bf   = (u16*)alloc((size_t)MTOK * DMODEL * 2);
  float* vpad   = (float*)alloc((size_t)MTOK * VPAD_LD * 4);   // 412 MB
  size_t need_pad = off;
  // ---- epoch 2 overlay (written only after layer loop) ----
  u16*  embed_bf = (u16*)ws;

  const bool use_pad = (ws_size >= need_pad);

  k_embed_norm<<<MTOK, 256, 0, stream>>>(tokens, embed, ln_in_w, x_f, x_bf);

  for (int lay = 0; lay < 8; ++lay) {
    const float* Wi_l = W_in  + (size_t)lay * DMODEL * DCELL;
    const float* Wo_l = W_out + (size_t)lay * DCELL * DMODEL;
    const float* Wg_l = Wg    + (size_t)lay * DMODEL * DFF;
    const float* Wu_l = Wu    + (size_t)lay * DMODEL * DFF;
    const float* Wd_l = Wd    + (size_t)lay * DFF * DMODEL;
    const float* Wr_l = W_route + (size_t)lay * NCELL * DMODEL;
    const float* cells_l = cells + (size_t)lay * NCELL * DCELL;

    // weight prep: transposes + W_route bf16 convert
    k_transpose_layer<<<14848, 256, 0, stream>>>(Wi_l, Wo_l, Wg_l, Wu_l, Wd_l,
                                                 Wr_l, WiT, WoT, WguT, WdT, WrB);
    // scores = x @ Wr^T / 32
    k_gemm_v3<128, 128, 0><<<512, 256, 0, stream>>>(x_bf, WrB, scores, nullptr,
        nullptr, NCELL, DMODEL, NCELL, 0.03125f);
    // xin GEMM + scan pass A (16 chunks)
    k_prep_fused<<<640, 256, 0, stream>>>(x_bf, WiT, xin, x_f, E,
        sgw + lay * DMODEL, sgb + lay * DMODEL, sdec + lay);
    // top-8 + softmax + readout
    k_cell_fused<<<512, 256, 0, stream>>>(scores, cells_l, xin, r_bf);
    // cell_out = readout @ W_out
    k_gemm64<<<dim3(32, 16), 256, 0, stream>>>(r_bf, WoT, cellout,
        DCELL, DCELL, DCELL, DMODEL);
    // scan pass B + both rmsnorms (16 chunks -> 128 blocks)
    k_scan_norm<<<128, 1024, 0, stream>>>(x_f, cellout, E, h2_bf,
        sgw + lay * DMODEL, sgb + lay * DMODEL, ssc + lay * DMODEL,
        sdec + lay, csc + lay, nrw + lay * DMODEL, ffw + lay * DMODEL);
    // act = silu(g)*u fused epilogue
    k_gemm_v3<128, 128, 3><<<1024, 256, 0, stream>>>(h2_bf, WguT, nullptr, act_bf,
        nullptr, 8192, DMODEL, 0, 1.0f);
    // x = x + act @ Wd
    k_gemm_v3<64, 64, 1><<<512, 256, 0, stream>>>(act_bf, WdT, x_f, x_bf, x_f,
        DMODEL, DFF, DMODEL, 1.0f);
  }

  // tail: final norm + embed bf16 convert (fused)
  k_tail<<<2048 + 25129, 256, 0, stream>>>(x_f, ln_out_w, xf_bf, embed, embed_bf);
  // logits GEMM: TM=128 x TN=64 (24 KB LDS -> ~6 blocks/CU TLP) -> pad -> copy
  if (use_pad) {
    k_gemm_v3<128, 64, 4><<<12576, 256, 0, stream>>>(xf_bf, embed_bf, vpad, nullptr,
        nullptr, NVOCAB, DMODEL, VPAD_LD, 1.0f);
    k_copy_out<<<MTOK, 256, 0, stream>>>(vpad, out);
  } else {
    k_gemm_v3<128, 64, 2><<<12576, 256, 0, stream>>>(xf_bf, embed_bf, out, nullptr,
        nullptr, NVOCAB, DMODEL, NVOCAB, 1.0f);
  }
}

// Round 13
// 2663.832 us; speedup vs baseline: 2.2223x; 1.0432x over previous
//
#include <hip/hip_runtime.h>
#include <stdint.h>

typedef __attribute__((ext_vector_type(8))) short bf16x8;
typedef __attribute__((ext_vector_type(4))) float f32x4;
typedef unsigned short u16;
typedef unsigned int u32;

#define MTOK 2048
#define DMODEL 1024
#define NCELL 4096
#define DCELL 256
#define DFF 4096
#define NVOCAB 50257
#define VPAD_LD 50304          // 393 * 128, aligned pad leading dim

static __device__ __forceinline__ u16 f2bf(float f) {
  u32 u = __builtin_bit_cast(u32, f);
  u = (u + 0x7FFFu + ((u >> 16) & 1u)) >> 16;
  return (u16)u;
}
static __device__ __forceinline__ u32 pk2(float a, float b) {
  return (u32)f2bf(a) | ((u32)f2bf(b) << 16);
}
static __device__ __forceinline__ float sigm(float x) { return 1.0f / (1.0f + __expf(-x)); }

// async global->LDS, 16 B per lane; lds dest = wave-uniform base + lane*16
static __device__ __forceinline__ void glds16(const void* g, void* l) {
  __builtin_amdgcn_global_load_lds(
      (const __attribute__((address_space(1))) void*)g,
      (__attribute__((address_space(3))) void*)l, 16, 0, 0);
}

static __device__ __forceinline__ float blockReduceSum(float v) {
#pragma unroll
  for (int o = 32; o > 0; o >>= 1) v += __shfl_xor(v, o);
  __shared__ float sm[4];
  __syncthreads();
  if ((threadIdx.x & 63) == 0) sm[threadIdx.x >> 6] = v;
  __syncthreads();
  return sm[0] + sm[1] + sm[2] + sm[3];
}

// 1024-thread block reduce (16 waves)
static __device__ __forceinline__ float blockReduce1024(float v, float* sm) {
#pragma unroll
  for (int o = 32; o > 0; o >>= 1) v += __shfl_xor(v, o);
  if ((threadIdx.x & 63) == 0) sm[threadIdx.x >> 6] = v;
  __syncthreads();
  float r = 0.f;
#pragma unroll
  for (int i = 0; i < 16; ++i) r += sm[i];
  __syncthreads();
  return r;
}

// ---------------------------------------------------------------------------
// m97-style GEMM device body: C[2048,N] = A[2048,K](bf16) x B[N,K]^T(bf16)
// TM,TN in {64,128}. global_load_lds staging, 2 barriers per K-step.
// Virtual 1D grid (bid in [0,T)), XCD-affine swizzle. 4 waves 2x2.
// EPI 0: Cf = alpha*acc          EPI 1: residual r=Res+acc -> Cf,f2bf->Cb
// EPI 2: predicated col<NB       EPI 3: fused SwiGLU -> bf16 Cb
// EPI 4: nontemporal aligned f32 store (vpad)
// ---------------------------------------------------------------------------
template<int TM, int TN, int EPI>
static __device__ __forceinline__ void v3_body(
    int bid, int T, char* smem,
    const u16* A, const u16* B,
    float* Cf, u16* Cb, const float* Res,
    int NB, int K, int ldc, float alpha)
{
  u16* As = (u16*)smem;
  u16* Bs = (u16*)(smem + TM * 128);
  constexpr int MI = TM / 32;
  constexpr int NI = TN / 32;
  constexpr int ACH = TM / 32;
  constexpr int BCH = TN / 32;
  constexpr int MB = 2048 / TM;
  const int tid = threadIdx.x;
  const int w = (bid & 7) * (T >> 3) + (bid >> 3);
  const int m0 = (w % MB) * TM;
  const int n0 = (w / MB) * TN;
  const int l = tid & 63;
  const int wv = tid >> 6;
  const int wm = wv >> 1, wn = wv & 1;
  const int lr = l & 15, lg = l >> 4;
  const int wbase = tid & ~63;

  f32x4 acc[MI][NI] = {};

  const int row_ = tid >> 3;
  const int kc_ = (tid & 7) << 3;
  const int nk = K >> 6;

  for (int s = 0; s < nk; ++s) {
    const int k0 = s << 6;
#pragma unroll
    for (int c = 0; c < ACH; ++c) {
      int row = c * 32 + row_;
      glds16(&A[(size_t)(m0 + row) * K + k0 + kc_],
             &As[(size_t)(c * 256 + wbase) * 8]);
    }
#pragma unroll
    for (int c = 0; c < BCH; ++c) {
      int row = c * 32 + row_;
      int gr = n0 + row; if (gr > NB - 1) gr = NB - 1;
      glds16(&B[(size_t)gr * K + k0 + kc_],
             &Bs[(size_t)(c * 256 + wbase) * 8]);
    }
    __syncthreads();
#pragma unroll
    for (int kk = 0; kk < 2; ++kk) {
      bf16x8 fa[MI], fb[NI];
#pragma unroll
      for (int mi = 0; mi < MI; ++mi)
        fa[mi] = *(const bf16x8*)&As[(wm * (TM / 2) + mi * 16 + lr) * 64 + kk * 32 + lg * 8];
#pragma unroll
      for (int ni = 0; ni < NI; ++ni)
        fb[ni] = *(const bf16x8*)&Bs[(wn * (TN / 2) + ni * 16 + lr) * 64 + kk * 32 + lg * 8];
#pragma unroll
      for (int mi = 0; mi < MI; ++mi)
#pragma unroll
        for (int ni = 0; ni < NI; ++ni)
          acc[mi][ni] = __builtin_amdgcn_mfma_f32_16x16x32_bf16(fa[mi], fb[ni], acc[mi][ni], 0, 0, 0);
    }
    __syncthreads();
  }

#pragma unroll
  for (int mi = 0; mi < MI; ++mi)
#pragma unroll
    for (int ni = 0; ni < NI; ++ni) {
      int col = n0 + wn * (TN / 2) + ni * 16 + lr;
#pragma unroll
      for (int j = 0; j < 4; ++j) {
        int row = m0 + wm * (TM / 2) + mi * 16 + lg * 4 + j;
        float v = acc[mi][ni][j];
        if constexpr (EPI == 0) {
          Cf[(size_t)row * ldc + col] = v * alpha;
        } else if constexpr (EPI == 1) {
          size_t off = (size_t)row * ldc + col;
          float r = Res[off] + v;
          Cf[off] = r;
          Cb[off] = f2bf(r);
        } else if constexpr (EPI == 2) {
          if (col < NB) Cf[(size_t)row * ldc + col] = v;
        } else if constexpr (EPI == 3) {
          float p = __shfl_xor(v, 1);
          float a = v * sigm(v) * p;
          float a2 = __shfl_xor(a, 2);
          if ((lr & 3) == 0)
            *(u32*)&Cb[(size_t)row * DFF + (col >> 1)] = pk2(a, a2);
        } else {  // EPI == 4
          __builtin_nontemporal_store(v, &Cf[(size_t)row * ldc + col]);
        }
      }
    }
}

template<int TM, int TN, int EPI>
__global__ __launch_bounds__(256, 3) void k_gemm_v3(
    const u16* __restrict__ A, const u16* __restrict__ B,
    float* __restrict__ Cf, u16* __restrict__ Cb, const float* __restrict__ Res,
    int NB, int K, int ldc, float alpha)
{
  __shared__ __align__(16) char smem[(TM + TN) * 128];
  v3_body<TM, TN, EPI>(blockIdx.x, gridDim.x, smem, A, B, Cf, Cb, Res,
                       NB, K, ldc, alpha);
}

// ---------------------------------------------------------------------------
// Weight transpose+convert body: fp32 [R,C] -> bf16 [C,R]; bid >= 12800
// flat-converts W_route. bid in [0, 14848).
// ---------------------------------------------------------------------------
static __device__ __forceinline__ void transpose_body(
    int bid, char* smem,
    const float* Wi, const float* Wo, const float* Wg, const float* Wu,
    const float* Wd, const float* Wr,
    u16* WiT, u16* WoT, u16* WguT, u16* WdT, u16* WrB)
{
  if (bid >= 12800) {
    int i = (bid - 12800) * 256 + threadIdx.x;
    const float4* s = (const float4*)(Wr + (size_t)i * 8);
    float4 a = s[0], b = s[1];
    *(uint4*)(WrB + (size_t)i * 8) =
        make_uint4(pk2(a.x, a.y), pk2(a.z, a.w), pk2(b.x, b.y), pk2(b.z, b.w));
    return;
  }
  const float* src; u16* dst; int R, C, t0, mul, add;
  if (bid < 256)       { src = Wi; dst = WiT;  R = 1024; C = 256;  t0 = bid;        mul = 1; add = 0; }
  else if (bid < 512)  { src = Wo; dst = WoT;  R = 256;  C = 1024; t0 = bid - 256;  mul = 1; add = 0; }
  else if (bid < 4608) { src = Wg; dst = WguT; R = 1024; C = 4096; t0 = bid - 512;  mul = 2; add = 0; }
  else if (bid < 8704) { src = Wu; dst = WguT; R = 1024; C = 4096; t0 = bid - 4608; mul = 2; add = 1; }
  else                 { src = Wd; dst = WdT;  R = 4096; C = 1024; t0 = bid - 8704; mul = 1; add = 0; }
  int tC = C >> 5;
  int r0 = (t0 / tC) << 5, c0 = (t0 % tC) << 5;
  float (*tile)[33] = (float(*)[33])smem;
  int ty = threadIdx.x >> 3;
  int tx = (threadIdx.x & 7) << 2;
  float4 v = *(const float4*)&src[(size_t)(r0 + ty) * C + c0 + tx];
  tile[ty][tx] = v.x; tile[ty][tx + 1] = v.y; tile[ty][tx + 2] = v.z; tile[ty][tx + 3] = v.w;
  __syncthreads();
  float a = tile[tx][ty], b = tile[tx + 1][ty], c = tile[tx + 2][ty], d = tile[tx + 3][ty];
  *(uint2*)&dst[((size_t)(c0 + ty) * mul + add) * R + r0 + tx] = make_uint2(pk2(a, b), pk2(c, d));
}

__global__ void k_transpose_layer(
    const float* __restrict__ Wi, const float* __restrict__ Wo,
    const float* __restrict__ Wg, const float* __restrict__ Wu,
    const float* __restrict__ Wd, const float* __restrict__ Wr,
    u16* __restrict__ WiT, u16* __restrict__ WoT,
    u16* __restrict__ WguT, u16* __restrict__ WdT, u16* __restrict__ WrB)
{
  __shared__ __align__(16) char smem[4224];
  transpose_body(blockIdx.x, smem, Wi, Wo, Wg, Wu, Wd, Wr,
                 WiT, WoT, WguT, WdT, WrB);
}

// ---------------------------------------------------------------------------
// Fused: blocks [0,512) = Wd GEMM (64x64, residual epilogue);
//        blocks [512,15360) = weight prep (transpose+convert) for NEXT layer.
// Overlaps memory-bound transpose with MFMA-bound GEMM; saves a launch.
// ---------------------------------------------------------------------------
__global__ __launch_bounds__(256, 3) void k_wd_prep(
    const u16* __restrict__ act, const u16* __restrict__ WdT_cur,
    float* __restrict__ x_f, u16* __restrict__ x_bf,
    const float* __restrict__ Wi, const float* __restrict__ Wo,
    const float* __restrict__ Wg, const float* __restrict__ Wu,
    const float* __restrict__ Wd, const float* __restrict__ Wr,
    u16* __restrict__ WiT, u16* __restrict__ WoT,
    u16* __restrict__ WguT, u16* __restrict__ WdT_nxt, u16* __restrict__ WrB)
{
  __shared__ __align__(16) char smem[16384];
  int bid = blockIdx.x;
  if (bid < 512) {
    v3_body<64, 64, 1>(bid, 512, smem, act, WdT_cur, x_f, x_bf, x_f,
                       DMODEL, DFF, DMODEL, 1.0f);
  } else {
    transpose_body(bid - 512, smem, Wi, Wo, Wg, Wu, Wd, Wr,
                   WiT, WoT, WguT, WdT_nxt, WrB);
  }
}

// Streaming copy pad[row][0:NVOCAB] -> out[row][*], NT load+store.
__global__ __launch_bounds__(256) void k_copy_out(
    const float* __restrict__ pad, float* __restrict__ out)
{
  int row = blockIdx.x;
  const float* s = pad + (size_t)row * VPAD_LD;
  float* d = out + (size_t)row * NVOCAB;
  int t = threadIdx.x;
  int head = (int)((16 - (((size_t)d) & 15)) & 15) >> 2;
  if (t < head) d[t] = s[t];
  int nb = (NVOCAB - head) >> 2;
  const float* sb = s + head;
  float* db = d + head;
  for (int i = t; i < nb; i += 256) {
    f32x4 v;
    v.x = __builtin_nontemporal_load(&sb[i * 4 + 0]);
    v.y = __builtin_nontemporal_load(&sb[i * 4 + 1]);
    v.z = __builtin_nontemporal_load(&sb[i * 4 + 2]);
    v.w = __builtin_nontemporal_load(&sb[i * 4 + 3]);
    __builtin_nontemporal_store(v, (f32x4*)&db[i * 4]);
  }
  int t0 = head + nb * 4;
  int rem = NVOCAB - t0;
  if (t < rem) d[t0 + t] = s[t0 + t];
}

// ---------------------------------------------------------------------------
// 64x64 GEMM device body (NT, bf16), Cf = acc. (reg-staged; small matmuls)
// ---------------------------------------------------------------------------
static __device__ __forceinline__ void gemm64_body(
    const u16* A, const u16* B, float* Cf,
    int m0, int n0, int K, int lda, int ldb, int ldc, char* smem)
{
  u16* As = (u16*)smem;
  u16* Bs = (u16*)(smem + 64 * 64 * 2);
  const int tid = threadIdx.x;
  const int l = tid & 63;
  const int wv = tid >> 6;
  const int wm = wv >> 1, wn = wv & 1;
  const int lr = l & 15, lg = l >> 4;

  uint4 aR[2], bR[2];
  f32x4 acc[2][2] = {};
  const int nk = K >> 6;

  auto loadAB = [&](int k0) {
#pragma unroll
    for (int c = 0; c < 2; ++c) {
      int id = c * 256 + tid;
      int row = id >> 3, kc = (id & 7) << 3;
      aR[c] = *(const uint4*)&A[(size_t)(m0 + row) * lda + k0 + kc];
      bR[c] = *(const uint4*)&B[(size_t)(n0 + row) * ldb + k0 + kc];
    }
  };
  auto stage = [&]() {
#pragma unroll
    for (int c = 0; c < 2; ++c) {
      int id = c * 256 + tid;
      int row = id >> 3, kc = (id & 7) << 3;
      *(uint4*)&As[row * 64 + kc] = aR[c];
      *(uint4*)&Bs[row * 64 + kc] = bR[c];
    }
  };

  loadAB(0);
  for (int s = 0; s < nk; ++s) {
    __syncthreads();
    stage();
    __syncthreads();
    if (s + 1 < nk) loadAB((s + 1) << 6);
#pragma unroll
    for (int kk = 0; kk < 2; ++kk) {
      bf16x8 fa[2], fb[2];
#pragma unroll
      for (int mi = 0; mi < 2; ++mi)
        fa[mi] = *(const bf16x8*)&As[(wm * 32 + mi * 16 + lr) * 64 + kk * 32 + lg * 8];
#pragma unroll
      for (int ni = 0; ni < 2; ++ni)
        fb[ni] = *(const bf16x8*)&Bs[(wn * 32 + ni * 16 + lr) * 64 + kk * 32 + lg * 8];
#pragma unroll
      for (int mi = 0; mi < 2; ++mi)
#pragma unroll
        for (int ni = 0; ni < 2; ++ni)
          acc[mi][ni] = __builtin_amdgcn_mfma_f32_16x16x32_bf16(fa[mi], fb[ni], acc[mi][ni], 0, 0, 0);
    }
  }

#pragma unroll
  for (int mi = 0; mi < 2; ++mi)
#pragma unroll
    for (int ni = 0; ni < 2; ++ni) {
      int col = n0 + wn * 32 + ni * 16 + lr;
#pragma unroll
      for (int j = 0; j < 4; ++j) {
        int row = m0 + wm * 32 + mi * 16 + lg * 4 + j;
        Cf[(size_t)row * ldc + col] = acc[mi][ni][j];
      }
    }
}

__global__ __launch_bounds__(256, 3) void k_gemm64(
    const u16* __restrict__ A, const u16* __restrict__ B,
    float* __restrict__ Cf, int K, int lda, int ldb, int ldc)
{
  __shared__ __align__(16) char smem[16384];
  gemm64_body(A, B, Cf, blockIdx.x * 64, blockIdx.y * 64, K, lda, ldb, ldc, smem);
}

// ---------------------------------------------------------------------------
// Fused: blocks [0,128) = gemm64 xin (x_bf @ WiT);
//        blocks [128,640) = scan_a (16 chunks of 16: E[b][c][d] end states)
// ---------------------------------------------------------------------------
__global__ __launch_bounds__(256, 3) void k_prep_fused(
    const u16* __restrict__ x_bf, const u16* __restrict__ WiT,
    float* __restrict__ xin,
    const float* __restrict__ x_f, float* __restrict__ E,
    const float* __restrict__ sgw, const float* __restrict__ sgb,
    const float* __restrict__ sdec)
{
  __shared__ __align__(16) char smem[16384];
  int bid = blockIdx.x;
  if (bid < 128) {
    gemm64_body(x_bf, WiT, xin, (bid & 31) * 64, (bid >> 5) * 64,
                DMODEL, DMODEL, DMODEL, DCELL, smem);
    return;
  }
  int tid = (bid - 128) * 256 + threadIdx.x;   // 131072 = 8b * 16c * 1024d
  int d = tid & 1023, bc = tid >> 10;
  int b = bc >> 4, c = bc & 15;
  float dec = sigm(sdec[0]);
  dec = fminf(fmaxf(dec, 0.01f), 0.99f);
  float gw = sgw[d], gb = sgb[d];
  size_t base = ((size_t)b * 256 + c * 16) * DMODEL + d;
  float h = 0.f;
  for (int t = 0; t < 16; ++t) {
    float xv = x_f[base + (size_t)t * DMODEL];
    h = h * dec + sigm(xv * gw + gb) * xv;
  }
  E[tid] = h;
}

// ---------------------------------------------------------------------------
// Fused top-8 + softmax + readout. Block = 4 rows.
// ---------------------------------------------------------------------------
__global__ __launch_bounds__(256) void k_cell_fused(
    const float* __restrict__ scores, const float* __restrict__ cells,
    const float* __restrict__ xin, u16* __restrict__ rb)
{
  __shared__ float sw[4][8];
  __shared__ int si[4][8];
  int row0 = blockIdx.x * 4;
  int wvid = threadIdx.x >> 6;
  int row = row0 + wvid;
  int l = threadIdx.x & 63;
  const float* s = scores + (size_t)row * NCELL;
  float v[8]; int ix[8];
#pragma unroll
  for (int i = 0; i < 8; ++i) { v[i] = -3.4e38f; ix[i] = 0x7fffffff; }
  for (int j = 0; j < 64; ++j) {
    float x = s[j * 64 + l];
    if (x > v[7]) {
      v[7] = x; ix[7] = j * 64 + l;
#pragma unroll
      for (int q = 7; q > 0; --q) {
        if (v[q] > v[q - 1]) {
          float tv = v[q]; v[q] = v[q - 1]; v[q - 1] = tv;
          int tt = ix[q]; ix[q] = ix[q - 1]; ix[q - 1] = tt;
        }
      }
    }
  }
  float ov[8]; int oi[8];
#pragma unroll
  for (int r = 0; r < 8; ++r) {
    float bv = v[0]; int bi = ix[0];
#pragma unroll
    for (int o = 32; o > 0; o >>= 1) {
      float tv = __shfl_xor(bv, o);
      int tb = __shfl_xor(bi, o);
      if (tv > bv || (tv == bv && tb < bi)) { bv = tv; bi = tb; }
    }
    ov[r] = bv; oi[r] = bi;
    if (bi == ix[0]) {
#pragma unroll
      for (int q = 0; q < 7; ++q) { v[q] = v[q + 1]; ix[q] = ix[q + 1]; }
      v[7] = -3.4e38f; ix[7] = 0x7fffffff;
    }
  }
  if (l == 0) {
    float m = ov[0], sum = 0.f, e[8];
#pragma unroll
    for (int r = 0; r < 8; ++r) { e[r] = __expf(ov[r] - m); sum += e[r]; }
    float inv = 1.0f / sum;
#pragma unroll
    for (int r = 0; r < 8; ++r) { sw[wvid][r] = e[r] * inv; si[wvid][r] = oi[r]; }
  }
  __syncthreads();
  int d = threadIdx.x;
#pragma unroll
  for (int r = 0; r < 4; ++r) {
    int rr = row0 + r;
    float acc = xin[(size_t)rr * DCELL + d];
#pragma unroll
    for (int k = 0; k < 8; ++k)
      acc += sw[r][k] * cells[(size_t)si[r][k] * DCELL + d];
    rb[(size_t)rr * DCELL + d] = f2bf(acc);
  }
}

// ---------------------------------------------------------------------------
// Fused scan_b + double rmsnorm. Block = (b,c): 16 chunks of 16 t-steps.
// ---------------------------------------------------------------------------
__global__ __launch_bounds__(1024) void k_scan_norm(
    float* __restrict__ x_f, const float* __restrict__ co,
    const float* __restrict__ E, u16* __restrict__ h2b,
    const float* __restrict__ sgw, const float* __restrict__ sgb,
    const float* __restrict__ ssc, const float* __restrict__ sdec,
    const float* __restrict__ csc, const float* __restrict__ nw,
    const float* __restrict__ fw)
{
  __shared__ float sm[16];
  int b = blockIdx.x >> 4, c = blockIdx.x & 15;
  int d = threadIdx.x;
  float dec = sigm(sdec[0]);
  dec = fminf(fmaxf(dec, 0.01f), 0.99f);
  float d2 = dec * dec, d4 = d2 * d2, d8 = d4 * d4;
  float d16 = d8 * d8;
  float cs = csc[0];
  float gw = sgw[d], gb = sgb[d], sc = ssc[d];
  float nwd = nw[d], fwd = fw[d];
  float h = 0.f;
  for (int cc = 0; cc < c; ++cc) h = h * d16 + E[((b << 4) + cc) * 1024 + d];
  size_t base = ((size_t)b * 256 + c * 16) * DMODEL + d;
  for (int t = 0; t < 16; ++t) {
    size_t o = base + (size_t)t * DMODEL;
    float xv = x_f[o];
    float g = sigm(xv * gw + gb);
    h = h * dec + g * xv;
    float pre = xv + cs * co[o] + h * sc;
    float s1 = blockReduce1024(pre * pre, sm);
    float inv = rsqrtf(s1 * (1.0f / DMODEL) + 1e-6f);
    float x1 = pre * inv * nwd;
    float s2 = blockReduce1024(x1 * x1, sm);
    float inv2 = rsqrtf(s2 * (1.0f / DMODEL) + 1e-6f);
    x_f[o] = x1;
    h2b[o] = f2bf(x1 * inv2 * fwd);
  }
}

__global__ void k_embed_norm(const int* __restrict__ tok, const float* __restrict__ emb,
                             const float* __restrict__ w, float* __restrict__ xf,
                             u16* __restrict__ xb)
{
  int row = blockIdx.x;
  int t = tok[row];
  float4 v = ((const float4*)(emb + (size_t)t * DMODEL))[threadIdx.x];
  float tot = blockReduceSum(v.x * v.x + v.y * v.y + v.z * v.z + v.w * v.w);
  float inv = rsqrtf(tot * (1.0f / DMODEL) + 1e-6f);
  int d0 = threadIdx.x << 2;
  float4 wv = *(const float4*)(w + d0);
  float4 o;
  o.x = v.x * inv * wv.x; o.y = v.y * inv * wv.y;
  o.z = v.z * inv * wv.z; o.w = v.w * inv * wv.w;
  *(float4*)(xf + (size_t)row * DMODEL + d0) = o;
  *(uint2*)(xb + (size_t)row * DMODEL + d0) = make_uint2(pk2(o.x, o.y), pk2(o.z, o.w));
}

// Tail fused: blocks [0,2048) rmsnorm(x_f)*ln_out -> xf_bf;
// blocks [2048, ...) embed fp32->bf16 flat convert.
__global__ __launch_bounds__(256) void k_tail(
    const float* __restrict__ xf, const float* __restrict__ w,
    u16* __restrict__ ob, const float* __restrict__ emb,
    u16* __restrict__ emb_bf)
{
  int bid = blockIdx.x;
  if (bid >= 2048) {
    int i = (bid - 2048) * 256 + threadIdx.x;
    if (i >= NVOCAB * (DMODEL / 8)) return;
    const float4* s = (const float4*)(emb + (size_t)i * 8);
    float4 a = s[0], b = s[1];
    *(uint4*)(emb_bf + (size_t)i * 8) =
        make_uint4(pk2(a.x, a.y), pk2(a.z, a.w), pk2(b.x, b.y), pk2(b.z, b.w));
    return;
  }
  int row = bid;
  float4 v = ((const float4*)(xf + (size_t)row * DMODEL))[threadIdx.x];
  float tot = blockReduceSum(v.x * v.x + v.y * v.y + v.z * v.z + v.w * v.w);
  float inv = rsqrtf(tot * (1.0f / DMODEL) + 1e-6f);
  int d0 = threadIdx.x << 2;
  float4 wv = *(const float4*)(w + d0);
  *(uint2*)(ob + (size_t)row * DMODEL + d0) =
      make_uint2(pk2(v.x * inv * wv.x, v.y * inv * wv.y),
                 pk2(v.z * inv * wv.z, v.w * inv * wv.w));
}

// ---------------------------------------------------------------------------
extern "C" void kernel_launch(void* const* d_in, const int* in_sizes, int n_in,
                              void* d_out, int out_size, void* d_ws, size_t ws_size,
                              hipStream_t stream)
{
  const int*   tokens  = (const int*)d_in[0];
  const float* embed   = (const float*)d_in[1];
  const float* ln_in_w = (const float*)d_in[2];
  const float* ln_out_w= (const float*)d_in[3];
  const float* W_route = (const float*)d_in[4];
  const float* cells   = (const float*)d_in[5];
  const float* W_in    = (const float*)d_in[6];
  const float* W_out   = (const float*)d_in[7];
  const float* sdec    = (const float*)d_in[8];
  const float* sgw     = (const float*)d_in[9];
  const float* sgb     = (const float*)d_in[10];
  const float* ssc     = (const float*)d_in[11];
  const float* csc     = (const float*)d_in[12];
  const float* Wg      = (const float*)d_in[13];
  const float* Wu      = (const float*)d_in[14];
  const float* Wd      = (const float*)d_in[15];
  const float* ffw     = (const float*)d_in[16];
  const float* nrw     = (const float*)d_in[17];
  float* out = (float*)d_out;
  (void)in_sizes; (void)n_in; (void)out_size;

  char* ws = (char*)d_ws;
  size_t off = 0;
  auto alloc = [&](size_t bytes) -> void* {
    void* p = ws + off;
    off += (bytes + 255) & ~(size_t)255;
    return p;
  };

  // ---- epoch 1 (layer loop scratch) ----
  float* scores = (float*)alloc((size_t)MTOK * NCELL * 4);
  u16*  act_bf  = (u16*)alloc((size_t)MTOK * DFF * 2);
  float* x_f    = (float*)alloc((size_t)MTOK * DMODEL * 4);
  u16*  x_bf    = (u16*)alloc((size_t)MTOK * DMODEL * 2);
  u16*  h2_bf   = (u16*)alloc((size_t)MTOK * DMODEL * 2);
  float* xin    = (float*)alloc((size_t)MTOK * DCELL * 4);
  u16*  r_bf    = (u16*)alloc((size_t)MTOK * DCELL * 2);
  float* cellout= (float*)alloc((size_t)MTOK * DMODEL * 4);
  u16*  WiT     = (u16*)alloc((size_t)DCELL * DMODEL * 2);
  u16*  WoT     = (u16*)alloc((size_t)DMODEL * DCELL * 2);
  u16*  WguT    = (u16*)alloc((size_t)8192 * DMODEL * 2);
  u16*  WdTa    = (u16*)alloc((size_t)DMODEL * DFF * 2);
  u16*  WdTb    = (u16*)alloc((size_t)DMODEL * DFF * 2);   // double-buffered
  u16*  WrB     = (u16*)alloc((size_t)NCELL * DMODEL * 2);
  float* E      = (float*)alloc((size_t)131072 * 4);
  // ---- persistent tail (above embed_bf's 103 MB span) ----
  if (off < ((size_t)108 << 20)) off = (size_t)108 << 20;
  u16*  xf_bf   = (u16*)alloc((size_t)MTOK * DMODEL * 2);
  float* vpad   = (float*)alloc((size_t)MTOK * VPAD_LD * 4);   // 412 MB
  size_t need_pad = off;
  // ---- epoch 2 overlay (written only after layer loop) ----
  u16*  embed_bf = (u16*)ws;

  const bool use_pad = (ws_size >= need_pad);

  k_embed_norm<<<MTOK, 256, 0, stream>>>(tokens, embed, ln_in_w, x_f, x_bf);
  // layer 0 weight prep
  k_transpose_layer<<<14848, 256, 0, stream>>>(W_in, W_out, Wg, Wu, Wd, W_route,
                                               WiT, WoT, WguT, WdTa, WrB);

  for (int lay = 0; lay < 8; ++lay) {
    const float* cells_l = cells + (size_t)lay * NCELL * DCELL;
    u16* WdT_cur = (lay & 1) ? WdTb : WdTa;
    u16* WdT_nxt = (lay & 1) ? WdTa : WdTb;

    // scores = x @ Wr^T / 32
    k_gemm_v3<128, 128, 0><<<512, 256, 0, stream>>>(x_bf, WrB, scores, nullptr,
        nullptr, NCELL, DMODEL, NCELL, 0.03125f);
    // xin GEMM + scan pass A
    k_prep_fused<<<640, 256, 0, stream>>>(x_bf, WiT, xin, x_f, E,
        sgw + lay * DMODEL, sgb + lay * DMODEL, sdec + lay);
    // top-8 + softmax + readout
    k_cell_fused<<<512, 256, 0, stream>>>(scores, cells_l, xin, r_bf);
    // cell_out = readout @ W_out
    k_gemm64<<<dim3(32, 16), 256, 0, stream>>>(r_bf, WoT, cellout,
        DCELL, DCELL, DCELL, DMODEL);
    // scan pass B + both rmsnorms
    k_scan_norm<<<128, 1024, 0, stream>>>(x_f, cellout, E, h2_bf,
        sgw + lay * DMODEL, sgb + lay * DMODEL, ssc + lay * DMODEL,
        sdec + lay, csc + lay, nrw + lay * DMODEL, ffw + lay * DMODEL);
    // act = silu(g)*u fused epilogue
    k_gemm_v3<128, 128, 3><<<1024, 256, 0, stream>>>(h2_bf, WguT, nullptr, act_bf,
        nullptr, 8192, DMODEL, 0, 1.0f);
    // x = x + act @ Wd ; fused with next layer's weight prep
    if (lay < 7) {
      int nl = lay + 1;
      k_wd_prep<<<15360, 256, 0, stream>>>(act_bf, WdT_cur, x_f, x_bf,
          W_in  + (size_t)nl * DMODEL * DCELL,
          W_out + (size_t)nl * DCELL * DMODEL,
          Wg    + (size_t)nl * DMODEL * DFF,
          Wu    + (size_t)nl * DMODEL * DFF,
          Wd    + (size_t)nl * DFF * DMODEL,
          W_route + (size_t)nl * NCELL * DMODEL,
          WiT, WoT, WguT, WdT_nxt, WrB);
    } else {
      k_gemm_v3<64, 64, 1><<<512, 256, 0, stream>>>(act_bf, WdT_cur, x_f, x_bf,
          x_f, DMODEL, DFF, DMODEL, 1.0f);
    }
  }

  // tail: final norm + embed bf16 convert (fused)
  k_tail<<<2048 + 25129, 256, 0, stream>>>(x_f, ln_out_w, xf_bf, embed, embed_bf);
  // logits GEMM (TM=128 x TN=128, NT stores) -> pad -> copy
  if (use_pad) {
    k_gemm_v3<128, 128, 4><<<6288, 256, 0, stream>>>(xf_bf, embed_bf, vpad, nullptr,
        nullptr, NVOCAB, DMODEL, VPAD_LD, 1.0f);
    k_copy_out<<<MTOK, 256, 0, stream>>>(vpad, out);
  } else {
    k_gemm_v3<128, 128, 2><<<6288, 256, 0, stream>>>(xf_bf, embed_bf, out, nullptr,
        nullptr, NVOCAB, DMODEL, NVOCAB, 1.0f);
  }
}

// Round 14
// 2484.859 us; speedup vs baseline: 2.3823x; 1.0720x over previous
//
#include <hip/hip_runtime.h>
#include <stdint.h>

typedef __attribute__((ext_vector_type(8))) short bf16x8;
typedef __attribute__((ext_vector_type(4))) float f32x4;
typedef unsigned short u16;
typedef unsigned int u32;

#define MTOK 2048
#define DMODEL 1024
#define NCELL 4096
#define DCELL 256
#define DFF 4096
#define NVOCAB 50257
#define VPAD_LD 50304          // 393 * 128, aligned pad leading dim

static __device__ __forceinline__ u16 f2bf(float f) {
  u32 u = __builtin_bit_cast(u32, f);
  u = (u + 0x7FFFu + ((u >> 16) & 1u)) >> 16;
  return (u16)u;
}
static __device__ __forceinline__ u32 pk2(float a, float b) {
  return (u32)f2bf(a) | ((u32)f2bf(b) << 16);
}
static __device__ __forceinline__ float sigm(float x) { return 1.0f / (1.0f + __expf(-x)); }

// async global->LDS, 16 B per lane; lds dest = wave-uniform base + lane*16
static __device__ __forceinline__ void glds16(const void* g, void* l) {
  __builtin_amdgcn_global_load_lds(
      (const __attribute__((address_space(1))) void*)g,
      (__attribute__((address_space(3))) void*)l, 16, 0, 0);
}

static __device__ __forceinline__ float blockReduceSum(float v) {
#pragma unroll
  for (int o = 32; o > 0; o >>= 1) v += __shfl_xor(v, o);
  __shared__ float sm[4];
  __syncthreads();
  if ((threadIdx.x & 63) == 0) sm[threadIdx.x >> 6] = v;
  __syncthreads();
  return sm[0] + sm[1] + sm[2] + sm[3];
}

// 1024-thread block reduce of a PAIR (16 waves)
static __device__ __forceinline__ void blockReducePair1024(
    float& a, float& b, float* sm)
{
#pragma unroll
  for (int o = 32; o > 0; o >>= 1) { a += __shfl_xor(a, o); b += __shfl_xor(b, o); }
  int wv = threadIdx.x >> 6;
  if ((threadIdx.x & 63) == 0) { sm[wv * 2] = a; sm[wv * 2 + 1] = b; }
  __syncthreads();
  float ra = 0.f, rb = 0.f;
#pragma unroll
  for (int i = 0; i < 16; ++i) { ra += sm[i * 2]; rb += sm[i * 2 + 1]; }
  __syncthreads();
  a = ra; b = rb;
}

// ---------------------------------------------------------------------------
// m97-style GEMM device body: C[2048,N] = A[2048,K](bf16) x B[N,K]^T(bf16)
// TM,TN in {64,128}. global_load_lds staging, 2 barriers per K-step.
// Virtual 1D grid (bid in [0,T)), XCD-affine swizzle. 4 waves 2x2.
// EPI 0: Cf = alpha*acc          EPI 1: residual r=Res+acc -> Cf,f2bf->Cb
// EPI 2: predicated col<NB       EPI 3: fused SwiGLU -> bf16 Cb
// EPI 4: nontemporal aligned f32 store (vpad)
// ---------------------------------------------------------------------------
template<int TM, int TN, int EPI>
static __device__ __forceinline__ void v3_body(
    int bid, int T, char* smem,
    const u16* A, const u16* B,
    float* Cf, u16* Cb, const float* Res,
    int NB, int K, int ldc, float alpha)
{
  u16* As = (u16*)smem;
  u16* Bs = (u16*)(smem + TM * 128);
  constexpr int MI = TM / 32;
  constexpr int NI = TN / 32;
  constexpr int ACH = TM / 32;
  constexpr int BCH = TN / 32;
  constexpr int MB = 2048 / TM;
  const int tid = threadIdx.x;
  const int w = (bid & 7) * (T >> 3) + (bid >> 3);
  const int m0 = (w % MB) * TM;
  const int n0 = (w / MB) * TN;
  const int l = tid & 63;
  const int wv = tid >> 6;
  const int wm = wv >> 1, wn = wv & 1;
  const int lr = l & 15, lg = l >> 4;
  const int wbase = tid & ~63;

  f32x4 acc[MI][NI] = {};

  const int row_ = tid >> 3;
  const int kc_ = (tid & 7) << 3;
  const int nk = K >> 6;

  for (int s = 0; s < nk; ++s) {
    const int k0 = s << 6;
#pragma unroll
    for (int c = 0; c < ACH; ++c) {
      int row = c * 32 + row_;
      glds16(&A[(size_t)(m0 + row) * K + k0 + kc_],
             &As[(size_t)(c * 256 + wbase) * 8]);
    }
#pragma unroll
    for (int c = 0; c < BCH; ++c) {
      int row = c * 32 + row_;
      int gr = n0 + row; if (gr > NB - 1) gr = NB - 1;
      glds16(&B[(size_t)gr * K + k0 + kc_],
             &Bs[(size_t)(c * 256 + wbase) * 8]);
    }
    __syncthreads();
#pragma unroll
    for (int kk = 0; kk < 2; ++kk) {
      bf16x8 fa[MI], fb[NI];
#pragma unroll
      for (int mi = 0; mi < MI; ++mi)
        fa[mi] = *(const bf16x8*)&As[(wm * (TM / 2) + mi * 16 + lr) * 64 + kk * 32 + lg * 8];
#pragma unroll
      for (int ni = 0; ni < NI; ++ni)
        fb[ni] = *(const bf16x8*)&Bs[(wn * (TN / 2) + ni * 16 + lr) * 64 + kk * 32 + lg * 8];
#pragma unroll
      for (int mi = 0; mi < MI; ++mi)
#pragma unroll
        for (int ni = 0; ni < NI; ++ni)
          acc[mi][ni] = __builtin_amdgcn_mfma_f32_16x16x32_bf16(fa[mi], fb[ni], acc[mi][ni], 0, 0, 0);
    }
    __syncthreads();
  }

#pragma unroll
  for (int mi = 0; mi < MI; ++mi)
#pragma unroll
    for (int ni = 0; ni < NI; ++ni) {
      int col = n0 + wn * (TN / 2) + ni * 16 + lr;
#pragma unroll
      for (int j = 0; j < 4; ++j) {
        int row = m0 + wm * (TM / 2) + mi * 16 + lg * 4 + j;
        float v = acc[mi][ni][j];
        if constexpr (EPI == 0) {
          Cf[(size_t)row * ldc + col] = v * alpha;
        } else if constexpr (EPI == 1) {
          size_t off = (size_t)row * ldc + col;
          float r = Res[off] + v;
          Cf[off] = r;
          Cb[off] = f2bf(r);
        } else if constexpr (EPI == 2) {
          if (col < NB) Cf[(size_t)row * ldc + col] = v;
        } else if constexpr (EPI == 3) {
          float p = __shfl_xor(v, 1);
          float a = v * sigm(v) * p;
          float a2 = __shfl_xor(a, 2);
          if ((lr & 3) == 0)
            *(u32*)&Cb[(size_t)row * DFF + (col >> 1)] = pk2(a, a2);
        } else {  // EPI == 4
          __builtin_nontemporal_store(v, &Cf[(size_t)row * ldc + col]);
        }
      }
    }
}

template<int TM, int TN, int EPI>
__global__ __launch_bounds__(256, 3) void k_gemm_v3(
    const u16* __restrict__ A, const u16* __restrict__ B,
    float* __restrict__ Cf, u16* __restrict__ Cb, const float* __restrict__ Res,
    int NB, int K, int ldc, float alpha)
{
  __shared__ __align__(16) char smem[(TM + TN) * 128];
  v3_body<TM, TN, EPI>(blockIdx.x, gridDim.x, smem, A, B, Cf, Cb, Res,
                       NB, K, ldc, alpha);
}

// ---------------------------------------------------------------------------
// Weight transpose+convert body: fp32 [R,C] -> bf16 [C,R]; bid >= 12800
// flat-converts W_route. bid in [0, 14848).
// ---------------------------------------------------------------------------
static __device__ __forceinline__ void transpose_body(
    int bid, char* smem,
    const float* Wi, const float* Wo, const float* Wg, const float* Wu,
    const float* Wd, const float* Wr,
    u16* WiT, u16* WoT, u16* WguT, u16* WdT, u16* WrB)
{
  if (bid >= 12800) {
    int i = (bid - 12800) * 256 + threadIdx.x;
    const float4* s = (const float4*)(Wr + (size_t)i * 8);
    float4 a = s[0], b = s[1];
    *(uint4*)(WrB + (size_t)i * 8) =
        make_uint4(pk2(a.x, a.y), pk2(a.z, a.w), pk2(b.x, b.y), pk2(b.z, b.w));
    return;
  }
  const float* src; u16* dst; int R, C, t0, mul, add;
  if (bid < 256)       { src = Wi; dst = WiT;  R = 1024; C = 256;  t0 = bid;        mul = 1; add = 0; }
  else if (bid < 512)  { src = Wo; dst = WoT;  R = 256;  C = 1024; t0 = bid - 256;  mul = 1; add = 0; }
  else if (bid < 4608) { src = Wg; dst = WguT; R = 1024; C = 4096; t0 = bid - 512;  mul = 2; add = 0; }
  else if (bid < 8704) { src = Wu; dst = WguT; R = 1024; C = 4096; t0 = bid - 4608; mul = 2; add = 1; }
  else                 { src = Wd; dst = WdT;  R = 4096; C = 1024; t0 = bid - 8704; mul = 1; add = 0; }
  int tC = C >> 5;
  int r0 = (t0 / tC) << 5, c0 = (t0 % tC) << 5;
  float (*tile)[33] = (float(*)[33])smem;
  int ty = threadIdx.x >> 3;
  int tx = (threadIdx.x & 7) << 2;
  float4 v = *(const float4*)&src[(size_t)(r0 + ty) * C + c0 + tx];
  tile[ty][tx] = v.x; tile[ty][tx + 1] = v.y; tile[ty][tx + 2] = v.z; tile[ty][tx + 3] = v.w;
  __syncthreads();
  float a = tile[tx][ty], b = tile[tx + 1][ty], c = tile[tx + 2][ty], d = tile[tx + 3][ty];
  *(uint2*)&dst[((size_t)(c0 + ty) * mul + add) * R + r0 + tx] = make_uint2(pk2(a, b), pk2(c, d));
}

__global__ void k_transpose_layer(
    const float* __restrict__ Wi, const float* __restrict__ Wo,
    const float* __restrict__ Wg, const float* __restrict__ Wu,
    const float* __restrict__ Wd, const float* __restrict__ Wr,
    u16* __restrict__ WiT, u16* __restrict__ WoT,
    u16* __restrict__ WguT, u16* __restrict__ WdT, u16* __restrict__ WrB)
{
  __shared__ __align__(16) char smem[4224];
  transpose_body(blockIdx.x, smem, Wi, Wo, Wg, Wu, Wd, Wr,
                 WiT, WoT, WguT, WdT, WrB);
}

// ---------------------------------------------------------------------------
// 64x64 GEMM device body (NT, bf16), Cf = acc.
// ---------------------------------------------------------------------------
static __device__ __forceinline__ void gemm64_body(
    const u16* A, const u16* B, float* Cf,
    int m0, int n0, int K, int lda, int ldb, int ldc, char* smem)
{
  u16* As = (u16*)smem;
  u16* Bs = (u16*)(smem + 64 * 64 * 2);
  const int tid = threadIdx.x;
  const int l = tid & 63;
  const int wv = tid >> 6;
  const int wm = wv >> 1, wn = wv & 1;
  const int lr = l & 15, lg = l >> 4;

  uint4 aR[2], bR[2];
  f32x4 acc[2][2] = {};
  const int nk = K >> 6;

  auto loadAB = [&](int k0) {
#pragma unroll
    for (int c = 0; c < 2; ++c) {
      int id = c * 256 + tid;
      int row = id >> 3, kc = (id & 7) << 3;
      aR[c] = *(const uint4*)&A[(size_t)(m0 + row) * lda + k0 + kc];
      bR[c] = *(const uint4*)&B[(size_t)(n0 + row) * ldb + k0 + kc];
    }
  };
  auto stage = [&]() {
#pragma unroll
    for (int c = 0; c < 2; ++c) {
      int id = c * 256 + tid;
      int row = id >> 3, kc = (id & 7) << 3;
      *(uint4*)&As[row * 64 + kc] = aR[c];
      *(uint4*)&Bs[row * 64 + kc] = bR[c];
    }
  };

  loadAB(0);
  for (int s = 0; s < nk; ++s) {
    __syncthreads();
    stage();
    __syncthreads();
    if (s + 1 < nk) loadAB((s + 1) << 6);
#pragma unroll
    for (int kk = 0; kk < 2; ++kk) {
      bf16x8 fa[2], fb[2];
#pragma unroll
      for (int mi = 0; mi < 2; ++mi)
        fa[mi] = *(const bf16x8*)&As[(wm * 32 + mi * 16 + lr) * 64 + kk * 32 + lg * 8];
#pragma unroll
      for (int ni = 0; ni < 2; ++ni)
        fb[ni] = *(const bf16x8*)&Bs[(wn * 32 + ni * 16 + lr) * 64 + kk * 32 + lg * 8];
#pragma unroll
      for (int mi = 0; mi < 2; ++mi)
#pragma unroll
        for (int ni = 0; ni < 2; ++ni)
          acc[mi][ni] = __builtin_amdgcn_mfma_f32_16x16x32_bf16(fa[mi], fb[ni], acc[mi][ni], 0, 0, 0);
    }
  }

#pragma unroll
  for (int mi = 0; mi < 2; ++mi)
#pragma unroll
    for (int ni = 0; ni < 2; ++ni) {
      int col = n0 + wn * 32 + ni * 16 + lr;
#pragma unroll
      for (int j = 0; j < 4; ++j) {
        int row = m0 + wm * 32 + mi * 16 + lg * 4 + j;
        Cf[(size_t)row * ldc + col] = acc[mi][ni][j];
      }
    }
}

__global__ __launch_bounds__(256, 3) void k_gemm64(
    const u16* __restrict__ A, const u16* __restrict__ B,
    float* __restrict__ Cf, int K, int lda, int ldb, int ldc)
{
  __shared__ __align__(16) char smem[16384];
  gemm64_body(A, B, Cf, blockIdx.x * 64, blockIdx.y * 64, K, lda, ldb, ldc, smem);
}

// ---------------------------------------------------------------------------
// Fused head-of-layer: blocks [0,512) = scores GEMM (128x128, EPI0);
// [512,640) = gemm64 xin; [640,1152) = scan_a (16 chunks of 16).
// All three depend only on previous-layer x_bf/x_f.
// ---------------------------------------------------------------------------
__global__ __launch_bounds__(256, 3) void k_head_fused(
    const u16* __restrict__ x_bf, const u16* __restrict__ WrB,
    float* __restrict__ scores,
    const u16* __restrict__ WiT, float* __restrict__ xin,
    const float* __restrict__ x_f, float* __restrict__ E,
    const float* __restrict__ sgw, const float* __restrict__ sgb,
    const float* __restrict__ sdec)
{
  __shared__ __align__(16) char smem[32768];
  int bid = blockIdx.x;
  if (bid < 512) {
    v3_body<128, 128, 0>(bid, 512, smem, x_bf, WrB, scores, nullptr, nullptr,
                         NCELL, DMODEL, NCELL, 0.03125f);
    return;
  }
  if (bid < 640) {
    int b2 = bid - 512;
    gemm64_body(x_bf, WiT, xin, (b2 & 31) * 64, (b2 >> 5) * 64,
                DMODEL, DMODEL, DMODEL, DCELL, smem);
    return;
  }
  int tid = (bid - 640) * 256 + threadIdx.x;   // 131072 = 8b * 16c * 1024d
  int d = tid & 1023, bc = tid >> 10;
  int b = bc >> 4, c = bc & 15;
  float dec = sigm(sdec[0]);
  dec = fminf(fmaxf(dec, 0.01f), 0.99f);
  float gw = sgw[d], gb = sgb[d];
  size_t base = ((size_t)b * 256 + c * 16) * DMODEL + d;
  float h = 0.f;
  for (int t = 0; t < 16; ++t) {
    float xv = x_f[base + (size_t)t * DMODEL];
    h = h * dec + sigm(xv * gw + gb) * xv;
  }
  E[tid] = h;
}

// ---------------------------------------------------------------------------
// Fused: blocks [0,512) = Wd GEMM (64x64, residual); [512,15360) = weight
// prep for NEXT layer.
// ---------------------------------------------------------------------------
__global__ __launch_bounds__(256, 3) void k_wd_prep(
    const u16* __restrict__ act, const u16* __restrict__ WdT_cur,
    float* __restrict__ x_f, u16* __restrict__ x_bf,
    const float* __restrict__ Wi, const float* __restrict__ Wo,
    const float* __restrict__ Wg, const float* __restrict__ Wu,
    const float* __restrict__ Wd, const float* __restrict__ Wr,
    u16* __restrict__ WiT, u16* __restrict__ WoT,
    u16* __restrict__ WguT, u16* __restrict__ WdT_nxt, u16* __restrict__ WrB)
{
  __shared__ __align__(16) char smem[16384];
  int bid = blockIdx.x;
  if (bid < 512) {
    v3_body<64, 64, 1>(bid, 512, smem, act, WdT_cur, x_f, x_bf, x_f,
                       DMODEL, DFF, DMODEL, 1.0f);
  } else {
    transpose_body(bid - 512, smem, Wi, Wo, Wg, Wu, Wd, Wr,
                   WiT, WoT, WguT, WdT_nxt, WrB);
  }
}

// Streaming copy pad[row][0:NVOCAB] -> out[row][*], NT load+store.
__global__ __launch_bounds__(256) void k_copy_out(
    const float* __restrict__ pad, float* __restrict__ out)
{
  int row = blockIdx.x;
  const float* s = pad + (size_t)row * VPAD_LD;
  float* d = out + (size_t)row * NVOCAB;
  int t = threadIdx.x;
  int head = (int)((16 - (((size_t)d) & 15)) & 15) >> 2;
  if (t < head) d[t] = s[t];
  int nb = (NVOCAB - head) >> 2;
  const float* sb = s + head;
  float* db = d + head;
  for (int i = t; i < nb; i += 256) {
    f32x4 v;
    v.x = __builtin_nontemporal_load(&sb[i * 4 + 0]);
    v.y = __builtin_nontemporal_load(&sb[i * 4 + 1]);
    v.z = __builtin_nontemporal_load(&sb[i * 4 + 2]);
    v.w = __builtin_nontemporal_load(&sb[i * 4 + 3]);
    __builtin_nontemporal_store(v, (f32x4*)&db[i * 4]);
  }
  int t0 = head + nb * 4;
  int rem = NVOCAB - t0;
  if (t < rem) d[t0 + t] = s[t0 + t];
}

// ---------------------------------------------------------------------------
// Fused top-8 + softmax + readout. Block = 4 rows.
// ---------------------------------------------------------------------------
__global__ __launch_bounds__(256) void k_cell_fused(
    const float* __restrict__ scores, const float* __restrict__ cells,
    const float* __restrict__ xin, u16* __restrict__ rb)
{
  __shared__ float sw[4][8];
  __shared__ int si[4][8];
  int row0 = blockIdx.x * 4;
  int wvid = threadIdx.x >> 6;
  int row = row0 + wvid;
  int l = threadIdx.x & 63;
  const float* s = scores + (size_t)row * NCELL;
  float v[8]; int ix[8];
#pragma unroll
  for (int i = 0; i < 8; ++i) { v[i] = -3.4e38f; ix[i] = 0x7fffffff; }
  for (int j = 0; j < 64; ++j) {
    float x = s[j * 64 + l];
    if (x > v[7]) {
      v[7] = x; ix[7] = j * 64 + l;
#pragma unroll
      for (int q = 7; q > 0; --q) {
        if (v[q] > v[q - 1]) {
          float tv = v[q]; v[q] = v[q - 1]; v[q - 1] = tv;
          int tt = ix[q]; ix[q] = ix[q - 1]; ix[q - 1] = tt;
        }
      }
    }
  }
  float ov[8]; int oi[8];
#pragma unroll
  for (int r = 0; r < 8; ++r) {
    float bv = v[0]; int bi = ix[0];
#pragma unroll
    for (int o = 32; o > 0; o >>= 1) {
      float tv = __shfl_xor(bv, o);
      int tb = __shfl_xor(bi, o);
      if (tv > bv || (tv == bv && tb < bi)) { bv = tv; bi = tb; }
    }
    ov[r] = bv; oi[r] = bi;
    if (bi == ix[0]) {
#pragma unroll
      for (int q = 0; q < 7; ++q) { v[q] = v[q + 1]; ix[q] = ix[q + 1]; }
      v[7] = -3.4e38f; ix[7] = 0x7fffffff;
    }
  }
  if (l == 0) {
    float m = ov[0], sum = 0.f, e[8];
#pragma unroll
    for (int r = 0; r < 8; ++r) { e[r] = __expf(ov[r] - m); sum += e[r]; }
    float inv = 1.0f / sum;
#pragma unroll
    for (int r = 0; r < 8; ++r) { sw[wvid][r] = e[r] * inv; si[wvid][r] = oi[r]; }
  }
  __syncthreads();
  int d = threadIdx.x;
#pragma unroll
  for (int r = 0; r < 4; ++r) {
    int rr = row0 + r;
    float acc = xin[(size_t)rr * DCELL + d];
#pragma unroll
    for (int k = 0; k < 8; ++k)
      acc += sw[r][k] * cells[(size_t)si[r][k] * DCELL + d];
    rb[(size_t)rr * DCELL + d] = f2bf(acc);
  }
}

// ---------------------------------------------------------------------------
// Fused scan_b + double rmsnorm, single reduction pass per t-step:
// reduce (pre^2, (pre*nw)^2) together; inv2 = rsqrt(inv^2*S2/D + eps).
// ---------------------------------------------------------------------------
__global__ __launch_bounds__(1024) void k_scan_norm(
    float* __restrict__ x_f, const float* __restrict__ co,
    const float* __restrict__ E, u16* __restrict__ h2b,
    const float* __restrict__ sgw, const float* __restrict__ sgb,
    const float* __restrict__ ssc, const float* __restrict__ sdec,
    const float* __restrict__ csc, const float* __restrict__ nw,
    const float* __restrict__ fw)
{
  __shared__ float sm[32];
  int b = blockIdx.x >> 4, c = blockIdx.x & 15;
  int d = threadIdx.x;
  float dec = sigm(sdec[0]);
  dec = fminf(fmaxf(dec, 0.01f), 0.99f);
  float d2 = dec * dec, d4 = d2 * d2, d8 = d4 * d4;
  float d16 = d8 * d8;
  float cs = csc[0];
  float gw = sgw[d], gb = sgb[d], sc = ssc[d];
  float nwd = nw[d], fwd = fw[d];
  float h = 0.f;
  for (int cc = 0; cc < c; ++cc) h = h * d16 + E[((b << 4) + cc) * 1024 + d];
  size_t base = ((size_t)b * 256 + c * 16) * DMODEL + d;
  for (int t = 0; t < 16; ++t) {
    size_t o = base + (size_t)t * DMODEL;
    float xv = x_f[o];
    float g = sigm(xv * gw + gb);
    h = h * dec + g * xv;
    float pre = xv + cs * co[o] + h * sc;
    float pn = pre * nwd;
    float s1 = pre * pre, s2 = pn * pn;
    blockReducePair1024(s1, s2, sm);
    float inv = rsqrtf(s1 * (1.0f / DMODEL) + 1e-6f);
    float x1 = pre * inv * nwd;
    float inv2 = rsqrtf(inv * inv * s2 * (1.0f / DMODEL) + 1e-6f);
    x_f[o] = x1;
    h2b[o] = f2bf(x1 * inv2 * fwd);
  }
}

__global__ void k_embed_norm(const int* __restrict__ tok, const float* __restrict__ emb,
                             const float* __restrict__ w, float* __restrict__ xf,
                             u16* __restrict__ xb)
{
  int row = blockIdx.x;
  int t = tok[row];
  float4 v = ((const float4*)(emb + (size_t)t * DMODEL))[threadIdx.x];
  float tot = blockReduceSum(v.x * v.x + v.y * v.y + v.z * v.z + v.w * v.w);
  float inv = rsqrtf(tot * (1.0f / DMODEL) + 1e-6f);
  int d0 = threadIdx.x << 2;
  float4 wv = *(const float4*)(w + d0);
  float4 o;
  o.x = v.x * inv * wv.x; o.y = v.y * inv * wv.y;
  o.z = v.z * inv * wv.z; o.w = v.w * inv * wv.w;
  *(float4*)(xf + (size_t)row * DMODEL + d0) = o;
  *(uint2*)(xb + (size_t)row * DMODEL + d0) = make_uint2(pk2(o.x, o.y), pk2(o.z, o.w));
}

// Tail fused: blocks [0,2048) rmsnorm(x_f)*ln_out -> xf_bf;
// blocks [2048, ...) embed fp32->bf16 flat convert.
__global__ __launch_bounds__(256) void k_tail(
    const float* __restrict__ xf, const float* __restrict__ w,
    u16* __restrict__ ob, const float* __restrict__ emb,
    u16* __restrict__ emb_bf)
{
  int bid = blockIdx.x;
  if (bid >= 2048) {
    int i = (bid - 2048) * 256 + threadIdx.x;
    if (i >= NVOCAB * (DMODEL / 8)) return;
    const float4* s = (const float4*)(emb + (size_t)i * 8);
    float4 a = s[0], b = s[1];
    *(uint4*)(emb_bf + (size_t)i * 8) =
        make_uint4(pk2(a.x, a.y), pk2(a.z, a.w), pk2(b.x, b.y), pk2(b.z, b.w));
    return;
  }
  int row = bid;
  float4 v = ((const float4*)(xf + (size_t)row * DMODEL))[threadIdx.x];
  float tot = blockReduceSum(v.x * v.x + v.y * v.y + v.z * v.z + v.w * v.w);
  float inv = rsqrtf(tot * (1.0f / DMODEL) + 1e-6f);
  int d0 = threadIdx.x << 2;
  float4 wv = *(const float4*)(w + d0);
  *(uint2*)(ob + (size_t)row * DMODEL + d0) =
      make_uint2(pk2(v.x * inv * wv.x, v.y * inv * wv.y),
                 pk2(v.z * inv * wv.z, v.w * inv * wv.w));
}

// ---------------------------------------------------------------------------
extern "C" void kernel_launch(void* const* d_in, const int* in_sizes, int n_in,
                              void* d_out, int out_size, void* d_ws, size_t ws_size,
                              hipStream_t stream)
{
  const int*   tokens  = (const int*)d_in[0];
  const float* embed   = (const float*)d_in[1];
  const float* ln_in_w = (const float*)d_in[2];
  const float* ln_out_w= (const float*)d_in[3];
  const float* W_route = (const float*)d_in[4];
  const float* cells   = (const float*)d_in[5];
  const float* W_in    = (const float*)d_in[6];
  const float* W_out   = (const float*)d_in[7];
  const float* sdec    = (const float*)d_in[8];
  const float* sgw     = (const float*)d_in[9];
  const float* sgb     = (const float*)d_in[10];
  const float* ssc     = (const float*)d_in[11];
  const float* csc     = (const float*)d_in[12];
  const float* Wg      = (const float*)d_in[13];
  const float* Wu      = (const float*)d_in[14];
  const float* Wd      = (const float*)d_in[15];
  const float* ffw     = (const float*)d_in[16];
  const float* nrw     = (const float*)d_in[17];
  float* out = (float*)d_out;
  (void)in_sizes; (void)n_in; (void)out_size;

  char* ws = (char*)d_ws;
  size_t off = 0;
  auto alloc = [&](size_t bytes) -> void* {
    void* p = ws + off;
    off += (bytes + 255) & ~(size_t)255;
    return p;
  };

  // ---- epoch 1 (layer loop scratch) ----
  float* scores = (float*)alloc((size_t)MTOK * NCELL * 4);
  u16*  act_bf  = (u16*)alloc((size_t)MTOK * DFF * 2);
  float* x_f    = (float*)alloc((size_t)MTOK * DMODEL * 4);
  u16*  x_bf    = (u16*)alloc((size_t)MTOK * DMODEL * 2);
  u16*  h2_bf   = (u16*)alloc((size_t)MTOK * DMODEL * 2);
  float* xin    = (float*)alloc((size_t)MTOK * DCELL * 4);
  u16*  r_bf    = (u16*)alloc((size_t)MTOK * DCELL * 2);
  float* cellout= (float*)alloc((size_t)MTOK * DMODEL * 4);
  u16*  WiT     = (u16*)alloc((size_t)DCELL * DMODEL * 2);
  u16*  WoT     = (u16*)alloc((size_t)DMODEL * DCELL * 2);
  u16*  WguT    = (u16*)alloc((size_t)8192 * DMODEL * 2);
  u16*  WdTa    = (u16*)alloc((size_t)DMODEL * DFF * 2);
  u16*  WdTb    = (u16*)alloc((size_t)DMODEL * DFF * 2);   // double-buffered
  u16*  WrB     = (u16*)alloc((size_t)NCELL * DMODEL * 2);
  float* E      = (float*)alloc((size_t)131072 * 4);
  // ---- persistent tail (above embed_bf's 103 MB span) ----
  if (off < ((size_t)108 << 20)) off = (size_t)108 << 20;
  u16*  xf_bf   = (u16*)alloc((size_t)MTOK * DMODEL * 2);
  float* vpad   = (float*)alloc((size_t)MTOK * VPAD_LD * 4);   // 412 MB
  size_t need_pad = off;
  // ---- epoch 2 overlay (written only after layer loop) ----
  u16*  embed_bf = (u16*)ws;

  const bool use_pad = (ws_size >= need_pad);

  k_embed_norm<<<MTOK, 256, 0, stream>>>(tokens, embed, ln_in_w, x_f, x_bf);
  // layer 0 weight prep
  k_transpose_layer<<<14848, 256, 0, stream>>>(W_in, W_out, Wg, Wu, Wd, W_route,
                                               WiT, WoT, WguT, WdTa, WrB);

  for (int lay = 0; lay < 8; ++lay) {
    const float* cells_l = cells + (size_t)lay * NCELL * DCELL;
    u16* WdT_cur = (lay & 1) ? WdTb : WdTa;
    u16* WdT_nxt = (lay & 1) ? WdTa : WdTb;

    // head: scores GEMM + xin GEMM + scan pass A (fused, independent)
    k_head_fused<<<1152, 256, 0, stream>>>(x_bf, WrB, scores, WiT, xin, x_f, E,
        sgw + lay * DMODEL, sgb + lay * DMODEL, sdec + lay);
    // top-8 + softmax + readout
    k_cell_fused<<<512, 256, 0, stream>>>(scores, cells_l, xin, r_bf);
    // cell_out = readout @ W_out
    k_gemm64<<<dim3(32, 16), 256, 0, stream>>>(r_bf, WoT, cellout,
        DCELL, DCELL, DCELL, DMODEL);
    // scan pass B + both rmsnorms (single reduction pass)
    k_scan_norm<<<128, 1024, 0, stream>>>(x_f, cellout, E, h2_bf,
        sgw + lay * DMODEL, sgb + lay * DMODEL, ssc + lay * DMODEL,
        sdec + lay, csc + lay, nrw + lay * DMODEL, ffw + lay * DMODEL);
    // act = silu(g)*u fused epilogue
    k_gemm_v3<128, 128, 3><<<1024, 256, 0, stream>>>(h2_bf, WguT, nullptr, act_bf,
        nullptr, 8192, DMODEL, 0, 1.0f);
    // x = x + act @ Wd ; fused with next layer's weight prep
    if (lay < 7) {
      int nl = lay + 1;
      k_wd_prep<<<15360, 256, 0, stream>>>(act_bf, WdT_cur, x_f, x_bf,
          W_in  + (size_t)nl * DMODEL * DCELL,
          W_out + (size_t)nl * DCELL * DMODEL,
          Wg    + (size_t)nl * DMODEL * DFF,
          Wu    + (size_t)nl * DMODEL * DFF,
          Wd    + (size_t)nl * DFF * DMODEL,
          W_route + (size_t)nl * NCELL * DMODEL,
          WiT, WoT, WguT, WdT_nxt, WrB);
    } else {
      k_gemm_v3<64, 64, 1><<<512, 256, 0, stream>>>(act_bf, WdT_cur, x_f, x_bf,
          x_f, DMODEL, DFF, DMODEL, 1.0f);
    }
  }

  // tail: final norm + embed bf16 convert (fused)
  k_tail<<<2048 + 25129, 256, 0, stream>>>(x_f, ln_out_w, xf_bf, embed, embed_bf);
  // logits GEMM (TM=128 x TN=128, NT stores) -> pad -> copy
  if (use_pad) {
    k_gemm_v3<128, 128, 4><<<6288, 256, 0, stream>>>(xf_bf, embed_bf, vpad, nullptr,
        nullptr, NVOCAB, DMODEL, VPAD_LD, 1.0f);
    k_copy_out<<<MTOK, 256, 0, stream>>>(vpad, out);
  } else {
    k_gemm_v3<128, 128, 2><<<6288, 256, 0, stream>>>(xf_bf, embed_bf, out, nullptr,
        nullptr, NVOCAB, DMODEL, NVOCAB, 1.0f);
  }
}